// Round 9
// baseline (31709.357 us; speedup 1.0000x reference)
//
#include <hip/hip_runtime.h>
#include <cstddef>

#define TSEQ 256
#define NB   128
#define HID  512
#define G3   1536
#define INDIM 768
#define CH   16
#define NWG  256
#define FLS  32   // u32 stride between barrier flag lines (128 B)

typedef unsigned short bfraw;
using short8 = __attribute__((ext_vector_type(8))) short;
using f32x4  = __attribute__((ext_vector_type(4))) float;

#define MFMA16 __builtin_amdgcn_mfma_f32_16x16x32_bf16

__device__ __forceinline__ float bf2f(unsigned int u){ return __uint_as_float(u<<16); }
__device__ __forceinline__ bfraw f2bf(float f){
  unsigned int u = __float_as_uint(f);
  u += 0x7fffu + ((u>>16)&1u);
  return (bfraw)(u>>16);
}
__device__ __forceinline__ float fsig(float x){
  return __builtin_amdgcn_rcpf(1.0f + __expf(-x));
}
__device__ __forceinline__ float ftanh(float x){
  return 1.0f - 2.0f*__builtin_amdgcn_rcpf(1.0f + __expf(2.0f*x));
}

// ---- L2-bypass (coherence-point) reads: relaxed agent-scope atomics -> sc1 loads
__device__ __forceinline__ uint4 bpu4(const void* p){
  unsigned long long a = __hip_atomic_load((const unsigned long long*)p,     __ATOMIC_RELAXED, __HIP_MEMORY_SCOPE_AGENT);
  unsigned long long b = __hip_atomic_load((const unsigned long long*)p + 1, __ATOMIC_RELAXED, __HIP_MEMORY_SCOPE_AGENT);
  uint4 r; r.x=(unsigned)a; r.y=(unsigned)(a>>32); r.z=(unsigned)b; r.w=(unsigned)(b>>32);
  return r;
}
__device__ __forceinline__ short8 bps8(const void* p){
  union{ uint4 u; short8 s; } cv; cv.u = bpu4(p); return cv.s;
}
__device__ __forceinline__ float4 bpf4(const void* p){
  union{ uint4 u; float4 f; } cv; cv.u = bpu4(p); return cv.f;
}
__device__ __forceinline__ float bpf(const void* p){
  unsigned u = __hip_atomic_load((const unsigned*)p, __ATOMIC_RELAXED, __HIP_MEMORY_SCOPE_AGENT);
  return __uint_as_float(u);
}

__device__ __forceinline__ float dot8(uint4 a, uint4 b){
  const unsigned* pa = (const unsigned*)&a;
  const unsigned* pb = (const unsigned*)&b;
  float s = 0.f;
  #pragma unroll
  for (int i=0;i<4;++i)
    s += bf2f(pa[i]&0xffffu)*bf2f(pb[i]&0xffffu) + bf2f(pa[i]>>16)*bf2f(pb[i]>>16);
  return s;
}

// ---- pure-relaxed spin: sc1 loads read the coherence point; NO invalidates ----
__device__ __forceinline__ void spin_ge(unsigned* p, unsigned epoch){
  while (__hip_atomic_load(p, __ATOMIC_RELAXED, __HIP_MEMORY_SCOPE_AGENT) < epoch)
    __builtin_amdgcn_s_sleep(1);
}

// ---- grid barrier: zero acquire/invalidate; producers publish via release ----
__device__ __forceinline__ void gbar(unsigned* bar, unsigned epoch){
  __syncthreads();
  const int wg = blockIdx.x;
  const int tid = threadIdx.x;
  if (wg == 0){
    if (tid >= 1 && tid < NWG) spin_ge(&bar[tid*FLS], epoch);
    __syncthreads();
    if (tid < 8)
      __hip_atomic_store(&bar[NWG*FLS + tid*FLS], epoch, __ATOMIC_RELEASE, __HIP_MEMORY_SCOPE_AGENT);
    __syncthreads();
  } else {
    if (tid == 0){
      __hip_atomic_store(&bar[wg*FLS], epoch, __ATOMIC_RELEASE, __HIP_MEMORY_SCOPE_AGENT);
      spin_ge(&bar[NWG*FLS + (wg&7)*FLS], epoch);
    }
    __syncthreads();
  }
}

__global__ void init_k(unsigned* bar){
  int i = blockIdx.x*256 + threadIdx.x;
  if (i < (NWG+8)*FLS) bar[i] = 0u;
}

// both slots of hmbuf (fp32) and hm_bf = 1.0
__global__ void hminit_k(float* hmbuf, bfraw* hm_bf){
  int i = blockIdx.x*256 + threadIdx.x;   // 131072
  hmbuf[i] = 1.0f;
  hm_bf[i] = (bfraw)0x3f80;
}

// ---- transpose+convert: in fp32 [R][Cc] -> out bf16 [Cc][R] ----
__global__ __launch_bounds__(256)
void tconv_k(const float* __restrict__ in, bfraw* __restrict__ out, int R, int Cc){
  __shared__ float t[32][33];
  int c0 = blockIdx.x*32, r0 = blockIdx.y*32;
  int tx = threadIdx.x&31, ty = threadIdx.x>>5;
  #pragma unroll
  for (int i=0;i<32;i+=8) t[ty+i][tx] = in[(size_t)(r0+ty+i)*Cc + c0+tx];
  __syncthreads();
  #pragma unroll
  for (int i=0;i<32;i+=8) out[(size_t)(c0+ty+i)*R + r0+tx] = f2bf(t[tx][ty+i]);
}

__global__ void cvt_k(const float* __restrict__ in, bfraw* __restrict__ out, int n){
  int i = (blockIdx.x*256 + threadIdx.x)*4;
  if (i >= n) return;
  float4 v = *(const float4*)(in+i);
  uint2 o;
  o.x = (unsigned)f2bf(v.x) | ((unsigned)f2bf(v.y)<<16);
  o.y = (unsigned)f2bf(v.z) | ((unsigned)f2bf(v.w)<<16);
  *(uint2*)(out+i) = o;
}

// W_cat[n'][k], n'=dd*4+g, k<1536 (segs: a[0,512) x[512,1024) -> mWih; hm[1024,1536) -> mWhh)
__global__ void wcat_k(const float* __restrict__ mWih, const float* __restrict__ mWhh,
                       bfraw* __restrict__ Wcat){
  size_t gid = (size_t)blockIdx.x*256 + threadIdx.x;
  int np = (int)(gid / 384);
  int k4 = ((int)(gid % 384))*4;
  int dd = np>>2, g = np&3;
  float v[4];
  #pragma unroll
  for (int j=0;j<4;++j){
    int k = k4+j; float x = 0.f;
    if (g==0)      x = (k<1024) ? mWih[(size_t)dd*1024 + k]        : mWhh[(size_t)dd*512 + (k-1024)];
    else if (g==1) x = (k<1024) ? mWih[(size_t)(512+dd)*1024 + k]  : mWhh[(size_t)(512+dd)*512 + (k-1024)];
    else if (g==2) x = (k<1024) ? mWih[(size_t)(1024+dd)*1024 + k] : 0.f;
    else           x = (k<1024) ? 0.f : mWhh[(size_t)(1024+dd)*512 + (k-1024)];
    v[j] = x;
  }
  uint2 o;
  o.x = (unsigned)f2bf(v[0]) | ((unsigned)f2bf(v[1])<<16);
  o.y = (unsigned)f2bf(v[2]) | ((unsigned)f2bf(v[3])<<16);
  *(uint2*)(Wcat + (size_t)np*1536 + k4) = o;
}

__global__ void bpack_k(const float* __restrict__ mbih, const float* __restrict__ mbhh,
                        float* __restrict__ bc){
  int dd = blockIdx.x*256 + threadIdx.x;
  if (dd >= 512) return;
  bc[dd]      = mbih[dd] + mbhh[dd];
  bc[512+dd]  = mbih[512+dd] + mbhh[512+dd];
  bc[1024+dd] = mbih[1024+dd];
  bc[1536+dd] = mbhh[1024+dd];
}

__global__ void fuse_bias_k(const float* __restrict__ Wih, const float* __restrict__ bih,
                            const float* __restrict__ pb, float* __restrict__ bout)
{
  int g = blockIdx.x*256 + threadIdx.x;
  if (g >= G3) return;
  float acc = bih[g];
  const float* w = Wih + (size_t)g*HID;
  for (int e=0;e<HID;e+=4){
    float4 wv = *(const float4*)(w+e);
    float4 pv = *(const float4*)(pb+e);
    acc += wv.x*pv.x + wv.y*pv.y + wv.z*pv.z + wv.w*pv.w;
  }
  bout[g] = acc;
}

// ---- MFMA bf16 GEMM: C[MxN] = A[MxK] * B^T (+bias); z selects operand set ----
template<typename TA, typename TC, bool BIAS>
__global__ __launch_bounds__(256)
void mgemm(const TA* __restrict__ A0, const TA* __restrict__ A1,
           const bfraw* __restrict__ B0, const bfraw* __restrict__ B1,
           const float* __restrict__ bias0, const float* __restrict__ bias1,
           TC* __restrict__ C0, TC* __restrict__ C1,
           int K, int lda, int ldb, int ldc)
{
  const TA* A = blockIdx.z ? A1 : A0;
  const bfraw* B = blockIdx.z ? B1 : B0;
  const float* bias = blockIdx.z ? bias1 : bias0;
  TC* C = blockIdx.z ? C1 : C0;
  __shared__ bfraw Al[128*40];
  __shared__ bfraw Bl[128*40];
  const int tid = threadIdx.x;
  const size_t m0 = (size_t)blockIdx.y*128, n0 = (size_t)blockIdx.x*128;
  const int w = tid>>6, l = tid&63;
  const int wr = (w>>1)*64, wc = (w&1)*64;
  const int fr = l&15, fg = l>>4;
  f32x4 acc[4][4];
  #pragma unroll
  for (int i=0;i<4;++i)
    #pragma unroll
    for (int j=0;j<4;++j) acc[i][j] = (f32x4){0.f,0.f,0.f,0.f};

  const int srow = tid>>1, skc = (tid&1)*16;
  for (int k0=0; k0<K; k0+=32){
    if constexpr (sizeof(TA)==4){
      const float* ap = (const float*)A + (m0+srow)*lda + k0 + skc;
      float4 v0=*(const float4*)ap, v1=*(const float4*)(ap+4),
             v2=*(const float4*)(ap+8), v3=*(const float4*)(ap+12);
      uint4 w0, w1;
      w0.x=(unsigned)f2bf(v0.x)|((unsigned)f2bf(v0.y)<<16);
      w0.y=(unsigned)f2bf(v0.z)|((unsigned)f2bf(v0.w)<<16);
      w0.z=(unsigned)f2bf(v1.x)|((unsigned)f2bf(v1.y)<<16);
      w0.w=(unsigned)f2bf(v1.z)|((unsigned)f2bf(v1.w)<<16);
      w1.x=(unsigned)f2bf(v2.x)|((unsigned)f2bf(v2.y)<<16);
      w1.y=(unsigned)f2bf(v2.z)|((unsigned)f2bf(v2.w)<<16);
      w1.z=(unsigned)f2bf(v3.x)|((unsigned)f2bf(v3.y)<<16);
      w1.w=(unsigned)f2bf(v3.z)|((unsigned)f2bf(v3.w)<<16);
      *(uint4*)&Al[srow*40+skc]   = w0;
      *(uint4*)&Al[srow*40+skc+8] = w1;
    } else {
      const bfraw* ap = (const bfraw*)A + (m0+srow)*lda + k0 + skc;
      *(uint4*)&Al[srow*40+skc]   = *(const uint4*)ap;
      *(uint4*)&Al[srow*40+skc+8] = *(const uint4*)(ap+8);
    }
    {
      const bfraw* bp = B + (n0+srow)*ldb + k0 + skc;
      *(uint4*)&Bl[srow*40+skc]   = *(const uint4*)bp;
      *(uint4*)&Bl[srow*40+skc+8] = *(const uint4*)(bp+8);
    }
    __syncthreads();
    short8 af[4], bfr[4];
    #pragma unroll
    for (int i=0;i<4;++i) af[i]  = *(const short8*)&Al[(wr+i*16+fr)*40 + fg*8];
    #pragma unroll
    for (int j=0;j<4;++j) bfr[j] = *(const short8*)&Bl[(wc+j*16+fr)*40 + fg*8];
    #pragma unroll
    for (int i=0;i<4;++i)
      #pragma unroll
      for (int j=0;j<4;++j)
        acc[i][j] = MFMA16(af[i], bfr[j], acc[i][j], 0,0,0);
    __syncthreads();
  }
  #pragma unroll
  for (int i=0;i<4;++i){
    #pragma unroll
    for (int j=0;j<4;++j){
      size_t n = n0 + wc + j*16 + fr;
      float bv = BIAS ? bias[n] : 0.f;
      #pragma unroll
      for (int r=0;r<4;++r){
        size_t m = m0 + wr + i*16 + fg*4 + r;
        float v = acc[i][j][r] + bv;
        if constexpr (sizeof(TC)==2) ((bfraw*)C)[m*ldc + n] = f2bf(v);
        else                         ((float*)C)[m*ldc + n] = v;
      }
    }
  }
}

// ---- Phase B: persistent GRU scan, weights LDS-resident, dyn LDS 131072 ----
__global__ __launch_bounds__(512, 2)
void scanB(const float* __restrict__ GIp, const float* __restrict__ GIh,
           const bfraw* __restrict__ Whhp, const bfraw* __restrict__ Whhh,
           const float* __restrict__ bhhp, const float* __restrict__ bhhh,
           float* __restrict__ hst, bfraw* __restrict__ o_p, bfraw* __restrict__ o_h,
           int c0, unsigned* __restrict__ bar, unsigned ep0)
{
  extern __shared__ char smem[];
  bfraw* wl = (bfraw*)smem;                  // 98304 B
  float* sh = (float*)(smem + 98304);        // 32768 B
  const int wg = blockIdx.x;
  const int z = wg>>7, rem = wg&127;
  const int bg = rem>>4, dg = rem&15;
  const float* GI  = z ? GIh : GIp;
  const bfraw* Wb  = z ? Whhh : Whhp;
  const float* bhh = z ? bhhh : bhhp;
  bfraw* ob = z ? o_h : o_p;
  float* hz = hst + (size_t)z*2*NB*HID;
  const int tid = threadIdx.x;

  #pragma unroll
  for (int g=0; g<3; ++g){
    const unsigned* src = (const unsigned*)(Wb + (size_t)(g*512 + dg*32)*512);
    for (int j=0; j<16; ++j){
      int iu = tid + j*512;
      unsigned v = src[iu];
      int d = iu>>8, kk = (iu&255)*2;
      int idx0 = g*16384 + (kk>>2)*128 + d*4 + (kk&3);
      *((unsigned*)wl + (idx0>>1)) = v;
    }
  }
  __syncthreads();

  const int bl = tid>>5, dl = tid&31;
  const int d = dg*32+dl, bglob = bg*16+bl;
  const float br = bhh[d], bz = bhh[512+d], bn = bhh[1024+d];

  #pragma clang loop unroll(disable)
  for (int tt=0; tt<CH; ++tt){
    const int t = c0+tt;
    if (t == 0){
      for (int j=0;j<4;++j){
        int i4 = tid + j*512;
        *(float4*)&sh[i4*4] = (float4){1.f,1.f,1.f,1.f};
      }
    } else {
      const float* hp = hz + (size_t)((t-1)&1)*NB*HID + (size_t)bg*16*HID;
      for (int j=0;j<4;++j){
        int i4 = tid + j*512;
        *(float4*)&sh[i4*4] = bpf4(&hp[i4*4]);   // cross-WG state: bypass read
      }
    }
    __syncthreads();
    float ar = br, az = bz, an = bn;
    const float* hb = sh + bl*512;
    for (int k=0;k<512;k+=4){
      float4 h4 = *(const float4*)(hb+k);
      int base = (k>>2)*128 + dl*4;
      uint2 wr = *(const uint2*)(wl + base);
      uint2 wz = *(const uint2*)(wl + 16384 + base);
      uint2 wn = *(const uint2*)(wl + 32768 + base);
      ar += h4.x*bf2f(wr.x&0xffffu) + h4.y*bf2f(wr.x>>16) + h4.z*bf2f(wr.y&0xffffu) + h4.w*bf2f(wr.y>>16);
      az += h4.x*bf2f(wz.x&0xffffu) + h4.y*bf2f(wz.x>>16) + h4.z*bf2f(wz.y&0xffffu) + h4.w*bf2f(wz.y>>16);
      an += h4.x*bf2f(wn.x&0xffffu) + h4.y*bf2f(wn.x>>16) + h4.z*bf2f(wn.y&0xffffu) + h4.w*bf2f(wn.y>>16);
    }
    const float* gi = GI + ((size_t)tt*NB + bglob)*G3;
    float r  = fsig(gi[d] + ar);
    float zz = fsig(gi[512+d] + az);
    float n  = ftanh(gi[1024+d] + r*an);
    float hp = hb[d];
    float hv = (1.0f-zz)*n + zz*hp;
    (hz + (size_t)(t&1)*NB*HID)[(size_t)bglob*HID + d] = hv;
    ob[((size_t)t*NB + bglob)*HID + d] = f2bf(hv);
    gbar(bar, ep0 + (unsigned)tt + 1u);
  }
}

// ---- Phase D: persistent attention-match scan — 3 phases/step, acquire-free --
__global__ __launch_bounds__(512, 2)
void scanD(const bfraw* __restrict__ Whs, const bfraw* __restrict__ o_p,
           const bfraw* __restrict__ o_h,
           const bfraw* __restrict__ WtT, const bfraw* __restrict__ WmT,
           const float* __restrict__ w_e,
           const bfraw* __restrict__ Wcat, const float* __restrict__ bc,
           float* __restrict__ hmbuf, bfraw* __restrict__ hm_bf,
           bfraw* __restrict__ a_bf, float* __restrict__ Lpart,
           const float* __restrict__ outW, const float* __restrict__ outb,
           float* __restrict__ out, unsigned* __restrict__ bar, unsigned ep0)
{
  extern __shared__ char smem[];
  bfraw* whs_l = (bfraw*)smem;                 // 135168 B
  char*  stg   = smem + 135168;                // 16384 B scratch
  float* c_l   = (float*)(smem + 151552);      // 1024 B
  float* l_s   = (float*)(smem + 152576);      // 1024 B
  float* red   = (float*)(smem + 153600);      // 64 B
  float* we_s  = (float*)(smem + 153664);      // 128 B

  const int wg = blockIdx.x, tid = threadIdx.x;
  const int bg = wg>>4, dg = wg&15;

  // preload Whs slice [256 tq][8 b][32 d], stride 264 (read-only: cached loads)
  for (int q=0; q<16; ++q){
    int quad = tid + q*512;
    int tq = quad>>5, b = (quad>>2)&7, dq = quad&3;
    const bfraw* src = Whs + ((size_t)tq*NB + bg*8+b)*HID + dg*32 + dq*8;
    *(uint4*)&whs_l[tq*264 + b*32 + dq*8] = *(const uint4*)src;
  }
  if (tid < 32) we_s[tid] = w_e[dg*32 + tid];
  __syncthreads();

  #pragma clang loop unroll(disable)
  for (int t=0; t<TSEQ; ++t){
    const int rs = (t+1)&1;                    // read slot (h_{m,t-1})
    const bfraw* hmr = hm_bf + (size_t)rs*65536;
    const float* hpr = hmbuf + (size_t)rs*65536;
    bfraw* hmw = hm_bf + (size_t)(t&1)*65536;
    float* hpw = hmbuf + (size_t)(t&1)*65536;

    // ===== P1a: c[b,e] = o_h[t]@W_t + hm@W_m =====
    {
      const int w = tid>>6, l = tid&63;
      const int kh = w>>2, eq = w&3;
      const int bl = l&7, eo = l>>3;
      const int el = eq*8+eo;
      const int bglob = bg*8+bl, eglob = dg*32+el;
      const bfraw* xr = o_h + ((size_t)t*NB + bglob)*HID + kh*256;
      const bfraw* hr = hmr + (size_t)bglob*HID + kh*256;
      const bfraw* wt = WtT + (size_t)eglob*HID + kh*256;
      const bfraw* wm = WmT + (size_t)eglob*HID + kh*256;
      float acc = 0.f;
      #pragma unroll 4
      for (int k8=0;k8<32;++k8){
        uint4 xu=*(const uint4*)(xr+k8*8), wu=*(const uint4*)(wt+k8*8);
        uint4 hu=bpu4(hr+k8*8);              // cross-WG state: bypass
        uint4 mu=*(const uint4*)(wm+k8*8);
        acc += dot8(xu,wu) + dot8(hu,mu);
      }
      float* cpart = (float*)stg;   // [2][256]
      cpart[kh*256 + bl*32 + el] = acc;
      __syncthreads();
      if (tid < 256) c_l[tid] = cpart[tid] + cpart[256+tid];
      __syncthreads();
    }
    // ===== P1b: logit partials from LDS Whs =====
    {
      const int wv = tid>>6, lane = tid&63, pair = lane>>2, dq = lane&3;
      const float* cb = c_l + wv*32;
      float* stf = (float*)stg;     // [8][256]
      #pragma unroll 2
      for (int it=0; it<16; ++it){
        int tq = it*16 + pair;
        uint4 u = *(const uint4*)&whs_l[tq*264 + wv*32 + dq*8];
        float s = 0.f;
        #pragma unroll
        for (int j=0;j<4;++j){
          unsigned uu = ((const unsigned*)&u)[j];
          int d0 = dq*8 + j*2;
          s += ftanh(bf2f(uu&0xffffu) + cb[d0])   * we_s[d0];
          s += ftanh(bf2f(uu>>16)     + cb[d0+1]) * we_s[d0+1];
        }
        s += __shfl_xor(s,1); s += __shfl_xor(s,2);
        if (dq==0) stf[wv*256 + tq] = s;
      }
      __syncthreads();
      float4 lv = *(float4*)&stf[(tid>>6)*256 + (tid&63)*4];
      *(float4*)&Lpart[(((size_t)(bg*8+(tid>>6)))*16 + dg)*256 + (tid&63)*4] = lv;
    }
    gbar(bar, ep0 + (unsigned)t*3u + 1u);

    // ===== P2: softmax + a_t d-half (ALL 256 WGs: b=wg>>1, dh=wg&1) =====
    {
      const int b = wg>>1, dh = wg&1, lane = tid&63;
      float v = -1e30f, e = 0.f;
      if (tid < TSEQ){
        float s = 0.f;
        #pragma unroll
        for (int g=0; g<16; ++g)
          s += bpf(&Lpart[((size_t)b*16 + g)*256 + tid]);   // cross-WG: bypass
        v = s;
        float m = v;
        #pragma unroll
        for (int off=32; off; off>>=1) m = fmaxf(m, __shfl_xor(m, off));
        if (lane==0) red[tid>>6] = m;
      }
      __syncthreads();
      float mx = fmaxf(fmaxf(red[0],red[1]), fmaxf(red[2],red[3]));
      if (tid < TSEQ){
        e = __expf(v - mx);
        float s2 = e;
        #pragma unroll
        for (int off=32; off; off>>=1) s2 += __shfl_xor(s2, off);
        if (lane==0) red[8+(tid>>6)] = s2;
      }
      __syncthreads();
      float S = red[8]+red[9]+red[10]+red[11];
      if (tid < TSEQ) l_s[tid] = e * __builtin_amdgcn_rcpf(S);
      __syncthreads();
      // a_t over d-half (o_p read-only: cached, stays L2-resident)
      const int dgrp = tid&31, tqs = tid>>5, d8 = dgrp*8;
      const bfraw* opb = o_p + (size_t)b*HID + dh*256 + d8;
      float a0=0,a1=0,a2=0,a3=0,a4=0,a5=0,a6=0,a7=0;
      #pragma unroll
      for (int i=0;i<16;++i){
        int tq = tqs*16 + i;
        float al = l_s[tq];
        uint4 u = *(const uint4*)(opb + (size_t)tq*NB*HID);
        a0 += al*bf2f(u.x&0xffffu); a1 += al*bf2f(u.x>>16);
        a2 += al*bf2f(u.y&0xffffu); a3 += al*bf2f(u.y>>16);
        a4 += al*bf2f(u.z&0xffffu); a5 += al*bf2f(u.z>>16);
        a6 += al*bf2f(u.w&0xffffu); a7 += al*bf2f(u.w>>16);
      }
      float* pt = (float*)stg;   // [16][256]
      *(float4*)&pt[tqs*256+d8]   = (float4){a0,a1,a2,a3};
      *(float4*)&pt[tqs*256+d8+4] = (float4){a4,a5,a6,a7};
      __syncthreads();
      if (tid < 256){
        float sA = 0.f;
        #pragma unroll
        for (int ss=0;ss<16;++ss) sA += pt[ss*256 + tid];
        float sB = __shfl_down(sA, 1);
        if ((tid&1)==0){
          unsigned pk = (unsigned)f2bf(sA) | ((unsigned)f2bf(sB)<<16);
          *(unsigned*)(a_bf + (size_t)b*HID + dh*256 + tid) = pk;
        }
      }
    }
    gbar(bar, ep0 + (unsigned)t*3u + 2u);

    // ===== P3: gate MFMA (full k) + state update (wg<128, n-slice 16) =====
    if (wg < 128){
      const int n0 = wg*16;
      const int w = tid>>6, l = tid&63, fr = l&15, fg = l>>4;
      const int m0w = w*16;
      const bfraw* arow = a_bf + (size_t)(m0w+fr)*HID;
      const bfraw* xrow = o_h + ((size_t)t*NB + m0w+fr)*HID;
      const bfraw* hrow = hmr + (size_t)(m0w+fr)*HID;
      const bfraw* wrow = Wcat + (size_t)(n0+fr)*1536;
      f32x4 accA={0.f,0.f,0.f,0.f}, accB={0.f,0.f,0.f,0.f};
      #pragma unroll
      for (int kk=0; kk<16; ++kk){
        short8 af = bps8(arow + kk*32 + fg*8);          // cross-WG: bypass
        short8 bv = *(const short8*)(wrow + kk*32 + fg*8);
        accA = MFMA16(af, bv, accA, 0,0,0);
      }
      #pragma unroll
      for (int kk=0; kk<16; ++kk){
        short8 af = *(const short8*)(xrow + kk*32 + fg*8);
        short8 bv = *(const short8*)(wrow + 512 + kk*32 + fg*8);
        accB = MFMA16(af, bv, accB, 0,0,0);
      }
      #pragma unroll
      for (int kk=0; kk<16; ++kk){
        short8 af = bps8(hrow + kk*32 + fg*8);          // cross-WG: bypass
        short8 bv = *(const short8*)(wrow + 1024 + kk*32 + fg*8);
        accA = MFMA16(af, bv, accA, 0,0,0);
      }
      f32x4 acc = accA + accB;
      const int np = n0 + fr, dd = np>>2, g = np&3;
      #pragma unroll
      for (int rr=0; rr<4; ++rr){
        float x0 = acc[rr];
        float x1 = __shfl_xor(x0, 1);
        float x2 = __shfl_xor(x0, 2);
        float x3 = __shfl_xor(x1, 2);
        if (g==0){
          int b3 = m0w + fg*4 + rr;
          float hp = bpf(&hpr[(size_t)b3*HID + dd]);    // cross-WG: bypass
          float rg = fsig(x0 + bc[dd]);
          float zg = fsig(x1 + bc[512+dd]);
          float gn = ftanh(x2 + bc[1024+dd] + rg*(x3 + bc[1536+dd]));
          float h = (1.f-zg)*gn + zg*hp;
          hpw[(size_t)b3*HID + dd] = h;
          hmw[(size_t)b3*HID + dd] = f2bf(h);
        }
      }
    }
    gbar(bar, ep0 + (unsigned)t*3u + 3u);
  }

  // ---- output head: h_star in slot (TSEQ-1)&1 = 1 ----
  if (wg == 0 && tid < NB*3){
    const float* hf = hmbuf + (size_t)((TSEQ-1)&1)*65536;
    int b = tid/3, c = tid%3;
    float acc = outb[c];
    const float* h = hf + (size_t)b*HID;
    const float* w = outW + (size_t)c*HID;
    for (int d2=0; d2<HID; ++d2) acc = fmaf(bpf(h+d2), w[d2], acc);
    out[tid] = fmaxf(acc, 0.f);
  }
}

extern "C" void kernel_launch(void* const* d_in, const int* in_sizes, int n_in,
                              void* d_out, int out_size, void* d_ws, size_t ws_size,
                              hipStream_t stream)
{
  const float* Ep    = (const float*)d_in[0];
  const float* Eh    = (const float*)d_in[1];
  const float* p_W   = (const float*)d_in[2];
  const float* p_b   = (const float*)d_in[3];
  const float* h_W   = (const float*)d_in[4];
  const float* h_b   = (const float*)d_in[5];
  const float* pgWih = (const float*)d_in[6];
  const float* pgWhh = (const float*)d_in[7];
  const float* pgbih = (const float*)d_in[8];
  const float* pgbhh = (const float*)d_in[9];
  const float* hgWih = (const float*)d_in[10];
  const float* hgWhh = (const float*)d_in[11];
  const float* hgbih = (const float*)d_in[12];
  const float* hgbhh = (const float*)d_in[13];
  const float* W_s   = (const float*)d_in[14];
  const float* W_t   = (const float*)d_in[15];
  const float* w_e   = (const float*)d_in[16];
  const float* W_m   = (const float*)d_in[17];
  const float* mWih  = (const float*)d_in[18];
  const float* mWhh  = (const float*)d_in[19];
  const float* mbih  = (const float*)d_in[20];
  const float* mbhh  = (const float*)d_in[21];
  const float* outW  = (const float*)d_in[22];
  const float* outb  = (const float*)d_in[23];

  const size_t OB    = (size_t)TSEQ*NB*HID*sizeof(bfraw);
  const size_t RB    = OB;
  const size_t WFB   = (size_t)G3*INDIM*sizeof(bfraw);
  const size_t SQB   = (size_t)HID*HID*sizeof(bfraw);
  const size_t WHHB  = (size_t)G3*HID*sizeof(bfraw);
  const size_t WCATB = (size_t)2048*1536*sizeof(bfraw);
  const size_t BARB  = (size_t)(NWG+8)*FLS*sizeof(unsigned);
  const size_t needed = 2*OB + RB + 2*WFB + 3*SQB + 2*WHHB + WCATB
                        + 8192 + 2*6144
                        + 4*262144 /*hst*/ + 2*262144 /*hmbuf x2*/ + 2*131072 /*hm_bf x2*/
                        + BARB;
  if (ws_size < needed) return;

  char* p = (char*)d_ws;
  bfraw* o_p_bf = (bfraw*)p; p += OB;
  bfraw* o_h_bf = (bfraw*)p; p += OB;
  char*  Rreg   = p;         p += RB;
  bfraw* Wfp_bf = (bfraw*)p; p += WFB;
  bfraw* Wfh_bf = (bfraw*)p; p += WFB;
  bfraw* WsT_bf = (bfraw*)p; p += SQB;
  bfraw* WtT_bf = (bfraw*)p; p += SQB;
  bfraw* WmT_bf = (bfraw*)p; p += SQB;
  bfraw* Whhp_bf= (bfraw*)p; p += WHHB;
  bfraw* Whhh_bf= (bfraw*)p; p += WHHB;
  bfraw* Wcat_bf= (bfraw*)p; p += WCATB;
  float* bc     = (float*)p; p += 8192;
  float* bfp    = (float*)p; p += 6144;
  float* bfh    = (float*)p; p += 6144;
  float* hst    = (float*)p; p += 4*262144;
  float* hmbuf  = (float*)p; p += 2*262144;
  bfraw* hm_bf  = (bfraw*)p; p += 2*131072;
  unsigned* bar = (unsigned*)p; p += BARB;

  bfraw* pWT_bf = (bfraw*)Rreg;
  bfraw* hWT_bf = (bfraw*)(Rreg + (size_t)INDIM*HID*sizeof(bfraw));
  float* GIp_c  = (float*)Rreg;
  float* GIh_c  = (float*)(Rreg + (size_t)CH*NB*G3*sizeof(float));
  bfraw* Whs_bf = (bfraw*)Rreg;
  float* Lpart  = (float*)Wfp_bf;                         // 2 MB overlay (Wf dead)
  bfraw* a_bf   = (bfraw*)((char*)Wfp_bf + 2097152);      // 128 KB

  (void)hipFuncSetAttribute((const void*)scanB, hipFuncAttributeMaxDynamicSharedMemorySize, 131072);
  (void)hipFuncSetAttribute((const void*)scanD, hipFuncAttributeMaxDynamicSharedMemorySize, 153856);

  dim3 b256(256), b512(512);

  init_k<<<dim3(33), b256, 0, stream>>>(bar);
  hminit_k<<<dim3(512), b256, 0, stream>>>(hmbuf, hm_bf);

  // ---- Phase A: weight prep ----
  tconv_k<<<dim3(INDIM/32, HID/32), b256, 0, stream>>>(p_W, pWT_bf, HID, INDIM);
  tconv_k<<<dim3(INDIM/32, HID/32), b256, 0, stream>>>(h_W, hWT_bf, HID, INDIM);
  tconv_k<<<dim3(HID/32, HID/32),  b256, 0, stream>>>(W_s, WsT_bf, HID, HID);
  tconv_k<<<dim3(HID/32, HID/32),  b256, 0, stream>>>(W_t, WtT_bf, HID, HID);
  tconv_k<<<dim3(HID/32, HID/32),  b256, 0, stream>>>(W_m, WmT_bf, HID, HID);
  cvt_k<<<dim3((G3*HID)/1024), b256, 0, stream>>>(pgWhh, Whhp_bf, G3*HID);
  cvt_k<<<dim3((G3*HID)/1024), b256, 0, stream>>>(hgWhh, Whhh_bf, G3*HID);
  wcat_k<<<dim3(3072), b256, 0, stream>>>(mWih, mWhh, Wcat_bf);
  bpack_k<<<dim3(2), b256, 0, stream>>>(mbih, mbhh, bc);
  fuse_bias_k<<<dim3(G3/256), b256, 0, stream>>>(pgWih, pgbih, p_b, bfp);
  fuse_bias_k<<<dim3(G3/256), b256, 0, stream>>>(hgWih, hgbih, h_b, bfh);
  mgemm<float, bfraw, false><<<dim3(INDIM/128, G3/128, 2), b256, 0, stream>>>(
    pgWih, hgWih, pWT_bf, hWT_bf, nullptr, nullptr, Wfp_bf, Wfh_bf,
    HID, HID, HID, INDIM);

  // ---- Phase B: chunked GI GEMM + persistent scan (epochs 1..256) ----
  for (int c = 0; c < TSEQ/CH; ++c){
    mgemm<float, float, true><<<dim3(G3/128, (CH*NB)/128, 2), b256, 0, stream>>>(
      Ep + (size_t)c*CH*NB*INDIM, Eh + (size_t)c*CH*NB*INDIM,
      Wfp_bf, Wfh_bf, bfp, bfh, GIp_c, GIh_c,
      INDIM, INDIM, INDIM, G3);
    scanB<<<dim3(NWG), b512, 131072, stream>>>(
      GIp_c, GIh_c, Whhp_bf, Whhh_bf, pgbhh, hgbhh,
      hst, o_p_bf, o_h_bf, c*CH, bar, (unsigned)(c*CH));
  }

  // ---- Phase C: Whs = o_p @ W_s ----
  mgemm<bfraw, bfraw, false><<<dim3(HID/128, (TSEQ*NB)/128, 1), b256, 0, stream>>>(
    o_p_bf, o_p_bf, WsT_bf, WsT_bf, nullptr, nullptr, Whs_bf, Whs_bf,
    HID, HID, HID, HID);

  // ---- Phase D: persistent scan, 3 barriers/step (epochs 257..1024) ----
  scanD<<<dim3(NWG), b512, 153856, stream>>>(
    Whs_bf, o_p_bf, o_h_bf, WtT_bf, WmT_bf, w_e, Wcat_bf, bc,
    hmbuf, hm_bf, a_bf, Lpart,
    outW, outb, (float*)d_out, bar, (unsigned)TSEQ);
}

// Round 10
// 26896.222 us; speedup vs baseline: 1.1790x; 1.1790x over previous
//
#include <hip/hip_runtime.h>
#include <cstddef>

#define TSEQ 256
#define NB   128
#define HID  512
#define G3   1536
#define INDIM 768
#define CH   16
#define NWG  256
#define FLS  32   // u32 stride between flag lines (128 B)

typedef unsigned short bfraw;
using short8 = __attribute__((ext_vector_type(8))) short;
using f32x4  = __attribute__((ext_vector_type(4))) float;

#define MFMA16 __builtin_amdgcn_mfma_f32_16x16x32_bf16

__device__ __forceinline__ float bf2f(unsigned int u){ return __uint_as_float(u<<16); }
__device__ __forceinline__ bfraw f2bf(float f){
  unsigned int u = __float_as_uint(f);
  u += 0x7fffu + ((u>>16)&1u);
  return (bfraw)(u>>16);
}
__device__ __forceinline__ float fsig(float x){
  return __builtin_amdgcn_rcpf(1.0f + __expf(-x));
}
__device__ __forceinline__ float ftanh(float x){
  return 1.0f - 2.0f*__builtin_amdgcn_rcpf(1.0f + __expf(2.0f*x));
}
// coherence-point (sc1) 16B read — used ONLY for tiny pairwise payloads
__device__ __forceinline__ float4 bpf4(const void* p){
  unsigned long long a = __hip_atomic_load((const unsigned long long*)p,     __ATOMIC_RELAXED, __HIP_MEMORY_SCOPE_AGENT);
  unsigned long long b = __hip_atomic_load((const unsigned long long*)p + 1, __ATOMIC_RELAXED, __HIP_MEMORY_SCOPE_AGENT);
  union{ unsigned long long q[2]; float4 f; } cv; cv.q[0]=a; cv.q[1]=b; return cv.f;
}

// ---- relaxed spin with periodic acquire refresh (r8-validated) ----
__device__ __forceinline__ void spin_ge(unsigned* p, unsigned epoch){
  int sp = 0;
  while (__hip_atomic_load(p, __ATOMIC_RELAXED, __HIP_MEMORY_SCOPE_AGENT) < epoch){
    __builtin_amdgcn_s_sleep(1);
    if (++sp >= 64){
      sp = 0;
      (void)__hip_atomic_load(p, __ATOMIC_ACQUIRE, __HIP_MEMORY_SCOPE_AGENT);
    }
  }
}
// relaxed-only spin (no invalidate) for pairwise flags (payload read via bypass)
__device__ __forceinline__ void spin_ge_rlx(unsigned* p, unsigned epoch){
  while (__hip_atomic_load(p, __ATOMIC_RELAXED, __HIP_MEMORY_SCOPE_AGENT) < epoch)
    __builtin_amdgcn_s_sleep(1);
}

// ---- grid barrier (r8-validated): one acquire per WG at wakeup ----
__device__ __forceinline__ void gbar(unsigned* bar, unsigned epoch){
  __syncthreads();
  const int wg = blockIdx.x;
  const int tid = threadIdx.x;
  if (wg == 0){
    if (tid >= 1 && tid < NWG) spin_ge(&bar[tid*FLS], epoch);
    __syncthreads();
    if (tid == 0){
      (void)__hip_atomic_load(&bar[FLS], __ATOMIC_ACQUIRE, __HIP_MEMORY_SCOPE_AGENT);
    }
    __syncthreads();
    if (tid < 8)
      __hip_atomic_store(&bar[NWG*FLS + tid*FLS], epoch, __ATOMIC_RELEASE, __HIP_MEMORY_SCOPE_AGENT);
    __syncthreads();
  } else {
    if (tid == 0){
      __hip_atomic_store(&bar[wg*FLS], epoch, __ATOMIC_RELEASE, __HIP_MEMORY_SCOPE_AGENT);
      spin_ge(&bar[NWG*FLS + (wg&7)*FLS], epoch);
      (void)__hip_atomic_load(&bar[NWG*FLS + (wg&7)*FLS], __ATOMIC_ACQUIRE, __HIP_MEMORY_SCOPE_AGENT);
    }
    __syncthreads();
  }
}

__global__ void init_k(unsigned* bar){
  int i = blockIdx.x*256 + threadIdx.x;
  if (i < (2*NWG+8)*FLS) bar[i] = 0u;
}

__global__ void hminit_k(float* hmbuf, bfraw* hm_bf){
  int i = blockIdx.x*256 + threadIdx.x;   // 131072 (both slots)
  hmbuf[i] = 1.0f;
  hm_bf[i] = (bfraw)0x3f80;
}

// ---- transpose+convert: in fp32 [R][Cc] -> out bf16 [Cc][R] ----
__global__ __launch_bounds__(256)
void tconv_k(const float* __restrict__ in, bfraw* __restrict__ out, int R, int Cc){
  __shared__ float t[32][33];
  int c0 = blockIdx.x*32, r0 = blockIdx.y*32;
  int tx = threadIdx.x&31, ty = threadIdx.x>>5;
  #pragma unroll
  for (int i=0;i<32;i+=8) t[ty+i][tx] = in[(size_t)(r0+ty+i)*Cc + c0+tx];
  __syncthreads();
  #pragma unroll
  for (int i=0;i<32;i+=8) out[(size_t)(c0+ty+i)*R + r0+tx] = f2bf(t[tx][ty+i]);
}

__global__ void cvt_k(const float* __restrict__ in, bfraw* __restrict__ out, int n){
  int i = (blockIdx.x*256 + threadIdx.x)*4;
  if (i >= n) return;
  float4 v = *(const float4*)(in+i);
  uint2 o;
  o.x = (unsigned)f2bf(v.x) | ((unsigned)f2bf(v.y)<<16);
  o.y = (unsigned)f2bf(v.z) | ((unsigned)f2bf(v.w)<<16);
  *(uint2*)(out+i) = o;
}

// W_cat[n'][k], n'=dd*4+g, k<1536 (segs: a[0,512) x[512,1024) -> mWih; hm[1024,1536) -> mWhh)
__global__ void wcat_k(const float* __restrict__ mWih, const float* __restrict__ mWhh,
                       bfraw* __restrict__ Wcat){
  size_t gid = (size_t)blockIdx.x*256 + threadIdx.x;
  int np = (int)(gid / 384);
  int k4 = ((int)(gid % 384))*4;
  int dd = np>>2, g = np&3;
  float v[4];
  #pragma unroll
  for (int j=0;j<4;++j){
    int k = k4+j; float x = 0.f;
    if (g==0)      x = (k<1024) ? mWih[(size_t)dd*1024 + k]        : mWhh[(size_t)dd*512 + (k-1024)];
    else if (g==1) x = (k<1024) ? mWih[(size_t)(512+dd)*1024 + k]  : mWhh[(size_t)(512+dd)*512 + (k-1024)];
    else if (g==2) x = (k<1024) ? mWih[(size_t)(1024+dd)*1024 + k] : 0.f;
    else           x = (k<1024) ? 0.f : mWhh[(size_t)(1024+dd)*512 + (k-1024)];
    v[j] = x;
  }
  uint2 o;
  o.x = (unsigned)f2bf(v[0]) | ((unsigned)f2bf(v[1])<<16);
  o.y = (unsigned)f2bf(v[2]) | ((unsigned)f2bf(v[3])<<16);
  *(uint2*)(Wcat + (size_t)np*1536 + k4) = o;
}

__global__ void bpack_k(const float* __restrict__ mbih, const float* __restrict__ mbhh,
                        float* __restrict__ bc){
  int dd = blockIdx.x*256 + threadIdx.x;
  if (dd >= 512) return;
  bc[dd]      = mbih[dd] + mbhh[dd];
  bc[512+dd]  = mbih[512+dd] + mbhh[512+dd];
  bc[1024+dd] = mbih[1024+dd];
  bc[1536+dd] = mbhh[1024+dd];
}

__global__ void fuse_bias_k(const float* __restrict__ Wih, const float* __restrict__ bih,
                            const float* __restrict__ pb, float* __restrict__ bout)
{
  int g = blockIdx.x*256 + threadIdx.x;
  if (g >= G3) return;
  float acc = bih[g];
  const float* w = Wih + (size_t)g*HID;
  for (int e=0;e<HID;e+=4){
    float4 wv = *(const float4*)(w+e);
    float4 pv = *(const float4*)(pb+e);
    acc += wv.x*pv.x + wv.y*pv.y + wv.z*pv.z + wv.w*pv.w;
  }
  bout[g] = acc;
}

// ---- MFMA bf16 GEMM: C[MxN] = A[MxK] * B^T (+bias); z selects operand set ----
template<typename TA, typename TC, bool BIAS>
__global__ __launch_bounds__(256)
void mgemm(const TA* __restrict__ A0, const TA* __restrict__ A1,
           const bfraw* __restrict__ B0, const bfraw* __restrict__ B1,
           const float* __restrict__ bias0, const float* __restrict__ bias1,
           TC* __restrict__ C0, TC* __restrict__ C1,
           int K, int lda, int ldb, int ldc)
{
  const TA* A = blockIdx.z ? A1 : A0;
  const bfraw* B = blockIdx.z ? B1 : B0;
  const float* bias = blockIdx.z ? bias1 : bias0;
  TC* C = blockIdx.z ? C1 : C0;
  __shared__ bfraw Al[128*40];
  __shared__ bfraw Bl[128*40];
  const int tid = threadIdx.x;
  const size_t m0 = (size_t)blockIdx.y*128, n0 = (size_t)blockIdx.x*128;
  const int w = tid>>6, l = tid&63;
  const int wr = (w>>1)*64, wc = (w&1)*64;
  const int fr = l&15, fg = l>>4;
  f32x4 acc[4][4];
  #pragma unroll
  for (int i=0;i<4;++i)
    #pragma unroll
    for (int j=0;j<4;++j) acc[i][j] = (f32x4){0.f,0.f,0.f,0.f};

  const int srow = tid>>1, skc = (tid&1)*16;
  for (int k0=0; k0<K; k0+=32){
    if constexpr (sizeof(TA)==4){
      const float* ap = (const float*)A + (m0+srow)*lda + k0 + skc;
      float4 v0=*(const float4*)ap, v1=*(const float4*)(ap+4),
             v2=*(const float4*)(ap+8), v3=*(const float4*)(ap+12);
      uint4 w0, w1;
      w0.x=(unsigned)f2bf(v0.x)|((unsigned)f2bf(v0.y)<<16);
      w0.y=(unsigned)f2bf(v0.z)|((unsigned)f2bf(v0.w)<<16);
      w0.z=(unsigned)f2bf(v1.x)|((unsigned)f2bf(v1.y)<<16);
      w0.w=(unsigned)f2bf(v1.z)|((unsigned)f2bf(v1.w)<<16);
      w1.x=(unsigned)f2bf(v2.x)|((unsigned)f2bf(v2.y)<<16);
      w1.y=(unsigned)f2bf(v2.z)|((unsigned)f2bf(v2.w)<<16);
      w1.z=(unsigned)f2bf(v3.x)|((unsigned)f2bf(v3.y)<<16);
      w1.w=(unsigned)f2bf(v3.z)|((unsigned)f2bf(v3.w)<<16);
      *(uint4*)&Al[srow*40+skc]   = w0;
      *(uint4*)&Al[srow*40+skc+8] = w1;
    } else {
      const bfraw* ap = (const bfraw*)A + (m0+srow)*lda + k0 + skc;
      *(uint4*)&Al[srow*40+skc]   = *(const uint4*)ap;
      *(uint4*)&Al[srow*40+skc+8] = *(const uint4*)(ap+8);
    }
    {
      const bfraw* bp = B + (n0+srow)*ldb + k0 + skc;
      *(uint4*)&Bl[srow*40+skc]   = *(const uint4*)bp;
      *(uint4*)&Bl[srow*40+skc+8] = *(const uint4*)(bp+8);
    }
    __syncthreads();
    short8 af[4], bfr[4];
    #pragma unroll
    for (int i=0;i<4;++i) af[i]  = *(const short8*)&Al[(wr+i*16+fr)*40 + fg*8];
    #pragma unroll
    for (int j=0;j<4;++j) bfr[j] = *(const short8*)&Bl[(wc+j*16+fr)*40 + fg*8];
    #pragma unroll
    for (int i=0;i<4;++i)
      #pragma unroll
      for (int j=0;j<4;++j)
        acc[i][j] = MFMA16(af[i], bfr[j], acc[i][j], 0,0,0);
    __syncthreads();
  }
  #pragma unroll
  for (int i=0;i<4;++i){
    #pragma unroll
    for (int j=0;j<4;++j){
      size_t n = n0 + wc + j*16 + fr;
      float bv = BIAS ? bias[n] : 0.f;
      #pragma unroll
      for (int r=0;r<4;++r){
        size_t m = m0 + wr + i*16 + fg*4 + r;
        float v = acc[i][j][r] + bv;
        if constexpr (sizeof(TC)==2) ((bfraw*)C)[m*ldc + n] = f2bf(v);
        else                         ((float*)C)[m*ldc + n] = v;
      }
    }
  }
}

// ---- Phase B: persistent GRU scan (r8-verbatim) ----
__global__ __launch_bounds__(512, 2)
void scanB(const float* __restrict__ GIp, const float* __restrict__ GIh,
           const bfraw* __restrict__ Whhp, const bfraw* __restrict__ Whhh,
           const float* __restrict__ bhhp, const float* __restrict__ bhhh,
           float* __restrict__ hst, bfraw* __restrict__ o_p, bfraw* __restrict__ o_h,
           int c0, unsigned* __restrict__ bar, unsigned ep0)
{
  extern __shared__ char smem[];
  bfraw* wl = (bfraw*)smem;                  // 98304 B
  float* sh = (float*)(smem + 98304);        // 32768 B
  const int wg = blockIdx.x;
  const int z = wg>>7, rem = wg&127;
  const int bg = rem>>4, dg = rem&15;
  const float* GI  = z ? GIh : GIp;
  const bfraw* Wb  = z ? Whhh : Whhp;
  const float* bhh = z ? bhhh : bhhp;
  bfraw* ob = z ? o_h : o_p;
  float* hz = hst + (size_t)z*2*NB*HID;
  const int tid = threadIdx.x;

  #pragma unroll
  for (int g=0; g<3; ++g){
    const unsigned* src = (const unsigned*)(Wb + (size_t)(g*512 + dg*32)*512);
    for (int j=0; j<16; ++j){
      int iu = tid + j*512;
      unsigned v = src[iu];
      int d = iu>>8, kk = (iu&255)*2;
      int idx0 = g*16384 + (kk>>2)*128 + d*4 + (kk&3);
      *((unsigned*)wl + (idx0>>1)) = v;
    }
  }
  __syncthreads();

  const int bl = tid>>5, dl = tid&31;
  const int d = dg*32+dl, bglob = bg*16+bl;
  const float br = bhh[d], bz = bhh[512+d], bn = bhh[1024+d];

  #pragma clang loop unroll(disable)
  for (int tt=0; tt<CH; ++tt){
    const int t = c0+tt;
    if (t == 0){
      for (int j=0;j<4;++j){
        int i4 = tid + j*512;
        *(float4*)&sh[i4*4] = (float4){1.f,1.f,1.f,1.f};
      }
    } else {
      const float* hp = hz + (size_t)((t-1)&1)*NB*HID + (size_t)bg*16*HID;
      for (int j=0;j<4;++j){
        int i4 = tid + j*512;
        *(float4*)&sh[i4*4] = *(const float4*)&hp[i4*4];
      }
    }
    __syncthreads();
    float ar = br, az = bz, an = bn;
    const float* hb = sh + bl*512;
    for (int k=0;k<512;k+=4){
      float4 h4 = *(const float4*)(hb+k);
      int base = (k>>2)*128 + dl*4;
      uint2 wr = *(const uint2*)(wl + base);
      uint2 wz = *(const uint2*)(wl + 16384 + base);
      uint2 wn = *(const uint2*)(wl + 32768 + base);
      ar += h4.x*bf2f(wr.x&0xffffu) + h4.y*bf2f(wr.x>>16) + h4.z*bf2f(wr.y&0xffffu) + h4.w*bf2f(wr.y>>16);
      az += h4.x*bf2f(wz.x&0xffffu) + h4.y*bf2f(wz.x>>16) + h4.z*bf2f(wz.y&0xffffu) + h4.w*bf2f(wz.y>>16);
      an += h4.x*bf2f(wn.x&0xffffu) + h4.y*bf2f(wn.x>>16) + h4.z*bf2f(wn.y&0xffffu) + h4.w*bf2f(wn.y>>16);
    }
    const float* gi = GI + ((size_t)tt*NB + bglob)*G3;
    float r  = fsig(gi[d] + ar);
    float zz = fsig(gi[512+d] + az);
    float n  = ftanh(gi[1024+d] + r*an);
    float hp = hb[d];
    float hv = (1.0f-zz)*n + zz*hp;
    (hz + (size_t)(t&1)*NB*HID)[(size_t)bglob*HID + d] = hv;
    ob[((size_t)t*NB + bglob)*HID + d] = f2bf(hv);
    gbar(bar, ep0 + (unsigned)tt + 1u);
  }
}

// ---- Phase D: merged-phase scan — 2 grid barriers + 1 pairwise sync per step --
// WG = (b = wg>>1, dh = wg&1). LDS: Whs[all tq, b, dh-half] 128 KB (swizzled).
__global__ __launch_bounds__(512, 2)
void scanD(const bfraw* __restrict__ Whs, const bfraw* __restrict__ o_p,
           const bfraw* __restrict__ o_h,
           const bfraw* __restrict__ WtT, const bfraw* __restrict__ WmT,
           const float* __restrict__ w_e,
           const bfraw* __restrict__ Wcat, const float* __restrict__ bc,
           float* __restrict__ hmbuf, bfraw* __restrict__ hm_bf,
           bfraw* __restrict__ a_bf, float* __restrict__ Lbuf,
           const float* __restrict__ outW, const float* __restrict__ outb,
           float* __restrict__ out, unsigned* __restrict__ bar, unsigned ep0)
{
  extern __shared__ char smem[];
  bfraw* whs_l = (bfraw*)smem;                 // 131072 B
  float* pt    = (float*)(smem + 131072);      // 16384 B [16][256]
  float* xlf   = (float*)(smem + 147456);      // 2048 B  x_t[b] fp32
  float* hml   = (float*)(smem + 149504);      // 2048 B  hm[b] fp32
  float* c_l   = (float*)(smem + 151552);      // 1024 B
  float* we_s  = (float*)(smem + 152576);      // 1024 B
  float* lp0   = (float*)(smem + 153600);      // 1024 B
  float* lp1   = (float*)(smem + 154624);      // 1024 B
  float* l_s   = (float*)(smem + 155648);      // 1024 B
  float* red   = (float*)(smem + 156672);      // 128 B

  const int wg = blockIdx.x, tid = threadIdx.x;
  const int b = wg>>1, dh = wg&1;
  unsigned* pf = bar + (NWG+8)*FLS;            // pairwise flags

  // preload Whs[tq, b, dh-half] with XOR-chunk swizzle (chunk = 16B = 8 bf16)
  for (int it=0; it<16; ++it){
    int idx = tid + it*512;                    // 8192 = 256 tq x 32 chunks
    int tq = idx>>5, c = idx&31;
    const bfraw* src = Whs + ((size_t)tq*NB + b)*HID + dh*256 + c*8;
    *(uint4*)&whs_l[tq*256 + ((c ^ (tq&15))<<3)] = *(const uint4*)src;
  }
  if (tid < 64) *(float4*)&we_s[tid*4] = *(const float4*)(w_e + dh*256 + tid*4);
  __syncthreads();

  #pragma clang loop unroll(disable)
  for (int t=0; t<TSEQ; ++t){
    const int rs = (t+1)&1;
    const bfraw* hmr = hm_bf + (size_t)rs*65536;
    const float* hpr = hmbuf + (size_t)rs*65536;
    bfraw* hmw = hm_bf + (size_t)(t&1)*65536;
    float* hpw = hmbuf + (size_t)(t&1)*65536;

    // ---- stage x_t[b], hm[b] ----
    if (tid < 64){
      uint4 u = *(const uint4*)(o_h + ((size_t)t*NB + b)*HID + tid*8);
      float4 f0, f1;
      f0.x=bf2f(u.x&0xffffu); f0.y=bf2f(u.x>>16); f0.z=bf2f(u.y&0xffffu); f0.w=bf2f(u.y>>16);
      f1.x=bf2f(u.z&0xffffu); f1.y=bf2f(u.z>>16); f1.z=bf2f(u.w&0xffffu); f1.w=bf2f(u.w>>16);
      *(float4*)&xlf[tid*8]   = f0;
      *(float4*)&xlf[tid*8+4] = f1;
    } else if (tid < 192){
      int i2 = tid - 64;
      *(float4*)&hml[i2*4] = *(const float4*)(hpr + (size_t)b*HID + i2*4);
    }
    __syncthreads();

    // ---- c[b, e] for e in dh-half: x@W_t + hm@W_m ----
    {
      const int el = tid>>1, kh = tid&1;
      const bfraw* wt = WtT + (size_t)(dh*256+el)*HID + kh*256;
      const bfraw* wm = WmT + (size_t)(dh*256+el)*HID + kh*256;
      const float* xv = xlf + kh*256;
      const float* hv = hml + kh*256;
      float acc = 0.f;
      #pragma unroll 4
      for (int k8=0;k8<32;++k8){
        uint4 wu = *(const uint4*)(wt+k8*8);
        uint4 mu = *(const uint4*)(wm+k8*8);
        float4 x0 = *(const float4*)(xv+k8*8), x1 = *(const float4*)(xv+k8*8+4);
        float4 h0 = *(const float4*)(hv+k8*8), h1 = *(const float4*)(hv+k8*8+4);
        acc += x0.x*bf2f(wu.x&0xffffu) + x0.y*bf2f(wu.x>>16) + x0.z*bf2f(wu.y&0xffffu) + x0.w*bf2f(wu.y>>16);
        acc += x1.x*bf2f(wu.z&0xffffu) + x1.y*bf2f(wu.z>>16) + x1.z*bf2f(wu.w&0xffffu) + x1.w*bf2f(wu.w>>16);
        acc += h0.x*bf2f(mu.x&0xffffu) + h0.y*bf2f(mu.x>>16) + h0.z*bf2f(mu.y&0xffffu) + h0.w*bf2f(mu.y>>16);
        acc += h1.x*bf2f(mu.z&0xffffu) + h1.y*bf2f(mu.z>>16) + h1.z*bf2f(mu.w&0xffffu) + h1.w*bf2f(mu.w>>16);
      }
      acc += __shfl_xor(acc, 1);
      if (kh == 0) c_l[el] = acc;
    }
    __syncthreads();

    // ---- logit partials over this d-half (from swizzled LDS Whs) ----
    {
      const int tqs = tid>>5, cc = tid&31;
      #pragma unroll 2
      for (int i=0;i<16;++i){
        int tq = tqs + i*16;
        uint4 u = *(const uint4*)&whs_l[tq*256 + ((cc ^ (tq&15))<<3)];
        float s = 0.f;
        #pragma unroll
        for (int j=0;j<4;++j){
          unsigned uu = ((const unsigned*)&u)[j];
          int d0 = cc*8 + j*2;
          s += ftanh(bf2f(uu&0xffffu) + c_l[d0])   * we_s[d0];
          s += ftanh(bf2f(uu>>16)     + c_l[d0+1]) * we_s[d0+1];
        }
        #pragma unroll
        for (int off=16; off; off>>=1) s += __shfl_xor(s, off);
        if (cc == 0) lp0[tq] = s;
      }
    }
    __syncthreads();
    // export partial for buddy + release flag
    if (tid < 64) *(float4*)&Lbuf[(size_t)wg*256 + tid*4] = *(const float4*)&lp0[tid*4];
    __syncthreads();
    if (tid == 0)
      __hip_atomic_store(&pf[wg*FLS], (unsigned)(t+1), __ATOMIC_RELEASE, __HIP_MEMORY_SCOPE_AGENT);

    // ---- issue o_p prefetch (latency hides under pairsync + softmax) ----
    const int dgrp = tid&31, tqs2 = tid>>5, d8 = dgrp*8;
    const bfraw* opb = o_p + (size_t)b*HID + dh*256 + d8;
    uint4 uu[16];
    #pragma unroll
    for (int i=0;i<16;++i)
      uu[i] = *(const uint4*)(opb + (size_t)(tqs2*16 + i)*NB*HID);

    // ---- pairwise sync + read buddy partials (bypass, 1 KB) ----
    if (tid == 0) spin_ge_rlx(&pf[(wg^1)*FLS], (unsigned)(t+1));
    __syncthreads();
    if (tid < 64) *(float4*)&lp1[tid*4] = bpf4(&Lbuf[(size_t)(wg^1)*256 + tid*4]);
    __syncthreads();

    // ---- softmax over 256 logits ----
    {
      const int lane = tid&63;
      float v = -1e30f, e = 0.f;
      if (tid < TSEQ){
        v = lp0[tid] + lp1[tid];
        float m = v;
        #pragma unroll
        for (int off=32; off; off>>=1) m = fmaxf(m, __shfl_xor(m, off));
        if (lane==0) red[tid>>6] = m;
      }
      __syncthreads();
      float mx = fmaxf(fmaxf(red[0],red[1]), fmaxf(red[2],red[3]));
      if (tid < TSEQ){
        e = __expf(v - mx);
        float s2 = e;
        #pragma unroll
        for (int off=32; off; off>>=1) s2 += __shfl_xor(s2, off);
        if (lane==0) red[8+(tid>>6)] = s2;
      }
      __syncthreads();
      float S = red[8]+red[9]+red[10]+red[11];
      if (tid < TSEQ) l_s[tid] = e * __builtin_amdgcn_rcpf(S);
      __syncthreads();
    }

    // ---- consume prefetched o_p -> a_t d-half ----
    {
      float a0=0,a1=0,a2=0,a3=0,a4=0,a5=0,a6=0,a7=0;
      #pragma unroll
      for (int i=0;i<16;++i){
        float al = l_s[tqs2*16 + i];
        uint4 u = uu[i];
        a0 += al*bf2f(u.x&0xffffu); a1 += al*bf2f(u.x>>16);
        a2 += al*bf2f(u.y&0xffffu); a3 += al*bf2f(u.y>>16);
        a4 += al*bf2f(u.z&0xffffu); a5 += al*bf2f(u.z>>16);
        a6 += al*bf2f(u.w&0xffffu); a7 += al*bf2f(u.w>>16);
      }
      *(float4*)&pt[tqs2*256+d8]   = (float4){a0,a1,a2,a3};
      *(float4*)&pt[tqs2*256+d8+4] = (float4){a4,a5,a6,a7};
      __syncthreads();
      if (tid < 256){
        float sA = 0.f;
        #pragma unroll
        for (int ss=0;ss<16;++ss) sA += pt[ss*256 + tid];
        float sB = __shfl_down(sA, 1);
        if ((tid&1)==0){
          unsigned pk = (unsigned)f2bf(sA) | ((unsigned)f2bf(sB)<<16);
          *(unsigned*)(a_bf + (size_t)b*HID + dh*256 + tid) = pk;
        }
      }
    }
    gbar(bar, ep0 + (unsigned)t*2u + 1u);

    // ---- P3: gate MFMA + state update (wg<128, n-slice 16) — r8-verbatim ----
    if (wg < 128){
      const int n0 = wg*16;
      const int w = tid>>6, l = tid&63, fr = l&15, fg = l>>4;
      const int m0w = w*16;
      const bfraw* arow = a_bf + (size_t)(m0w+fr)*HID;
      const bfraw* xrow = o_h + ((size_t)t*NB + m0w+fr)*HID;
      const bfraw* hrow = hmr + (size_t)(m0w+fr)*HID;
      const bfraw* wrow = Wcat + (size_t)(n0+fr)*1536;
      f32x4 accA={0.f,0.f,0.f,0.f}, accB={0.f,0.f,0.f,0.f};
      #pragma unroll
      for (int kk=0; kk<16; ++kk){
        short8 af = *(const short8*)(arow + kk*32 + fg*8);
        short8 bv = *(const short8*)(wrow + kk*32 + fg*8);
        accA = MFMA16(af, bv, accA, 0,0,0);
      }
      #pragma unroll
      for (int kk=0; kk<16; ++kk){
        short8 af = *(const short8*)(xrow + kk*32 + fg*8);
        short8 bv = *(const short8*)(wrow + 512 + kk*32 + fg*8);
        accB = MFMA16(af, bv, accB, 0,0,0);
      }
      #pragma unroll
      for (int kk=0; kk<16; ++kk){
        short8 af = *(const short8*)(hrow + kk*32 + fg*8);
        short8 bv = *(const short8*)(wrow + 1024 + kk*32 + fg*8);
        accA = MFMA16(af, bv, accA, 0,0,0);
      }
      f32x4 acc = accA + accB;
      const int np = n0 + fr, dd = np>>2, g = np&3;
      #pragma unroll
      for (int rr=0; rr<4; ++rr){
        float x0 = acc[rr];
        float x1 = __shfl_xor(x0, 1);
        float x2 = __shfl_xor(x0, 2);
        float x3 = __shfl_xor(x1, 2);
        if (g==0){
          int b3 = m0w + fg*4 + rr;
          float hp = hpr[(size_t)b3*HID + dd];
          float rg = fsig(x0 + bc[dd]);
          float zg = fsig(x1 + bc[512+dd]);
          float gn = ftanh(x2 + bc[1024+dd] + rg*(x3 + bc[1536+dd]));
          float h = (1.f-zg)*gn + zg*hp;
          hpw[(size_t)b3*HID + dd] = h;
          hmw[(size_t)b3*HID + dd] = f2bf(h);
        }
      }
    }
    gbar(bar, ep0 + (unsigned)t*2u + 2u);
  }

  // ---- output head: h_star in slot (TSEQ-1)&1 = 1 ----
  if (wg == 0 && tid < NB*3){
    const float* hf = hmbuf + (size_t)((TSEQ-1)&1)*65536;
    int b2 = tid/3, c = tid%3;
    float acc = outb[c];
    const float* h = hf + (size_t)b2*HID;
    const float* w = outW + (size_t)c*HID;
    for (int d2=0; d2<HID; ++d2) acc = fmaf(h[d2], w[d2], acc);
    out[tid] = fmaxf(acc, 0.f);
  }
}

extern "C" void kernel_launch(void* const* d_in, const int* in_sizes, int n_in,
                              void* d_out, int out_size, void* d_ws, size_t ws_size,
                              hipStream_t stream)
{
  const float* Ep    = (const float*)d_in[0];
  const float* Eh    = (const float*)d_in[1];
  const float* p_W   = (const float*)d_in[2];
  const float* p_b   = (const float*)d_in[3];
  const float* h_W   = (const float*)d_in[4];
  const float* h_b   = (const float*)d_in[5];
  const float* pgWih = (const float*)d_in[6];
  const float* pgWhh = (const float*)d_in[7];
  const float* pgbih = (const float*)d_in[8];
  const float* pgbhh = (const float*)d_in[9];
  const float* hgWih = (const float*)d_in[10];
  const float* hgWhh = (const float*)d_in[11];
  const float* hgbih = (const float*)d_in[12];
  const float* hgbhh = (const float*)d_in[13];
  const float* W_s   = (const float*)d_in[14];
  const float* W_t   = (const float*)d_in[15];
  const float* w_e   = (const float*)d_in[16];
  const float* W_m   = (const float*)d_in[17];
  const float* mWih  = (const float*)d_in[18];
  const float* mWhh  = (const float*)d_in[19];
  const float* mbih  = (const float*)d_in[20];
  const float* mbhh  = (const float*)d_in[21];
  const float* outW  = (const float*)d_in[22];
  const float* outb  = (const float*)d_in[23];

  const size_t OB    = (size_t)TSEQ*NB*HID*sizeof(bfraw);
  const size_t RB    = OB;
  const size_t WFB   = (size_t)G3*INDIM*sizeof(bfraw);
  const size_t SQB   = (size_t)HID*HID*sizeof(bfraw);
  const size_t WHHB  = (size_t)G3*HID*sizeof(bfraw);
  const size_t WCATB = (size_t)2048*1536*sizeof(bfraw);
  const size_t BARB  = (size_t)(2*NWG+8)*FLS*sizeof(unsigned);
  const size_t needed = 2*OB + RB + 2*WFB + 3*SQB + 2*WHHB + WCATB
                        + 8192 + 2*6144
                        + 4*262144 + 2*262144 + 2*131072
                        + BARB;
  if (ws_size < needed) return;

  char* p = (char*)d_ws;
  bfraw* o_p_bf = (bfraw*)p; p += OB;
  bfraw* o_h_bf = (bfraw*)p; p += OB;
  char*  Rreg   = p;         p += RB;
  bfraw* Wfp_bf = (bfraw*)p; p += WFB;
  bfraw* Wfh_bf = (bfraw*)p; p += WFB;
  bfraw* WsT_bf = (bfraw*)p; p += SQB;
  bfraw* WtT_bf = (bfraw*)p; p += SQB;
  bfraw* WmT_bf = (bfraw*)p; p += SQB;
  bfraw* Whhp_bf= (bfraw*)p; p += WHHB;
  bfraw* Whhh_bf= (bfraw*)p; p += WHHB;
  bfraw* Wcat_bf= (bfraw*)p; p += WCATB;
  float* bc     = (float*)p; p += 8192;
  float* bfp    = (float*)p; p += 6144;
  float* bfh    = (float*)p; p += 6144;
  float* hst    = (float*)p; p += 4*262144;
  float* hmbuf  = (float*)p; p += 2*262144;
  bfraw* hm_bf  = (bfraw*)p; p += 2*131072;
  unsigned* bar = (unsigned*)p; p += BARB;

  bfraw* pWT_bf = (bfraw*)Rreg;
  bfraw* hWT_bf = (bfraw*)(Rreg + (size_t)INDIM*HID*sizeof(bfraw));
  float* GIp_c  = (float*)Rreg;
  float* GIh_c  = (float*)(Rreg + (size_t)CH*NB*G3*sizeof(float));
  bfraw* Whs_bf = (bfraw*)Rreg;
  float* Lbuf   = (float*)Wfp_bf;                         // 256 KB overlay (Wf dead in D)
  bfraw* a_bf   = (bfraw*)((char*)Wfp_bf + 2097152);      // 128 KB

  (void)hipFuncSetAttribute((const void*)scanB, hipFuncAttributeMaxDynamicSharedMemorySize, 131072);
  (void)hipFuncSetAttribute((const void*)scanD, hipFuncAttributeMaxDynamicSharedMemorySize, 156800);

  dim3 b256(256), b512(512);

  init_k<<<dim3(65), b256, 0, stream>>>(bar);
  hminit_k<<<dim3(512), b256, 0, stream>>>(hmbuf, hm_bf);

  // ---- Phase A: weight prep ----
  tconv_k<<<dim3(INDIM/32, HID/32), b256, 0, stream>>>(p_W, pWT_bf, HID, INDIM);
  tconv_k<<<dim3(INDIM/32, HID/32), b256, 0, stream>>>(h_W, hWT_bf, HID, INDIM);
  tconv_k<<<dim3(HID/32, HID/32),  b256, 0, stream>>>(W_s, WsT_bf, HID, HID);
  tconv_k<<<dim3(HID/32, HID/32),  b256, 0, stream>>>(W_t, WtT_bf, HID, HID);
  tconv_k<<<dim3(HID/32, HID/32),  b256, 0, stream>>>(W_m, WmT_bf, HID, HID);
  cvt_k<<<dim3((G3*HID)/1024), b256, 0, stream>>>(pgWhh, Whhp_bf, G3*HID);
  cvt_k<<<dim3((G3*HID)/1024), b256, 0, stream>>>(hgWhh, Whhh_bf, G3*HID);
  wcat_k<<<dim3(3072), b256, 0, stream>>>(mWih, mWhh, Wcat_bf);
  bpack_k<<<dim3(2), b256, 0, stream>>>(mbih, mbhh, bc);
  fuse_bias_k<<<dim3(G3/256), b256, 0, stream>>>(pgWih, pgbih, p_b, bfp);
  fuse_bias_k<<<dim3(G3/256), b256, 0, stream>>>(hgWih, hgbih, h_b, bfh);
  mgemm<float, bfraw, false><<<dim3(INDIM/128, G3/128, 2), b256, 0, stream>>>(
    pgWih, hgWih, pWT_bf, hWT_bf, nullptr, nullptr, Wfp_bf, Wfh_bf,
    HID, HID, HID, INDIM);

  // ---- Phase B: chunked GI GEMM + persistent scan (epochs 1..256) ----
  for (int c = 0; c < TSEQ/CH; ++c){
    mgemm<float, float, true><<<dim3(G3/128, (CH*NB)/128, 2), b256, 0, stream>>>(
      Ep + (size_t)c*CH*NB*INDIM, Eh + (size_t)c*CH*NB*INDIM,
      Wfp_bf, Wfh_bf, bfp, bfh, GIp_c, GIh_c,
      INDIM, INDIM, INDIM, G3);
    scanB<<<dim3(NWG), b512, 131072, stream>>>(
      GIp_c, GIh_c, Whhp_bf, Whhh_bf, pgbhh, hgbhh,
      hst, o_p_bf, o_h_bf, c*CH, bar, (unsigned)(c*CH));
  }

  // ---- Phase C: Whs = o_p @ W_s ----
  mgemm<bfraw, bfraw, false><<<dim3(HID/128, (TSEQ*NB)/128, 1), b256, 0, stream>>>(
    o_p_bf, o_p_bf, WsT_bf, WsT_bf, nullptr, nullptr, Whs_bf, Whs_bf,
    HID, HID, HID, HID);

  // ---- Phase D: merged-phase scan, 2 barriers + pairsync (epochs 257..768) ----
  scanD<<<dim3(NWG), b512, 156800, stream>>>(
    Whs_bf, o_p_bf, o_h_bf, WtT_bf, WmT_bf, w_e, Wcat_bf, bc,
    hmbuf, hm_bf, a_bf, Lbuf,
    outW, outb, (float*)d_out, bar, (unsigned)TSEQ);
}

// Round 11
// 24906.239 us; speedup vs baseline: 1.2731x; 1.0799x over previous
//
#include <hip/hip_runtime.h>
#include <cstddef>

#define TSEQ 256
#define NB   128
#define HID  512
#define G3   1536
#define INDIM 768
#define CH   16
#define NWG  256
#define FLS  32   // u32 stride between flag lines (128 B)

typedef unsigned short bfraw;
using short8 = __attribute__((ext_vector_type(8))) short;
using f32x4  = __attribute__((ext_vector_type(4))) float;

#define MFMA16 __builtin_amdgcn_mfma_f32_16x16x32_bf16

__device__ __forceinline__ float bf2f(unsigned int u){ return __uint_as_float(u<<16); }
__device__ __forceinline__ bfraw f2bf(float f){
  unsigned int u = __float_as_uint(f);
  u += 0x7fffu + ((u>>16)&1u);
  return (bfraw)(u>>16);
}
__device__ __forceinline__ float fsig(float x){
  return __builtin_amdgcn_rcpf(1.0f + __expf(-x));
}
__device__ __forceinline__ float ftanh(float x){
  return 1.0f - 2.0f*__builtin_amdgcn_rcpf(1.0f + __expf(2.0f*x));
}
// coherence-point (sc1) 16B read — tiny pairwise payloads only
__device__ __forceinline__ float4 bpf4(const void* p){
  unsigned long long a = __hip_atomic_load((const unsigned long long*)p,     __ATOMIC_RELAXED, __HIP_MEMORY_SCOPE_AGENT);
  unsigned long long b = __hip_atomic_load((const unsigned long long*)p + 1, __ATOMIC_RELAXED, __HIP_MEMORY_SCOPE_AGENT);
  union{ unsigned long long q[2]; float4 f; } cv; cv.q[0]=a; cv.q[1]=b; return cv.f;
}

// ---- pure-relaxed spin: sc1 polls read the coherence point; NO invalidates ----
__device__ __forceinline__ void spin_ge(unsigned* p, unsigned epoch){
  while (__hip_atomic_load(p, __ATOMIC_RELAXED, __HIP_MEMORY_SCOPE_AGENT) < epoch)
    __builtin_amdgcn_s_sleep(1);
}

// ---- grid barrier: relaxed spins, exactly ONE acquire per WG at wakeup ----
__device__ __forceinline__ void gbar(unsigned* bar, unsigned epoch){
  __syncthreads();
  const int wg = blockIdx.x;
  const int tid = threadIdx.x;
  if (wg == 0){
    if (tid >= 1 && tid < NWG) spin_ge(&bar[tid*FLS], epoch);
    __syncthreads();
    if (tid == 0){
      (void)__hip_atomic_load(&bar[FLS], __ATOMIC_ACQUIRE, __HIP_MEMORY_SCOPE_AGENT);
    }
    __syncthreads();
    if (tid < 8)
      __hip_atomic_store(&bar[NWG*FLS + tid*FLS], epoch, __ATOMIC_RELEASE, __HIP_MEMORY_SCOPE_AGENT);
    __syncthreads();
  } else {
    if (tid == 0){
      __hip_atomic_store(&bar[wg*FLS], epoch, __ATOMIC_RELEASE, __HIP_MEMORY_SCOPE_AGENT);
      spin_ge(&bar[NWG*FLS + (wg&7)*FLS], epoch);
      (void)__hip_atomic_load(&bar[NWG*FLS + (wg&7)*FLS], __ATOMIC_ACQUIRE, __HIP_MEMORY_SCOPE_AGENT);
    }
    __syncthreads();
  }
}

__global__ void init_k(unsigned* bar){
  int i = blockIdx.x*256 + threadIdx.x;
  if (i < (2*NWG+8)*FLS) bar[i] = 0u;
}

__global__ void hminit_k(float* hmbuf, bfraw* hm_bf){
  int i = blockIdx.x*256 + threadIdx.x;   // 131072 (both slots)
  hmbuf[i] = 1.0f;
  hm_bf[i] = (bfraw)0x3f80;
}

// ---- transpose+convert: in fp32 [R][Cc] -> out bf16 [Cc][R] ----
__global__ __launch_bounds__(256)
void tconv_k(const float* __restrict__ in, bfraw* __restrict__ out, int R, int Cc){
  __shared__ float t[32][33];
  int c0 = blockIdx.x*32, r0 = blockIdx.y*32;
  int tx = threadIdx.x&31, ty = threadIdx.x>>5;
  #pragma unroll
  for (int i=0;i<32;i+=8) t[ty+i][tx] = in[(size_t)(r0+ty+i)*Cc + c0+tx];
  __syncthreads();
  #pragma unroll
  for (int i=0;i<32;i+=8) out[(size_t)(c0+ty+i)*R + r0+tx] = f2bf(t[tx][ty+i]);
}

__global__ void cvt_k(const float* __restrict__ in, bfraw* __restrict__ out, int n){
  int i = (blockIdx.x*256 + threadIdx.x)*4;
  if (i >= n) return;
  float4 v = *(const float4*)(in+i);
  uint2 o;
  o.x = (unsigned)f2bf(v.x) | ((unsigned)f2bf(v.y)<<16);
  o.y = (unsigned)f2bf(v.z) | ((unsigned)f2bf(v.w)<<16);
  *(uint2*)(out+i) = o;
}

// W_cat[n'][k], n'=dd*4+g, k<1536 (segs: a[0,512) x[512,1024) -> mWih; hm[1024,1536) -> mWhh)
__global__ void wcat_k(const float* __restrict__ mWih, const float* __restrict__ mWhh,
                       bfraw* __restrict__ Wcat){
  size_t gid = (size_t)blockIdx.x*256 + threadIdx.x;
  int np = (int)(gid / 384);
  int k4 = ((int)(gid % 384))*4;
  int dd = np>>2, g = np&3;
  float v[4];
  #pragma unroll
  for (int j=0;j<4;++j){
    int k = k4+j; float x = 0.f;
    if (g==0)      x = (k<1024) ? mWih[(size_t)dd*1024 + k]        : mWhh[(size_t)dd*512 + (k-1024)];
    else if (g==1) x = (k<1024) ? mWih[(size_t)(512+dd)*1024 + k]  : mWhh[(size_t)(512+dd)*512 + (k-1024)];
    else if (g==2) x = (k<1024) ? mWih[(size_t)(1024+dd)*1024 + k] : 0.f;
    else           x = (k<1024) ? 0.f : mWhh[(size_t)(1024+dd)*512 + (k-1024)];
    v[j] = x;
  }
  uint2 o;
  o.x = (unsigned)f2bf(v[0]) | ((unsigned)f2bf(v[1])<<16);
  o.y = (unsigned)f2bf(v[2]) | ((unsigned)f2bf(v[3])<<16);
  *(uint2*)(Wcat + (size_t)np*1536 + k4) = o;
}

__global__ void bpack_k(const float* __restrict__ mbih, const float* __restrict__ mbhh,
                        float* __restrict__ bc){
  int dd = blockIdx.x*256 + threadIdx.x;
  if (dd >= 512) return;
  bc[dd]      = mbih[dd] + mbhh[dd];
  bc[512+dd]  = mbih[512+dd] + mbhh[512+dd];
  bc[1024+dd] = mbih[1024+dd];
  bc[1536+dd] = mbhh[1024+dd];
}

__global__ void fuse_bias_k(const float* __restrict__ Wih, const float* __restrict__ bih,
                            const float* __restrict__ pb, float* __restrict__ bout)
{
  int g = blockIdx.x*256 + threadIdx.x;
  if (g >= G3) return;
  float acc = bih[g];
  const float* w = Wih + (size_t)g*HID;
  for (int e=0;e<HID;e+=4){
    float4 wv = *(const float4*)(w+e);
    float4 pv = *(const float4*)(pb+e);
    acc += wv.x*pv.x + wv.y*pv.y + wv.z*pv.z + wv.w*pv.w;
  }
  bout[g] = acc;
}

// ---- MFMA bf16 GEMM: C[MxN] = A[MxK] * B^T (+bias); z selects operand set ----
template<typename TA, typename TC, bool BIAS>
__global__ __launch_bounds__(256)
void mgemm(const TA* __restrict__ A0, const TA* __restrict__ A1,
           const bfraw* __restrict__ B0, const bfraw* __restrict__ B1,
           const float* __restrict__ bias0, const float* __restrict__ bias1,
           TC* __restrict__ C0, TC* __restrict__ C1,
           int K, int lda, int ldb, int ldc)
{
  const TA* A = blockIdx.z ? A1 : A0;
  const bfraw* B = blockIdx.z ? B1 : B0;
  const float* bias = blockIdx.z ? bias1 : bias0;
  TC* C = blockIdx.z ? C1 : C0;
  __shared__ bfraw Al[128*40];
  __shared__ bfraw Bl[128*40];
  const int tid = threadIdx.x;
  const size_t m0 = (size_t)blockIdx.y*128, n0 = (size_t)blockIdx.x*128;
  const int w = tid>>6, l = tid&63;
  const int wr = (w>>1)*64, wc = (w&1)*64;
  const int fr = l&15, fg = l>>4;
  f32x4 acc[4][4];
  #pragma unroll
  for (int i=0;i<4;++i)
    #pragma unroll
    for (int j=0;j<4;++j) acc[i][j] = (f32x4){0.f,0.f,0.f,0.f};

  const int srow = tid>>1, skc = (tid&1)*16;
  for (int k0=0; k0<K; k0+=32){
    if constexpr (sizeof(TA)==4){
      const float* ap = (const float*)A + (m0+srow)*lda + k0 + skc;
      float4 v0=*(const float4*)ap, v1=*(const float4*)(ap+4),
             v2=*(const float4*)(ap+8), v3=*(const float4*)(ap+12);
      uint4 w0, w1;
      w0.x=(unsigned)f2bf(v0.x)|((unsigned)f2bf(v0.y)<<16);
      w0.y=(unsigned)f2bf(v0.z)|((unsigned)f2bf(v0.w)<<16);
      w0.z=(unsigned)f2bf(v1.x)|((unsigned)f2bf(v1.y)<<16);
      w0.w=(unsigned)f2bf(v1.z)|((unsigned)f2bf(v1.w)<<16);
      w1.x=(unsigned)f2bf(v2.x)|((unsigned)f2bf(v2.y)<<16);
      w1.y=(unsigned)f2bf(v2.z)|((unsigned)f2bf(v2.w)<<16);
      w1.z=(unsigned)f2bf(v3.x)|((unsigned)f2bf(v3.y)<<16);
      w1.w=(unsigned)f2bf(v3.z)|((unsigned)f2bf(v3.w)<<16);
      *(uint4*)&Al[srow*40+skc]   = w0;
      *(uint4*)&Al[srow*40+skc+8] = w1;
    } else {
      const bfraw* ap = (const bfraw*)A + (m0+srow)*lda + k0 + skc;
      *(uint4*)&Al[srow*40+skc]   = *(const uint4*)ap;
      *(uint4*)&Al[srow*40+skc+8] = *(const uint4*)(ap+8);
    }
    {
      const bfraw* bp = B + (n0+srow)*ldb + k0 + skc;
      *(uint4*)&Bl[srow*40+skc]   = *(const uint4*)bp;
      *(uint4*)&Bl[srow*40+skc+8] = *(const uint4*)(bp+8);
    }
    __syncthreads();
    short8 af[4], bfr[4];
    #pragma unroll
    for (int i=0;i<4;++i) af[i]  = *(const short8*)&Al[(wr+i*16+fr)*40 + fg*8];
    #pragma unroll
    for (int j=0;j<4;++j) bfr[j] = *(const short8*)&Bl[(wc+j*16+fr)*40 + fg*8];
    #pragma unroll
    for (int i=0;i<4;++i)
      #pragma unroll
      for (int j=0;j<4;++j)
        acc[i][j] = MFMA16(af[i], bfr[j], acc[i][j], 0,0,0);
    __syncthreads();
  }
  #pragma unroll
  for (int i=0;i<4;++i){
    #pragma unroll
    for (int j=0;j<4;++j){
      size_t n = n0 + wc + j*16 + fr;
      float bv = BIAS ? bias[n] : 0.f;
      #pragma unroll
      for (int r=0;r<4;++r){
        size_t m = m0 + wr + i*16 + fg*4 + r;
        float v = acc[i][j][r] + bv;
        if constexpr (sizeof(TC)==2) ((bfraw*)C)[m*ldc + n] = f2bf(v);
        else                         ((float*)C)[m*ldc + n] = v;
      }
    }
  }
}

// ---- Phase B: persistent GRU scan (r8-verbatim, relaxed-spin barrier) ----
__global__ __launch_bounds__(512, 2)
void scanB(const float* __restrict__ GIp, const float* __restrict__ GIh,
           const bfraw* __restrict__ Whhp, const bfraw* __restrict__ Whhh,
           const float* __restrict__ bhhp, const float* __restrict__ bhhh,
           float* __restrict__ hst, bfraw* __restrict__ o_p, bfraw* __restrict__ o_h,
           int c0, unsigned* __restrict__ bar, unsigned ep0)
{
  extern __shared__ char smem[];
  bfraw* wl = (bfraw*)smem;                  // 98304 B
  float* sh = (float*)(smem + 98304);        // 32768 B
  const int wg = blockIdx.x;
  const int z = wg>>7, rem = wg&127;
  const int bg = rem>>4, dg = rem&15;
  const float* GI  = z ? GIh : GIp;
  const bfraw* Wb  = z ? Whhh : Whhp;
  const float* bhh = z ? bhhh : bhhp;
  bfraw* ob = z ? o_h : o_p;
  float* hz = hst + (size_t)z*2*NB*HID;
  const int tid = threadIdx.x;

  #pragma unroll
  for (int g=0; g<3; ++g){
    const unsigned* src = (const unsigned*)(Wb + (size_t)(g*512 + dg*32)*512);
    for (int j=0; j<16; ++j){
      int iu = tid + j*512;
      unsigned v = src[iu];
      int d = iu>>8, kk = (iu&255)*2;
      int idx0 = g*16384 + (kk>>2)*128 + d*4 + (kk&3);
      *((unsigned*)wl + (idx0>>1)) = v;
    }
  }
  __syncthreads();

  const int bl = tid>>5, dl = tid&31;
  const int d = dg*32+dl, bglob = bg*16+bl;
  const float br = bhh[d], bz = bhh[512+d], bn = bhh[1024+d];

  #pragma clang loop unroll(disable)
  for (int tt=0; tt<CH; ++tt){
    const int t = c0+tt;
    if (t == 0){
      for (int j=0;j<4;++j){
        int i4 = tid + j*512;
        *(float4*)&sh[i4*4] = (float4){1.f,1.f,1.f,1.f};
      }
    } else {
      const float* hp = hz + (size_t)((t-1)&1)*NB*HID + (size_t)bg*16*HID;
      for (int j=0;j<4;++j){
        int i4 = tid + j*512;
        *(float4*)&sh[i4*4] = *(const float4*)&hp[i4*4];
      }
    }
    __syncthreads();
    float ar = br, az = bz, an = bn;
    const float* hb = sh + bl*512;
    for (int k=0;k<512;k+=4){
      float4 h4 = *(const float4*)(hb+k);
      int base = (k>>2)*128 + dl*4;
      uint2 wr = *(const uint2*)(wl + base);
      uint2 wz = *(const uint2*)(wl + 16384 + base);
      uint2 wn = *(const uint2*)(wl + 32768 + base);
      ar += h4.x*bf2f(wr.x&0xffffu) + h4.y*bf2f(wr.x>>16) + h4.z*bf2f(wr.y&0xffffu) + h4.w*bf2f(wr.y>>16);
      az += h4.x*bf2f(wz.x&0xffffu) + h4.y*bf2f(wz.x>>16) + h4.z*bf2f(wz.y&0xffffu) + h4.w*bf2f(wz.y>>16);
      an += h4.x*bf2f(wn.x&0xffffu) + h4.y*bf2f(wn.x>>16) + h4.z*bf2f(wn.y&0xffffu) + h4.w*bf2f(wn.y>>16);
    }
    const float* gi = GI + ((size_t)tt*NB + bglob)*G3;
    float r  = fsig(gi[d] + ar);
    float zz = fsig(gi[512+d] + az);
    float n  = ftanh(gi[1024+d] + r*an);
    float hp = hb[d];
    float hv = (1.0f-zz)*n + zz*hp;
    (hz + (size_t)(t&1)*NB*HID)[(size_t)bglob*HID + d] = hv;
    ob[((size_t)t*NB + bglob)*HID + d] = f2bf(hv);
    gbar(bar, ep0 + (unsigned)tt + 1u);
  }
}

// ---- Phase D: merged-phase scan — 2 grid barriers + 1 pairwise sync per step --
// WG = (b = wg>>1, dh = wg&1). LDS: Whs[all tq, b, dh-half] 128 KB (swizzled).
__global__ __launch_bounds__(512, 2)
void scanD(const bfraw* __restrict__ Whs, const bfraw* __restrict__ o_p,
           const bfraw* __restrict__ o_h,
           const bfraw* __restrict__ WtT, const bfraw* __restrict__ WmT,
           const float* __restrict__ w_e,
           const bfraw* __restrict__ Wcat, const float* __restrict__ bc,
           float* __restrict__ hmbuf, bfraw* __restrict__ hm_bf,
           bfraw* __restrict__ a_bf, float* __restrict__ Lbuf,
           const float* __restrict__ outW, const float* __restrict__ outb,
           float* __restrict__ out, unsigned* __restrict__ bar, unsigned ep0)
{
  extern __shared__ char smem[];
  bfraw* whs_l = (bfraw*)smem;                 // 131072 B
  float* pt    = (float*)(smem + 131072);      // 16384 B [16][256]
  float* xlf   = (float*)(smem + 147456);      // 2048 B  x_t[b] fp32
  float* hml   = (float*)(smem + 149504);      // 2048 B  hm[b] fp32
  float* c_l   = (float*)(smem + 151552);      // 1024 B
  float* lp0   = (float*)(smem + 152576);      // 1024 B
  float* lp1   = (float*)(smem + 153600);      // 1024 B
  float* l_s   = (float*)(smem + 154624);      // 1024 B
  float* red   = (float*)(smem + 155648);      // 128 B

  const int wg = blockIdx.x, tid = threadIdx.x;
  const int b = wg>>1, dh = wg&1;
  unsigned* pf = bar + (NWG+8)*FLS;            // pairwise flags

  // preload Whs[tq, b, dh-half] with XOR-chunk swizzle (chunk = 16B = 8 bf16)
  for (int it=0; it<16; ++it){
    int idx = tid + it*512;                    // 8192 = 256 tq x 32 chunks
    int tq = idx>>5, c = idx&31;
    const bfraw* src = Whs + ((size_t)tq*NB + b)*HID + dh*256 + c*8;
    *(uint4*)&whs_l[tq*256 + ((c ^ (tq&15))<<3)] = *(const uint4*)src;
  }
  // per-thread w_e registers (logit d-slice is fixed per thread: cc*8..cc*8+8)
  const int cc_ = tid&31;
  float we8[8];
  #pragma unroll
  for (int r=0;r<8;++r) we8[r] = w_e[dh*256 + cc_*8 + r];
  __syncthreads();

  #pragma clang loop unroll(disable)
  for (int t=0; t<TSEQ; ++t){
    const int rs = (t+1)&1;
    const bfraw* hmr = hm_bf + (size_t)rs*65536;
    const float* hpr = hmbuf + (size_t)rs*65536;
    bfraw* hmw = hm_bf + (size_t)(t&1)*65536;
    float* hpw = hmbuf + (size_t)(t&1)*65536;

    // ---- stage x_t[b], hm[b] ----
    if (tid < 64){
      uint4 u = *(const uint4*)(o_h + ((size_t)t*NB + b)*HID + tid*8);
      float4 f0, f1;
      f0.x=bf2f(u.x&0xffffu); f0.y=bf2f(u.x>>16); f0.z=bf2f(u.y&0xffffu); f0.w=bf2f(u.y>>16);
      f1.x=bf2f(u.z&0xffffu); f1.y=bf2f(u.z>>16); f1.z=bf2f(u.w&0xffffu); f1.w=bf2f(u.w>>16);
      *(float4*)&xlf[tid*8]   = f0;
      *(float4*)&xlf[tid*8+4] = f1;
    } else if (tid < 192){
      int i2 = tid - 64;
      *(float4*)&hml[i2*4] = *(const float4*)(hpr + (size_t)b*HID + i2*4);
    }
    __syncthreads();

    // ---- c[b, e] for e in dh-half: x@W_t + hm@W_m ----
    {
      const int el = tid>>1, kh = tid&1;
      const bfraw* wt = WtT + (size_t)(dh*256+el)*HID + kh*256;
      const bfraw* wm = WmT + (size_t)(dh*256+el)*HID + kh*256;
      const float* xv = xlf + kh*256;
      const float* hv = hml + kh*256;
      float acc = 0.f;
      #pragma unroll 4
      for (int k8=0;k8<32;++k8){
        uint4 wu = *(const uint4*)(wt+k8*8);
        uint4 mu = *(const uint4*)(wm+k8*8);
        float4 x0 = *(const float4*)(xv+k8*8), x1 = *(const float4*)(xv+k8*8+4);
        float4 h0 = *(const float4*)(hv+k8*8), h1 = *(const float4*)(hv+k8*8+4);
        acc += x0.x*bf2f(wu.x&0xffffu) + x0.y*bf2f(wu.x>>16) + x0.z*bf2f(wu.y&0xffffu) + x0.w*bf2f(wu.y>>16);
        acc += x1.x*bf2f(wu.z&0xffffu) + x1.y*bf2f(wu.z>>16) + x1.z*bf2f(wu.w&0xffffu) + x1.w*bf2f(wu.w>>16);
        acc += h0.x*bf2f(mu.x&0xffffu) + h0.y*bf2f(mu.x>>16) + h0.z*bf2f(mu.y&0xffffu) + h0.w*bf2f(mu.y>>16);
        acc += h1.x*bf2f(mu.z&0xffffu) + h1.y*bf2f(mu.z>>16) + h1.z*bf2f(mu.w&0xffffu) + h1.w*bf2f(mu.w>>16);
      }
      acc += __shfl_xor(acc, 1);
      if (kh == 0) c_l[el] = acc;
    }
    __syncthreads();

    // ---- logit partials over this d-half (register c/we; LDS only for Whs) ----
    {
      const int tqs = tid>>5;
      float c8[8];
      *(float4*)&c8[0] = *(const float4*)&c_l[cc_*8];
      *(float4*)&c8[4] = *(const float4*)&c_l[cc_*8+4];
      #pragma unroll 2
      for (int i=0;i<16;++i){
        int tq = tqs + i*16;
        uint4 u = *(const uint4*)&whs_l[tq*256 + ((cc_ ^ (tq&15))<<3)];
        float s = 0.f;
        #pragma unroll
        for (int j=0;j<4;++j){
          unsigned uu = ((const unsigned*)&u)[j];
          s += ftanh(bf2f(uu&0xffffu) + c8[j*2])   * we8[j*2];
          s += ftanh(bf2f(uu>>16)     + c8[j*2+1]) * we8[j*2+1];
        }
        #pragma unroll
        for (int off=16; off; off>>=1) s += __shfl_xor(s, off);
        if (cc_ == 0) lp0[tq] = s;
      }
    }
    __syncthreads();
    // export partial for buddy + release flag
    if (tid < 64) *(float4*)&Lbuf[(size_t)wg*256 + tid*4] = *(const float4*)&lp0[tid*4];
    __syncthreads();
    if (tid == 0)
      __hip_atomic_store(&pf[wg*FLS], (unsigned)(t+1), __ATOMIC_RELEASE, __HIP_MEMORY_SCOPE_AGENT);

    // ---- issue o_p prefetch (latency hides under pairsync + softmax) ----
    const int dgrp = tid&31, tqs2 = tid>>5, d8 = dgrp*8;
    const bfraw* opb = o_p + (size_t)b*HID + dh*256 + d8;
    uint4 uu[16];
    #pragma unroll
    for (int i=0;i<16;++i)
      uu[i] = *(const uint4*)(opb + (size_t)(tqs2*16 + i)*NB*HID);

    // ---- pairwise sync + read buddy partials (bypass, 1 KB) ----
    if (tid == 0) spin_ge(&pf[(wg^1)*FLS], (unsigned)(t+1));
    __syncthreads();
    if (tid < 64) *(float4*)&lp1[tid*4] = bpf4(&Lbuf[(size_t)(wg^1)*256 + tid*4]);
    __syncthreads();

    // ---- softmax over 256 logits ----
    {
      const int lane = tid&63;
      float v = -1e30f, e = 0.f;
      if (tid < TSEQ){
        v = lp0[tid] + lp1[tid];
        float m = v;
        #pragma unroll
        for (int off=32; off; off>>=1) m = fmaxf(m, __shfl_xor(m, off));
        if (lane==0) red[tid>>6] = m;
      }
      __syncthreads();
      float mx = fmaxf(fmaxf(red[0],red[1]), fmaxf(red[2],red[3]));
      if (tid < TSEQ){
        e = __expf(v - mx);
        float s2 = e;
        #pragma unroll
        for (int off=32; off; off>>=1) s2 += __shfl_xor(s2, off);
        if (lane==0) red[8+(tid>>6)] = s2;
      }
      __syncthreads();
      float S = red[8]+red[9]+red[10]+red[11];
      if (tid < TSEQ) l_s[tid] = e * __builtin_amdgcn_rcpf(S);
      __syncthreads();
    }

    // ---- consume prefetched o_p -> a_t d-half ----
    {
      float a0=0,a1=0,a2=0,a3=0,a4=0,a5=0,a6=0,a7=0;
      #pragma unroll
      for (int i=0;i<16;++i){
        float al = l_s[tqs2*16 + i];
        uint4 u = uu[i];
        a0 += al*bf2f(u.x&0xffffu); a1 += al*bf2f(u.x>>16);
        a2 += al*bf2f(u.y&0xffffu); a3 += al*bf2f(u.y>>16);
        a4 += al*bf2f(u.z&0xffffu); a5 += al*bf2f(u.z>>16);
        a6 += al*bf2f(u.w&0xffffu); a7 += al*bf2f(u.w>>16);
      }
      *(float4*)&pt[tqs2*256+d8]   = (float4){a0,a1,a2,a3};
      *(float4*)&pt[tqs2*256+d8+4] = (float4){a4,a5,a6,a7};
      __syncthreads();
      if (tid < 256){
        float sA = 0.f;
        #pragma unroll
        for (int ss=0;ss<16;++ss) sA += pt[ss*256 + tid];
        float sB = __shfl_down(sA, 1);
        if ((tid&1)==0){
          unsigned pk = (unsigned)f2bf(sA) | ((unsigned)f2bf(sB)<<16);
          *(unsigned*)(a_bf + (size_t)b*HID + dh*256 + tid) = pk;
        }
      }
    }
    gbar(bar, ep0 + (unsigned)t*2u + 1u);

    // ---- P3: gate MFMA + state update (wg<128, n-slice 16) ----
    if (wg < 128){
      const int n0 = wg*16;
      const int w = tid>>6, l = tid&63, fr = l&15, fg = l>>4;
      const int m0w = w*16;
      const bfraw* arow = a_bf + (size_t)(m0w+fr)*HID;
      const bfraw* xrow = o_h + ((size_t)t*NB + m0w+fr)*HID;
      const bfraw* hrow = hmr + (size_t)(m0w+fr)*HID;
      const bfraw* wrow = Wcat + (size_t)(n0+fr)*1536;
      f32x4 accA={0.f,0.f,0.f,0.f}, accB={0.f,0.f,0.f,0.f};
      #pragma unroll
      for (int kk=0; kk<16; ++kk){
        short8 af = *(const short8*)(arow + kk*32 + fg*8);
        short8 bv = *(const short8*)(wrow + kk*32 + fg*8);
        accA = MFMA16(af, bv, accA, 0,0,0);
      }
      #pragma unroll
      for (int kk=0; kk<16; ++kk){
        short8 af = *(const short8*)(xrow + kk*32 + fg*8);
        short8 bv = *(const short8*)(wrow + 512 + kk*32 + fg*8);
        accB = MFMA16(af, bv, accB, 0,0,0);
      }
      #pragma unroll
      for (int kk=0; kk<16; ++kk){
        short8 af = *(const short8*)(hrow + kk*32 + fg*8);
        short8 bv = *(const short8*)(wrow + 1024 + kk*32 + fg*8);
        accA = MFMA16(af, bv, accA, 0,0,0);
      }
      f32x4 acc = accA + accB;
      const int np = n0 + fr, dd = np>>2, g = np&3;
      #pragma unroll
      for (int rr=0; rr<4; ++rr){
        float x0 = acc[rr];
        float x1 = __shfl_xor(x0, 1);
        float x2 = __shfl_xor(x0, 2);
        float x3 = __shfl_xor(x1, 2);
        if (g==0){
          int b3 = m0w + fg*4 + rr;
          float hp = hpr[(size_t)b3*HID + dd];
          float rg = fsig(x0 + bc[dd]);
          float zg = fsig(x1 + bc[512+dd]);
          float gn = ftanh(x2 + bc[1024+dd] + rg*(x3 + bc[1536+dd]));
          float h = (1.f-zg)*gn + zg*hp;
          hpw[(size_t)b3*HID + dd] = h;
          hmw[(size_t)b3*HID + dd] = f2bf(h);
        }
      }
    }
    gbar(bar, ep0 + (unsigned)t*2u + 2u);
  }

  // ---- output head: h_star in slot (TSEQ-1)&1 = 1 ----
  if (wg == 0 && tid < NB*3){
    const float* hf = hmbuf + (size_t)((TSEQ-1)&1)*65536;
    int b2 = tid/3, c = tid%3;
    float acc = outb[c];
    const float* h = hf + (size_t)b2*HID;
    const float* w = outW + (size_t)c*HID;
    for (int d2=0; d2<HID; ++d2) acc = fmaf(h[d2], w[d2], acc);
    out[tid] = fmaxf(acc, 0.f);
  }
}

extern "C" void kernel_launch(void* const* d_in, const int* in_sizes, int n_in,
                              void* d_out, int out_size, void* d_ws, size_t ws_size,
                              hipStream_t stream)
{
  const float* Ep    = (const float*)d_in[0];
  const float* Eh    = (const float*)d_in[1];
  const float* p_W   = (const float*)d_in[2];
  const float* p_b   = (const float*)d_in[3];
  const float* h_W   = (const float*)d_in[4];
  const float* h_b   = (const float*)d_in[5];
  const float* pgWih = (const float*)d_in[6];
  const float* pgWhh = (const float*)d_in[7];
  const float* pgbih = (const float*)d_in[8];
  const float* pgbhh = (const float*)d_in[9];
  const float* hgWih = (const float*)d_in[10];
  const float* hgWhh = (const float*)d_in[11];
  const float* hgbih = (const float*)d_in[12];
  const float* hgbhh = (const float*)d_in[13];
  const float* W_s   = (const float*)d_in[14];
  const float* W_t   = (const float*)d_in[15];
  const float* w_e   = (const float*)d_in[16];
  const float* W_m   = (const float*)d_in[17];
  const float* mWih  = (const float*)d_in[18];
  const float* mWhh  = (const float*)d_in[19];
  const float* mbih  = (const float*)d_in[20];
  const float* mbhh  = (const float*)d_in[21];
  const float* outW  = (const float*)d_in[22];
  const float* outb  = (const float*)d_in[23];

  const size_t OB    = (size_t)TSEQ*NB*HID*sizeof(bfraw);
  const size_t RB    = OB;
  const size_t WFB   = (size_t)G3*INDIM*sizeof(bfraw);
  const size_t SQB   = (size_t)HID*HID*sizeof(bfraw);
  const size_t WHHB  = (size_t)G3*HID*sizeof(bfraw);
  const size_t WCATB = (size_t)2048*1536*sizeof(bfraw);
  const size_t BARB  = (size_t)(2*NWG+8)*FLS*sizeof(unsigned);
  const size_t needed = 2*OB + RB + 2*WFB + 3*SQB + 2*WHHB + WCATB
                        + 8192 + 2*6144
                        + 4*262144 + 2*262144 + 2*131072
                        + BARB;
  if (ws_size < needed) return;

  char* p = (char*)d_ws;
  bfraw* o_p_bf = (bfraw*)p; p += OB;
  bfraw* o_h_bf = (bfraw*)p; p += OB;
  char*  Rreg   = p;         p += RB;
  bfraw* Wfp_bf = (bfraw*)p; p += WFB;
  bfraw* Wfh_bf = (bfraw*)p; p += WFB;
  bfraw* WsT_bf = (bfraw*)p; p += SQB;
  bfraw* WtT_bf = (bfraw*)p; p += SQB;
  bfraw* WmT_bf = (bfraw*)p; p += SQB;
  bfraw* Whhp_bf= (bfraw*)p; p += WHHB;
  bfraw* Whhh_bf= (bfraw*)p; p += WHHB;
  bfraw* Wcat_bf= (bfraw*)p; p += WCATB;
  float* bc     = (float*)p; p += 8192;
  float* bfp    = (float*)p; p += 6144;
  float* bfh    = (float*)p; p += 6144;
  float* hst    = (float*)p; p += 4*262144;
  float* hmbuf  = (float*)p; p += 2*262144;
  bfraw* hm_bf  = (bfraw*)p; p += 2*131072;
  unsigned* bar = (unsigned*)p; p += BARB;

  bfraw* pWT_bf = (bfraw*)Rreg;
  bfraw* hWT_bf = (bfraw*)(Rreg + (size_t)INDIM*HID*sizeof(bfraw));
  float* GIp_c  = (float*)Rreg;
  float* GIh_c  = (float*)(Rreg + (size_t)CH*NB*G3*sizeof(float));
  bfraw* Whs_bf = (bfraw*)Rreg;
  float* Lbuf   = (float*)Wfp_bf;                         // 256 KB overlay (Wf dead in D)
  bfraw* a_bf   = (bfraw*)((char*)Wfp_bf + 2097152);      // 128 KB

  (void)hipFuncSetAttribute((const void*)scanB, hipFuncAttributeMaxDynamicSharedMemorySize, 131072);
  (void)hipFuncSetAttribute((const void*)scanD, hipFuncAttributeMaxDynamicSharedMemorySize, 155776);

  dim3 b256(256), b512(512);

  init_k<<<dim3(65), b256, 0, stream>>>(bar);
  hminit_k<<<dim3(512), b256, 0, stream>>>(hmbuf, hm_bf);

  // ---- Phase A: weight prep ----
  tconv_k<<<dim3(INDIM/32, HID/32), b256, 0, stream>>>(p_W, pWT_bf, HID, INDIM);
  tconv_k<<<dim3(INDIM/32, HID/32), b256, 0, stream>>>(h_W, hWT_bf, HID, INDIM);
  tconv_k<<<dim3(HID/32, HID/32),  b256, 0, stream>>>(W_s, WsT_bf, HID, HID);
  tconv_k<<<dim3(HID/32, HID/32),  b256, 0, stream>>>(W_t, WtT_bf, HID, HID);
  tconv_k<<<dim3(HID/32, HID/32),  b256, 0, stream>>>(W_m, WmT_bf, HID, HID);
  cvt_k<<<dim3((G3*HID)/1024), b256, 0, stream>>>(pgWhh, Whhp_bf, G3*HID);
  cvt_k<<<dim3((G3*HID)/1024), b256, 0, stream>>>(hgWhh, Whhh_bf, G3*HID);
  wcat_k<<<dim3(3072), b256, 0, stream>>>(mWih, mWhh, Wcat_bf);
  bpack_k<<<dim3(2), b256, 0, stream>>>(mbih, mbhh, bc);
  fuse_bias_k<<<dim3(G3/256), b256, 0, stream>>>(pgWih, pgbih, p_b, bfp);
  fuse_bias_k<<<dim3(G3/256), b256, 0, stream>>>(hgWih, hgbih, h_b, bfh);
  mgemm<float, bfraw, false><<<dim3(INDIM/128, G3/128, 2), b256, 0, stream>>>(
    pgWih, hgWih, pWT_bf, hWT_bf, nullptr, nullptr, Wfp_bf, Wfh_bf,
    HID, HID, HID, INDIM);

  // ---- Phase B: chunked GI GEMM + persistent scan (epochs 1..256) ----
  for (int c = 0; c < TSEQ/CH; ++c){
    mgemm<float, float, true><<<dim3(G3/128, (CH*NB)/128, 2), b256, 0, stream>>>(
      Ep + (size_t)c*CH*NB*INDIM, Eh + (size_t)c*CH*NB*INDIM,
      Wfp_bf, Wfh_bf, bfp, bfh, GIp_c, GIh_c,
      INDIM, INDIM, INDIM, G3);
    scanB<<<dim3(NWG), b512, 131072, stream>>>(
      GIp_c, GIh_c, Whhp_bf, Whhh_bf, pgbhh, hgbhh,
      hst, o_p_bf, o_h_bf, c*CH, bar, (unsigned)(c*CH));
  }

  // ---- Phase C: Whs = o_p @ W_s ----
  mgemm<bfraw, bfraw, false><<<dim3(HID/128, (TSEQ*NB)/128, 1), b256, 0, stream>>>(
    o_p_bf, o_p_bf, WsT_bf, WsT_bf, nullptr, nullptr, Whs_bf, Whs_bf,
    HID, HID, HID, HID);

  // ---- Phase D: merged-phase scan, 2 barriers + pairsync (epochs 257..768) ----
  scanD<<<dim3(NWG), b512, 155776, stream>>>(
    Whs_bf, o_p_bf, o_h_bf, WtT_bf, WmT_bf, w_e, Wcat_bf, bc,
    hmbuf, hm_bf, a_bf, Lbuf,
    outW, outb, (float*)d_out, bar, (unsigned)TSEQ);
}

// Round 12
// 24161.450 us; speedup vs baseline: 1.3124x; 1.0308x over previous
//
#include <hip/hip_runtime.h>
#include <cstddef>

#define TSEQ 256
#define NB   128
#define HID  512
#define G3   1536
#define INDIM 768
#define CH   16
#define NWG  256
#define FLS  32   // u32 stride between flag lines (128 B)

typedef unsigned short bfraw;
using short8 = __attribute__((ext_vector_type(8))) short;
using f32x4  = __attribute__((ext_vector_type(4))) float;

#define MFMA16 __builtin_amdgcn_mfma_f32_16x16x32_bf16

__device__ __forceinline__ float bf2f(unsigned int u){ return __uint_as_float(u<<16); }
__device__ __forceinline__ bfraw f2bf(float f){
  unsigned int u = __float_as_uint(f);
  u += 0x7fffu + ((u>>16)&1u);
  return (bfraw)(u>>16);
}
__device__ __forceinline__ float fsig(float x){
  return __builtin_amdgcn_rcpf(1.0f + __expf(-x));
}
__device__ __forceinline__ float ftanh(float x){
  return 1.0f - 2.0f*__builtin_amdgcn_rcpf(1.0f + __expf(2.0f*x));
}
// coherence-point (sc1) 16B read — tiny pairwise payloads only
__device__ __forceinline__ float4 bpf4(const void* p){
  unsigned long long a = __hip_atomic_load((const unsigned long long*)p,     __ATOMIC_RELAXED, __HIP_MEMORY_SCOPE_AGENT);
  unsigned long long b = __hip_atomic_load((const unsigned long long*)p + 1, __ATOMIC_RELAXED, __HIP_MEMORY_SCOPE_AGENT);
  union{ unsigned long long q[2]; float4 f; } cv; cv.q[0]=a; cv.q[1]=b; return cv.f;
}

// ---- pure-relaxed spin: sc1 polls read the coherence point; NO invalidates ----
__device__ __forceinline__ void spin_ge(unsigned* p, unsigned epoch){
  while (__hip_atomic_load(p, __ATOMIC_RELAXED, __HIP_MEMORY_SCOPE_AGENT) < epoch)
    __builtin_amdgcn_s_sleep(1);
}

// ---- direct flag wait: poll n producer flags in parallel, ONE acquire at wakeup ----
__device__ __forceinline__ void pollN(unsigned* flags, int n, unsigned epoch){
  const int tid = threadIdx.x;
  if (tid < n) spin_ge(&flags[tid*FLS], epoch);
  __syncthreads();
  if (tid == 0)
    (void)__hip_atomic_load(&flags[0], __ATOMIC_ACQUIRE, __HIP_MEMORY_SCOPE_AGENT);
  __syncthreads();
}
// release own flag (caller must __syncthreads() first so all WG stores are in L2)
__device__ __forceinline__ void setflag(unsigned* f, unsigned v){
  if (threadIdx.x == 0)
    __hip_atomic_store(f, v, __ATOMIC_RELEASE, __HIP_MEMORY_SCOPE_AGENT);
}

__global__ void init_k(unsigned* bar){
  int i = blockIdx.x*256 + threadIdx.x;
  if (i < 4*NWG*FLS) bar[i] = 0u;
}

__global__ void hminit_k(float* hmbuf, bfraw* hm_bf){
  int i = blockIdx.x*256 + threadIdx.x;   // 131072 (both slots)
  hmbuf[i] = 1.0f;
  hm_bf[i] = (bfraw)0x3f80;
}

// ---- transpose+convert: in fp32 [R][Cc] -> out bf16 [Cc][R] ----
__global__ __launch_bounds__(256)
void tconv_k(const float* __restrict__ in, bfraw* __restrict__ out, int R, int Cc){
  __shared__ float t[32][33];
  int c0 = blockIdx.x*32, r0 = blockIdx.y*32;
  int tx = threadIdx.x&31, ty = threadIdx.x>>5;
  #pragma unroll
  for (int i=0;i<32;i+=8) t[ty+i][tx] = in[(size_t)(r0+ty+i)*Cc + c0+tx];
  __syncthreads();
  #pragma unroll
  for (int i=0;i<32;i+=8) out[(size_t)(c0+ty+i)*R + r0+tx] = f2bf(t[tx][ty+i]);
}

__global__ void cvt_k(const float* __restrict__ in, bfraw* __restrict__ out, int n){
  int i = (blockIdx.x*256 + threadIdx.x)*4;
  if (i >= n) return;
  float4 v = *(const float4*)(in+i);
  uint2 o;
  o.x = (unsigned)f2bf(v.x) | ((unsigned)f2bf(v.y)<<16);
  o.y = (unsigned)f2bf(v.z) | ((unsigned)f2bf(v.w)<<16);
  *(uint2*)(out+i) = o;
}

// W_cat[n'][k], n'=dd*4+g, k<1536 (segs: a[0,512) x[512,1024) -> mWih; hm[1024,1536) -> mWhh)
__global__ void wcat_k(const float* __restrict__ mWih, const float* __restrict__ mWhh,
                       bfraw* __restrict__ Wcat){
  size_t gid = (size_t)blockIdx.x*256 + threadIdx.x;
  int np = (int)(gid / 384);
  int k4 = ((int)(gid % 384))*4;
  int dd = np>>2, g = np&3;
  float v[4];
  #pragma unroll
  for (int j=0;j<4;++j){
    int k = k4+j; float x = 0.f;
    if (g==0)      x = (k<1024) ? mWih[(size_t)dd*1024 + k]        : mWhh[(size_t)dd*512 + (k-1024)];
    else if (g==1) x = (k<1024) ? mWih[(size_t)(512+dd)*1024 + k]  : mWhh[(size_t)(512+dd)*512 + (k-1024)];
    else if (g==2) x = (k<1024) ? mWih[(size_t)(1024+dd)*1024 + k] : 0.f;
    else           x = (k<1024) ? 0.f : mWhh[(size_t)(1024+dd)*512 + (k-1024)];
    v[j] = x;
  }
  uint2 o;
  o.x = (unsigned)f2bf(v[0]) | ((unsigned)f2bf(v[1])<<16);
  o.y = (unsigned)f2bf(v[2]) | ((unsigned)f2bf(v[3])<<16);
  *(uint2*)(Wcat + (size_t)np*1536 + k4) = o;
}

__global__ void bpack_k(const float* __restrict__ mbih, const float* __restrict__ mbhh,
                        float* __restrict__ bc){
  int dd = blockIdx.x*256 + threadIdx.x;
  if (dd >= 512) return;
  bc[dd]      = mbih[dd] + mbhh[dd];
  bc[512+dd]  = mbih[512+dd] + mbhh[512+dd];
  bc[1024+dd] = mbih[1024+dd];
  bc[1536+dd] = mbhh[1024+dd];
}

__global__ void fuse_bias_k(const float* __restrict__ Wih, const float* __restrict__ bih,
                            const float* __restrict__ pb, float* __restrict__ bout)
{
  int g = blockIdx.x*256 + threadIdx.x;
  if (g >= G3) return;
  float acc = bih[g];
  const float* w = Wih + (size_t)g*HID;
  for (int e=0;e<HID;e+=4){
    float4 wv = *(const float4*)(w+e);
    float4 pv = *(const float4*)(pb+e);
    acc += wv.x*pv.x + wv.y*pv.y + wv.z*pv.z + wv.w*pv.w;
  }
  bout[g] = acc;
}

// ---- MFMA bf16 GEMM: C[MxN] = A[MxK] * B^T (+bias); z selects operand set ----
template<typename TA, typename TC, bool BIAS>
__global__ __launch_bounds__(256)
void mgemm(const TA* __restrict__ A0, const TA* __restrict__ A1,
           const bfraw* __restrict__ B0, const bfraw* __restrict__ B1,
           const float* __restrict__ bias0, const float* __restrict__ bias1,
           TC* __restrict__ C0, TC* __restrict__ C1,
           int K, int lda, int ldb, int ldc)
{
  const TA* A = blockIdx.z ? A1 : A0;
  const bfraw* B = blockIdx.z ? B1 : B0;
  const float* bias = blockIdx.z ? bias1 : bias0;
  TC* C = blockIdx.z ? C1 : C0;
  __shared__ bfraw Al[128*40];
  __shared__ bfraw Bl[128*40];
  const int tid = threadIdx.x;
  const size_t m0 = (size_t)blockIdx.y*128, n0 = (size_t)blockIdx.x*128;
  const int w = tid>>6, l = tid&63;
  const int wr = (w>>1)*64, wc = (w&1)*64;
  const int fr = l&15, fg = l>>4;
  f32x4 acc[4][4];
  #pragma unroll
  for (int i=0;i<4;++i)
    #pragma unroll
    for (int j=0;j<4;++j) acc[i][j] = (f32x4){0.f,0.f,0.f,0.f};

  const int srow = tid>>1, skc = (tid&1)*16;
  for (int k0=0; k0<K; k0+=32){
    if constexpr (sizeof(TA)==4){
      const float* ap = (const float*)A + (m0+srow)*lda + k0 + skc;
      float4 v0=*(const float4*)ap, v1=*(const float4*)(ap+4),
             v2=*(const float4*)(ap+8), v3=*(const float4*)(ap+12);
      uint4 w0, w1;
      w0.x=(unsigned)f2bf(v0.x)|((unsigned)f2bf(v0.y)<<16);
      w0.y=(unsigned)f2bf(v0.z)|((unsigned)f2bf(v0.w)<<16);
      w0.z=(unsigned)f2bf(v1.x)|((unsigned)f2bf(v1.y)<<16);
      w0.w=(unsigned)f2bf(v1.z)|((unsigned)f2bf(v1.w)<<16);
      w1.x=(unsigned)f2bf(v2.x)|((unsigned)f2bf(v2.y)<<16);
      w1.y=(unsigned)f2bf(v2.z)|((unsigned)f2bf(v2.w)<<16);
      w1.z=(unsigned)f2bf(v3.x)|((unsigned)f2bf(v3.y)<<16);
      w1.w=(unsigned)f2bf(v3.z)|((unsigned)f2bf(v3.w)<<16);
      *(uint4*)&Al[srow*40+skc]   = w0;
      *(uint4*)&Al[srow*40+skc+8] = w1;
    } else {
      const bfraw* ap = (const bfraw*)A + (m0+srow)*lda + k0 + skc;
      *(uint4*)&Al[srow*40+skc]   = *(const uint4*)ap;
      *(uint4*)&Al[srow*40+skc+8] = *(const uint4*)(ap+8);
    }
    {
      const bfraw* bp = B + (n0+srow)*ldb + k0 + skc;
      *(uint4*)&Bl[srow*40+skc]   = *(const uint4*)bp;
      *(uint4*)&Bl[srow*40+skc+8] = *(const uint4*)(bp+8);
    }
    __syncthreads();
    short8 af[4], bfr[4];
    #pragma unroll
    for (int i=0;i<4;++i) af[i]  = *(const short8*)&Al[(wr+i*16+fr)*40 + fg*8];
    #pragma unroll
    for (int j=0;j<4;++j) bfr[j] = *(const short8*)&Bl[(wc+j*16+fr)*40 + fg*8];
    #pragma unroll
    for (int i=0;i<4;++i)
      #pragma unroll
      for (int j=0;j<4;++j)
        acc[i][j] = MFMA16(af[i], bfr[j], acc[i][j], 0,0,0);
    __syncthreads();
  }
  #pragma unroll
  for (int i=0;i<4;++i){
    #pragma unroll
    for (int j=0;j<4;++j){
      size_t n = n0 + wc + j*16 + fr;
      float bv = BIAS ? bias[n] : 0.f;
      #pragma unroll
      for (int r=0;r<4;++r){
        size_t m = m0 + wr + i*16 + fg*4 + r;
        float v = acc[i][j][r] + bv;
        if constexpr (sizeof(TC)==2) ((bfraw*)C)[m*ldc + n] = f2bf(v);
        else                         ((float*)C)[m*ldc + n] = v;
      }
    }
  }
}

// ---- Phase B: persistent GRU scan; 16-WG-group DIRECT flag sync (1 hop/step) ----
__global__ __launch_bounds__(512, 2)
void scanB(const float* __restrict__ GIp, const float* __restrict__ GIh,
           const bfraw* __restrict__ Whhp, const bfraw* __restrict__ Whhh,
           const float* __restrict__ bhhp, const float* __restrict__ bhhh,
           float* __restrict__ hst, bfraw* __restrict__ o_p, bfraw* __restrict__ o_h,
           int c0, unsigned* __restrict__ bar)
{
  extern __shared__ char smem[];
  bfraw* wl = (bfraw*)smem;                  // 98304 B
  float* sh = (float*)(smem + 98304);        // 32768 B
  const int wg = blockIdx.x;
  const int z = wg>>7, rem = wg&127;
  const int bg = rem>>4, dg = rem&15;
  const float* GI  = z ? GIh : GIp;
  const bfraw* Wb  = z ? Whhh : Whhp;
  const float* bhh = z ? bhhh : bhhp;
  bfraw* ob = z ? o_h : o_p;
  float* hz = hst + (size_t)z*2*NB*HID;
  const int tid = threadIdx.x;
  unsigned* bfl = bar + 3*NWG*FLS;
  unsigned* grp = bfl + (size_t)(z*128 + bg*16)*FLS;   // this group's 16 flags
  unsigned* own = bfl + (size_t)wg*FLS;

  #pragma unroll
  for (int g=0; g<3; ++g){
    const unsigned* src = (const unsigned*)(Wb + (size_t)(g*512 + dg*32)*512);
    for (int j=0; j<16; ++j){
      int iu = tid + j*512;
      unsigned v = src[iu];
      int d = iu>>8, kk = (iu&255)*2;
      int idx0 = g*16384 + (kk>>2)*128 + d*4 + (kk&3);
      *((unsigned*)wl + (idx0>>1)) = v;
    }
  }
  __syncthreads();

  const int bl = tid>>5, dl = tid&31;
  const int d = dg*32+dl, bglob = bg*16+bl;
  const float br = bhh[d], bz = bhh[512+d], bn = bhh[1024+d];

  #pragma clang loop unroll(disable)
  for (int tt=0; tt<CH; ++tt){
    const int t = c0+tt;
    if (t > 0) pollN(grp, 16, (unsigned)t);   // h(t-1) published by group
    if (t == 0){
      for (int j=0;j<4;++j){
        int i4 = tid + j*512;
        *(float4*)&sh[i4*4] = (float4){1.f,1.f,1.f,1.f};
      }
    } else {
      const float* hp = hz + (size_t)((t-1)&1)*NB*HID + (size_t)bg*16*HID;
      for (int j=0;j<4;++j){
        int i4 = tid + j*512;
        *(float4*)&sh[i4*4] = *(const float4*)&hp[i4*4];
      }
    }
    __syncthreads();
    float ar = br, az = bz, an = bn;
    const float* hb = sh + bl*512;
    for (int k=0;k<512;k+=4){
      float4 h4 = *(const float4*)(hb+k);
      int base = (k>>2)*128 + dl*4;
      uint2 wr = *(const uint2*)(wl + base);
      uint2 wz = *(const uint2*)(wl + 16384 + base);
      uint2 wn = *(const uint2*)(wl + 32768 + base);
      ar += h4.x*bf2f(wr.x&0xffffu) + h4.y*bf2f(wr.x>>16) + h4.z*bf2f(wr.y&0xffffu) + h4.w*bf2f(wr.y>>16);
      az += h4.x*bf2f(wz.x&0xffffu) + h4.y*bf2f(wz.x>>16) + h4.z*bf2f(wz.y&0xffffu) + h4.w*bf2f(wz.y>>16);
      an += h4.x*bf2f(wn.x&0xffffu) + h4.y*bf2f(wn.x>>16) + h4.z*bf2f(wn.y&0xffffu) + h4.w*bf2f(wn.y>>16);
    }
    const float* gi = GI + ((size_t)tt*NB + bglob)*G3;
    float r  = fsig(gi[d] + ar);
    float zz = fsig(gi[512+d] + az);
    float n  = ftanh(gi[1024+d] + r*an);
    float hp = hb[d];
    float hv = (1.0f-zz)*n + zz*hp;
    (hz + (size_t)(t&1)*NB*HID)[(size_t)bglob*HID + d] = hv;
    ob[((size_t)t*NB + bglob)*HID + d] = f2bf(hv);
    __syncthreads();
    setflag(own, (unsigned)(t+1));
  }
}

// ---- Phase D: persistent scan — 3 DIRECT flag hops/step, no grid barrier -----
// WG = (b = wg>>1, dh = wg&1). LDS: Whs[all tq, b, dh-half] 128 KB (swizzled).
__global__ __launch_bounds__(512, 2)
void scanD(const bfraw* __restrict__ Whs, const bfraw* __restrict__ o_p,
           const bfraw* __restrict__ o_h,
           const bfraw* __restrict__ WtT, const bfraw* __restrict__ WmT,
           const float* __restrict__ w_e,
           const bfraw* __restrict__ Wcat, const float* __restrict__ bc,
           float* __restrict__ hmbuf, bfraw* __restrict__ hm_bf,
           bfraw* __restrict__ a_bf, float* __restrict__ Lbuf,
           const float* __restrict__ outW, const float* __restrict__ outb,
           float* __restrict__ out, unsigned* __restrict__ bar)
{
  extern __shared__ char smem[];
  bfraw* whs_l = (bfraw*)smem;                 // 131072 B
  float* pt    = (float*)(smem + 131072);      // 16384 B [16][256]
  float* xlf   = (float*)(smem + 147456);      // 2048 B  x_t[b] fp32
  float* hml   = (float*)(smem + 149504);      // 2048 B  hm[b] fp32
  float* c_l   = (float*)(smem + 151552);      // 1024 B
  float* lp0   = (float*)(smem + 152576);      // 1024 B
  float* lp1   = (float*)(smem + 153600);      // 1024 B
  float* l_s   = (float*)(smem + 154624);      // 1024 B
  float* red   = (float*)(smem + 155648);      // 128 B

  const int wg = blockIdx.x, tid = threadIdx.x;
  const int b = wg>>1, dh = wg&1;
  unsigned* pf  = bar;                          // pairwise flags
  unsigned* afl = bar + NWG*FLS;                // a_bf-ready flags (all 256)
  unsigned* hfl = bar + 2*NWG*FLS;              // hm-ready flags (gate WGs, 128)

  // preload Whs[tq, b, dh-half] with XOR-chunk swizzle (chunk = 16B = 8 bf16)
  for (int it=0; it<16; ++it){
    int idx = tid + it*512;                    // 8192 = 256 tq x 32 chunks
    int tq = idx>>5, c = idx&31;
    const bfraw* src = Whs + ((size_t)tq*NB + b)*HID + dh*256 + c*8;
    *(uint4*)&whs_l[tq*256 + ((c ^ (tq&15))<<3)] = *(const uint4*)src;
  }
  const int cc_ = tid&31;
  float we8[8];
  #pragma unroll
  for (int r=0;r<8;++r) we8[r] = w_e[dh*256 + cc_*8 + r];
  __syncthreads();

  #pragma clang loop unroll(disable)
  for (int t=0; t<TSEQ; ++t){
    const int rs = (t+1)&1;
    const bfraw* hmr = hm_bf + (size_t)rs*65536;
    const float* hpr = hmbuf + (size_t)rs*65536;
    bfraw* hmw = hm_bf + (size_t)(t&1)*65536;
    float* hpw = hmbuf + (size_t)(t&1)*65536;

    // ---- wait for hm(t-1): poll the 128 gate-WG flags directly ----
    if (t > 0) pollN(hfl, 128, (unsigned)t);

    // ---- stage x_t[b], hm[b] ----
    if (tid < 64){
      uint4 u = *(const uint4*)(o_h + ((size_t)t*NB + b)*HID + tid*8);
      float4 f0, f1;
      f0.x=bf2f(u.x&0xffffu); f0.y=bf2f(u.x>>16); f0.z=bf2f(u.y&0xffffu); f0.w=bf2f(u.y>>16);
      f1.x=bf2f(u.z&0xffffu); f1.y=bf2f(u.z>>16); f1.z=bf2f(u.w&0xffffu); f1.w=bf2f(u.w>>16);
      *(float4*)&xlf[tid*8]   = f0;
      *(float4*)&xlf[tid*8+4] = f1;
    } else if (tid < 192){
      int i2 = tid - 64;
      *(float4*)&hml[i2*4] = *(const float4*)(hpr + (size_t)b*HID + i2*4);
    }
    __syncthreads();

    // ---- c[b, e] for e in dh-half: x@W_t + hm@W_m ----
    {
      const int el = tid>>1, kh = tid&1;
      const bfraw* wt = WtT + (size_t)(dh*256+el)*HID + kh*256;
      const bfraw* wm = WmT + (size_t)(dh*256+el)*HID + kh*256;
      const float* xv = xlf + kh*256;
      const float* hv = hml + kh*256;
      float acc = 0.f;
      #pragma unroll 4
      for (int k8=0;k8<32;++k8){
        uint4 wu = *(const uint4*)(wt+k8*8);
        uint4 mu = *(const uint4*)(wm+k8*8);
        float4 x0 = *(const float4*)(xv+k8*8), x1 = *(const float4*)(xv+k8*8+4);
        float4 h0 = *(const float4*)(hv+k8*8), h1 = *(const float4*)(hv+k8*8+4);
        acc += x0.x*bf2f(wu.x&0xffffu) + x0.y*bf2f(wu.x>>16) + x0.z*bf2f(wu.y&0xffffu) + x0.w*bf2f(wu.y>>16);
        acc += x1.x*bf2f(wu.z&0xffffu) + x1.y*bf2f(wu.z>>16) + x1.z*bf2f(wu.w&0xffffu) + x1.w*bf2f(wu.w>>16);
        acc += h0.x*bf2f(mu.x&0xffffu) + h0.y*bf2f(mu.x>>16) + h0.z*bf2f(mu.y&0xffffu) + h0.w*bf2f(mu.y>>16);
        acc += h1.x*bf2f(mu.z&0xffffu) + h1.y*bf2f(mu.z>>16) + h1.z*bf2f(mu.w&0xffffu) + h1.w*bf2f(mu.w>>16);
      }
      acc += __shfl_xor(acc, 1);
      if (kh == 0) c_l[el] = acc;
    }
    __syncthreads();

    // ---- logit partials over this d-half (register c/we; LDS only for Whs) ----
    {
      const int tqs = tid>>5;
      float c8[8];
      *(float4*)&c8[0] = *(const float4*)&c_l[cc_*8];
      *(float4*)&c8[4] = *(const float4*)&c_l[cc_*8+4];
      #pragma unroll 2
      for (int i=0;i<16;++i){
        int tq = tqs + i*16;
        uint4 u = *(const uint4*)&whs_l[tq*256 + ((cc_ ^ (tq&15))<<3)];
        float s = 0.f;
        #pragma unroll
        for (int j=0;j<4;++j){
          unsigned uu = ((const unsigned*)&u)[j];
          s += ftanh(bf2f(uu&0xffffu) + c8[j*2])   * we8[j*2];
          s += ftanh(bf2f(uu>>16)     + c8[j*2+1]) * we8[j*2+1];
        }
        #pragma unroll
        for (int off=16; off; off>>=1) s += __shfl_xor(s, off);
        if (cc_ == 0) lp0[tq] = s;
      }
    }
    __syncthreads();
    // export partial for buddy + release pair flag
    if (tid < 64) *(float4*)&Lbuf[(size_t)wg*256 + tid*4] = *(const float4*)&lp0[tid*4];
    __syncthreads();
    setflag(&pf[wg*FLS], (unsigned)(t+1));

    // ---- issue o_p prefetch (latency hides under pairsync + softmax) ----
    const int dgrp = tid&31, tqs2 = tid>>5, d8 = dgrp*8;
    const bfraw* opb = o_p + (size_t)b*HID + dh*256 + d8;
    uint4 uu[16];
    #pragma unroll
    for (int i=0;i<16;++i)
      uu[i] = *(const uint4*)(opb + (size_t)(tqs2*16 + i)*NB*HID);

    // ---- pairwise sync + read buddy partials (bypass, 1 KB) ----
    if (tid == 0) spin_ge(&pf[(wg^1)*FLS], (unsigned)(t+1));
    __syncthreads();
    if (tid < 64) *(float4*)&lp1[tid*4] = bpf4(&Lbuf[(size_t)(wg^1)*256 + tid*4]);
    __syncthreads();

    // ---- softmax over 256 logits ----
    {
      const int lane = tid&63;
      float v = -1e30f, e = 0.f;
      if (tid < TSEQ){
        v = lp0[tid] + lp1[tid];
        float m = v;
        #pragma unroll
        for (int off=32; off; off>>=1) m = fmaxf(m, __shfl_xor(m, off));
        if (lane==0) red[tid>>6] = m;
      }
      __syncthreads();
      float mx = fmaxf(fmaxf(red[0],red[1]), fmaxf(red[2],red[3]));
      if (tid < TSEQ){
        e = __expf(v - mx);
        float s2 = e;
        #pragma unroll
        for (int off=32; off; off>>=1) s2 += __shfl_xor(s2, off);
        if (lane==0) red[8+(tid>>6)] = s2;
      }
      __syncthreads();
      float S = red[8]+red[9]+red[10]+red[11];
      if (tid < TSEQ) l_s[tid] = e * __builtin_amdgcn_rcpf(S);
      __syncthreads();
    }

    // ---- consume prefetched o_p -> a_t d-half ----
    {
      float a0=0,a1=0,a2=0,a3=0,a4=0,a5=0,a6=0,a7=0;
      #pragma unroll
      for (int i=0;i<16;++i){
        float al = l_s[tqs2*16 + i];
        uint4 u = uu[i];
        a0 += al*bf2f(u.x&0xffffu); a1 += al*bf2f(u.x>>16);
        a2 += al*bf2f(u.y&0xffffu); a3 += al*bf2f(u.y>>16);
        a4 += al*bf2f(u.z&0xffffu); a5 += al*bf2f(u.z>>16);
        a6 += al*bf2f(u.w&0xffffu); a7 += al*bf2f(u.w>>16);
      }
      *(float4*)&pt[tqs2*256+d8]   = (float4){a0,a1,a2,a3};
      *(float4*)&pt[tqs2*256+d8+4] = (float4){a4,a5,a6,a7};
      __syncthreads();
      if (tid < 256){
        float sA = 0.f;
        #pragma unroll
        for (int ss=0;ss<16;++ss) sA += pt[ss*256 + tid];
        float sB = __shfl_down(sA, 1);
        if ((tid&1)==0){
          unsigned pk = (unsigned)f2bf(sA) | ((unsigned)f2bf(sB)<<16);
          *(unsigned*)(a_bf + (size_t)b*HID + dh*256 + tid) = pk;
        }
      }
    }
    __syncthreads();
    setflag(&afl[wg*FLS], (unsigned)(t+1));   // a_bf half published

    // ---- gates: MFMA + state update (wg<128, n-slice 16) ----
    if (wg < 128){
      pollN(afl, 256, (unsigned)(t+1));       // all a_bf halves ready (direct)
      const int n0 = wg*16;
      const int w = tid>>6, l = tid&63, fr = l&15, fg = l>>4;
      const int m0w = w*16;
      const bfraw* arow = a_bf + (size_t)(m0w+fr)*HID;
      const bfraw* xrow = o_h + ((size_t)t*NB + m0w+fr)*HID;
      const bfraw* hrow = hmr + (size_t)(m0w+fr)*HID;
      const bfraw* wrow = Wcat + (size_t)(n0+fr)*1536;
      f32x4 accA={0.f,0.f,0.f,0.f}, accB={0.f,0.f,0.f,0.f};
      #pragma unroll
      for (int kk=0; kk<16; ++kk){
        short8 af = *(const short8*)(arow + kk*32 + fg*8);
        short8 bv = *(const short8*)(wrow + kk*32 + fg*8);
        accA = MFMA16(af, bv, accA, 0,0,0);
      }
      #pragma unroll
      for (int kk=0; kk<16; ++kk){
        short8 af = *(const short8*)(xrow + kk*32 + fg*8);
        short8 bv = *(const short8*)(wrow + 512 + kk*32 + fg*8);
        accB = MFMA16(af, bv, accB, 0,0,0);
      }
      #pragma unroll
      for (int kk=0; kk<16; ++kk){
        short8 af = *(const short8*)(hrow + kk*32 + fg*8);
        short8 bv = *(const short8*)(wrow + 1024 + kk*32 + fg*8);
        accA = MFMA16(af, bv, accA, 0,0,0);
      }
      f32x4 acc = accA + accB;
      const int np = n0 + fr, dd = np>>2, g = np&3;
      #pragma unroll
      for (int rr=0; rr<4; ++rr){
        float x0 = acc[rr];
        float x1 = __shfl_xor(x0, 1);
        float x2 = __shfl_xor(x0, 2);
        float x3 = __shfl_xor(x1, 2);
        if (g==0){
          int b3 = m0w + fg*4 + rr;
          float hp = hpr[(size_t)b3*HID + dd];
          float rg = fsig(x0 + bc[dd]);
          float zg = fsig(x1 + bc[512+dd]);
          float gn = ftanh(x2 + bc[1024+dd] + rg*(x3 + bc[1536+dd]));
          float h = (1.f-zg)*gn + zg*hp;
          hpw[(size_t)b3*HID + dd] = h;
          hmw[(size_t)b3*HID + dd] = f2bf(h);
        }
      }
      __syncthreads();
      setflag(&hfl[wg*FLS], (unsigned)(t+1)); // hm slice published
    }
  }

  // ---- output head: h_star in slot (TSEQ-1)&1 = 1 ----
  if (wg == 0){
    pollN(hfl, 128, (unsigned)TSEQ);
    if (tid < NB*3){
      const float* hf = hmbuf + (size_t)((TSEQ-1)&1)*65536;
      int b2 = tid/3, c = tid%3;
      float acc = outb[c];
      const float* h = hf + (size_t)b2*HID;
      const float* w = outW + (size_t)c*HID;
      for (int d2=0; d2<HID; ++d2) acc = fmaf(h[d2], w[d2], acc);
      out[tid] = fmaxf(acc, 0.f);
    }
  }
}

extern "C" void kernel_launch(void* const* d_in, const int* in_sizes, int n_in,
                              void* d_out, int out_size, void* d_ws, size_t ws_size,
                              hipStream_t stream)
{
  const float* Ep    = (const float*)d_in[0];
  const float* Eh    = (const float*)d_in[1];
  const float* p_W   = (const float*)d_in[2];
  const float* p_b   = (const float*)d_in[3];
  const float* h_W   = (const float*)d_in[4];
  const float* h_b   = (const float*)d_in[5];
  const float* pgWih = (const float*)d_in[6];
  const float* pgWhh = (const float*)d_in[7];
  const float* pgbih = (const float*)d_in[8];
  const float* pgbhh = (const float*)d_in[9];
  const float* hgWih = (const float*)d_in[10];
  const float* hgWhh = (const float*)d_in[11];
  const float* hgbih = (const float*)d_in[12];
  const float* hgbhh = (const float*)d_in[13];
  const float* W_s   = (const float*)d_in[14];
  const float* W_t   = (const float*)d_in[15];
  const float* w_e   = (const float*)d_in[16];
  const float* W_m   = (const float*)d_in[17];
  const float* mWih  = (const float*)d_in[18];
  const float* mWhh  = (const float*)d_in[19];
  const float* mbih  = (const float*)d_in[20];
  const float* mbhh  = (const float*)d_in[21];
  const float* outW  = (const float*)d_in[22];
  const float* outb  = (const float*)d_in[23];

  const size_t OB    = (size_t)TSEQ*NB*HID*sizeof(bfraw);
  const size_t RB    = OB;
  const size_t WFB   = (size_t)G3*INDIM*sizeof(bfraw);
  const size_t SQB   = (size_t)HID*HID*sizeof(bfraw);
  const size_t WHHB  = (size_t)G3*HID*sizeof(bfraw);
  const size_t WCATB = (size_t)2048*1536*sizeof(bfraw);
  const size_t BARB  = (size_t)4*NWG*FLS*sizeof(unsigned);   // pf/afl/hfl/bfl
  const size_t needed = 2*OB + RB + 2*WFB + 3*SQB + 2*WHHB + WCATB
                        + 8192 + 2*6144
                        + 4*262144 + 2*262144 + 2*131072
                        + BARB;
  if (ws_size < needed) return;

  char* p = (char*)d_ws;
  bfraw* o_p_bf = (bfraw*)p; p += OB;
  bfraw* o_h_bf = (bfraw*)p; p += OB;
  char*  Rreg   = p;         p += RB;
  bfraw* Wfp_bf = (bfraw*)p; p += WFB;
  bfraw* Wfh_bf = (bfraw*)p; p += WFB;
  bfraw* WsT_bf = (bfraw*)p; p += SQB;
  bfraw* WtT_bf = (bfraw*)p; p += SQB;
  bfraw* WmT_bf = (bfraw*)p; p += SQB;
  bfraw* Whhp_bf= (bfraw*)p; p += WHHB;
  bfraw* Whhh_bf= (bfraw*)p; p += WHHB;
  bfraw* Wcat_bf= (bfraw*)p; p += WCATB;
  float* bc     = (float*)p; p += 8192;
  float* bfp    = (float*)p; p += 6144;
  float* bfh    = (float*)p; p += 6144;
  float* hst    = (float*)p; p += 4*262144;
  float* hmbuf  = (float*)p; p += 2*262144;
  bfraw* hm_bf  = (bfraw*)p; p += 2*131072;
  unsigned* bar = (unsigned*)p; p += BARB;

  bfraw* pWT_bf = (bfraw*)Rreg;
  bfraw* hWT_bf = (bfraw*)(Rreg + (size_t)INDIM*HID*sizeof(bfraw));
  float* GIp_c  = (float*)Rreg;
  float* GIh_c  = (float*)(Rreg + (size_t)CH*NB*G3*sizeof(float));
  bfraw* Whs_bf = (bfraw*)Rreg;
  float* Lbuf   = (float*)Wfp_bf;                         // 256 KB overlay (Wf dead in D)
  bfraw* a_bf   = (bfraw*)((char*)Wfp_bf + 2097152);      // 128 KB

  (void)hipFuncSetAttribute((const void*)scanB, hipFuncAttributeMaxDynamicSharedMemorySize, 131072);
  (void)hipFuncSetAttribute((const void*)scanD, hipFuncAttributeMaxDynamicSharedMemorySize, 155776);

  dim3 b256(256), b512(512);

  init_k<<<dim3(128), b256, 0, stream>>>(bar);
  hminit_k<<<dim3(512), b256, 0, stream>>>(hmbuf, hm_bf);

  // ---- Phase A: weight prep ----
  tconv_k<<<dim3(INDIM/32, HID/32), b256, 0, stream>>>(p_W, pWT_bf, HID, INDIM);
  tconv_k<<<dim3(INDIM/32, HID/32), b256, 0, stream>>>(h_W, hWT_bf, HID, INDIM);
  tconv_k<<<dim3(HID/32, HID/32),  b256, 0, stream>>>(W_s, WsT_bf, HID, HID);
  tconv_k<<<dim3(HID/32, HID/32),  b256, 0, stream>>>(W_t, WtT_bf, HID, HID);
  tconv_k<<<dim3(HID/32, HID/32),  b256, 0, stream>>>(W_m, WmT_bf, HID, HID);
  cvt_k<<<dim3((G3*HID)/1024), b256, 0, stream>>>(pgWhh, Whhp_bf, G3*HID);
  cvt_k<<<dim3((G3*HID)/1024), b256, 0, stream>>>(hgWhh, Whhh_bf, G3*HID);
  wcat_k<<<dim3(3072), b256, 0, stream>>>(mWih, mWhh, Wcat_bf);
  bpack_k<<<dim3(2), b256, 0, stream>>>(mbih, mbhh, bc);
  fuse_bias_k<<<dim3(G3/256), b256, 0, stream>>>(pgWih, pgbih, p_b, bfp);
  fuse_bias_k<<<dim3(G3/256), b256, 0, stream>>>(hgWih, hgbih, h_b, bfh);
  mgemm<float, bfraw, false><<<dim3(INDIM/128, G3/128, 2), b256, 0, stream>>>(
    pgWih, hgWih, pWT_bf, hWT_bf, nullptr, nullptr, Wfp_bf, Wfh_bf,
    HID, HID, HID, INDIM);

  // ---- Phase B: chunked GI GEMM + persistent scan (direct flags) ----
  for (int c = 0; c < TSEQ/CH; ++c){
    mgemm<float, float, true><<<dim3(G3/128, (CH*NB)/128, 2), b256, 0, stream>>>(
      Ep + (size_t)c*CH*NB*INDIM, Eh + (size_t)c*CH*NB*INDIM,
      Wfp_bf, Wfh_bf, bfp, bfh, GIp_c, GIh_c,
      INDIM, INDIM, INDIM, G3);
    scanB<<<dim3(NWG), b512, 131072, stream>>>(
      GIp_c, GIh_c, Whhp_bf, Whhh_bf, pgbhh, hgbhh,
      hst, o_p_bf, o_h_bf, c*CH, bar);
  }

  // ---- Phase C: Whs = o_p @ W_s ----
  mgemm<bfraw, bfraw, false><<<dim3(HID/128, (TSEQ*NB)/128, 1), b256, 0, stream>>>(
    o_p_bf, o_p_bf, WsT_bf, WsT_bf, nullptr, nullptr, Whs_bf, Whs_bf,
    HID, HID, HID, HID);

  // ---- Phase D: persistent scan, direct flags (no grid barrier) ----
  scanD<<<dim3(NWG), b512, 155776, stream>>>(
    Whs_bf, o_p_bf, o_h_bf, WtT_bf, WmT_bf, w_e, Wcat_bf, bc,
    hmbuf, hm_bf, a_bf, Lbuf,
    outW, outb, (float*)d_out, bar);
}

// Round 13
// 22150.931 us; speedup vs baseline: 1.4315x; 1.0908x over previous
//
#include <hip/hip_runtime.h>
#include <cstddef>

#define TSEQ 256
#define NB   128
#define HID  512
#define G3   1536
#define INDIM 768
#define CH   16
#define NWG  256
#define FLS  32   // u32 stride between flag lines (128 B)

typedef unsigned short bfraw;
using short8 = __attribute__((ext_vector_type(8))) short;
using f32x4  = __attribute__((ext_vector_type(4))) float;

#define MFMA16 __builtin_amdgcn_mfma_f32_16x16x32_bf16

__device__ __forceinline__ float bf2f(unsigned int u){ return __uint_as_float(u<<16); }
__device__ __forceinline__ bfraw f2bf(float f){
  unsigned int u = __float_as_uint(f);
  u += 0x7fffu + ((u>>16)&1u);
  return (bfraw)(u>>16);
}
__device__ __forceinline__ float fsig(float x){
  return __builtin_amdgcn_rcpf(1.0f + __expf(-x));
}
__device__ __forceinline__ float ftanh(float x){
  return 1.0f - 2.0f*__builtin_amdgcn_rcpf(1.0f + __expf(2.0f*x));
}
// coherence-point (sc1) 16B read — tiny pairwise payloads only
__device__ __forceinline__ float4 bpf4(const void* p){
  unsigned long long a = __hip_atomic_load((const unsigned long long*)p,     __ATOMIC_RELAXED, __HIP_MEMORY_SCOPE_AGENT);
  unsigned long long b = __hip_atomic_load((const unsigned long long*)p + 1, __ATOMIC_RELAXED, __HIP_MEMORY_SCOPE_AGENT);
  union{ unsigned long long q[2]; float4 f; } cv; cv.q[0]=a; cv.q[1]=b; return cv.f;
}

// ---- relaxed spin with exponential backoff (cuts coherence-fabric poll storm) ----
__device__ __forceinline__ void spin_ge(unsigned* p, unsigned epoch){
  int sp = 0;
  while (__hip_atomic_load(p, __ATOMIC_RELAXED, __HIP_MEMORY_SCOPE_AGENT) < epoch){
    if (sp < 3){ __builtin_amdgcn_s_sleep(1); ++sp; }
    else        __builtin_amdgcn_s_sleep(16);   // ~1024 cyc
  }
}

// ---- direct flag wait: poll n producer flags in parallel, ONE acquire at wakeup ----
__device__ __forceinline__ void pollN(unsigned* flags, int n, unsigned epoch){
  const int tid = threadIdx.x;
  if (tid < n) spin_ge(&flags[tid*FLS], epoch);
  __syncthreads();
  if (tid == 0)
    (void)__hip_atomic_load(&flags[0], __ATOMIC_ACQUIRE, __HIP_MEMORY_SCOPE_AGENT);
  __syncthreads();
}
__device__ __forceinline__ void setflag(unsigned* f, unsigned v){
  if (threadIdx.x == 0)
    __hip_atomic_store(f, v, __ATOMIC_RELEASE, __HIP_MEMORY_SCOPE_AGENT);
}

__global__ void init_k(unsigned* bar){
  int i = blockIdx.x*256 + threadIdx.x;
  if (i < 4*NWG*FLS) bar[i] = 0u;
}

__global__ void hminit_k(float* hmbuf, bfraw* hm_bf){
  int i = blockIdx.x*256 + threadIdx.x;   // 131072 (both slots)
  hmbuf[i] = 1.0f;
  hm_bf[i] = (bfraw)0x3f80;
}

// ---- transpose+convert: in fp32 [R][Cc] -> out bf16 [Cc][R] ----
__global__ __launch_bounds__(256)
void tconv_k(const float* __restrict__ in, bfraw* __restrict__ out, int R, int Cc){
  __shared__ float t[32][33];
  int c0 = blockIdx.x*32, r0 = blockIdx.y*32;
  int tx = threadIdx.x&31, ty = threadIdx.x>>5;
  #pragma unroll
  for (int i=0;i<32;i+=8) t[ty+i][tx] = in[(size_t)(r0+ty+i)*Cc + c0+tx];
  __syncthreads();
  #pragma unroll
  for (int i=0;i<32;i+=8) out[(size_t)(c0+ty+i)*R + r0+tx] = f2bf(t[tx][ty+i]);
}

__global__ void cvt_k(const float* __restrict__ in, bfraw* __restrict__ out, int n){
  int i = (blockIdx.x*256 + threadIdx.x)*4;
  if (i >= n) return;
  float4 v = *(const float4*)(in+i);
  uint2 o;
  o.x = (unsigned)f2bf(v.x) | ((unsigned)f2bf(v.y)<<16);
  o.y = (unsigned)f2bf(v.z) | ((unsigned)f2bf(v.w)<<16);
  *(uint2*)(out+i) = o;
}

// W_cat[n'][k], n'=dd*4+g, k<1536 (segs: a[0,512) x[512,1024) -> mWih; hm[1024,1536) -> mWhh)
__global__ void wcat_k(const float* __restrict__ mWih, const float* __restrict__ mWhh,
                       bfraw* __restrict__ Wcat){
  size_t gid = (size_t)blockIdx.x*256 + threadIdx.x;
  int np = (int)(gid / 384);
  int k4 = ((int)(gid % 384))*4;
  int dd = np>>2, g = np&3;
  float v[4];
  #pragma unroll
  for (int j=0;j<4;++j){
    int k = k4+j; float x = 0.f;
    if (g==0)      x = (k<1024) ? mWih[(size_t)dd*1024 + k]        : mWhh[(size_t)dd*512 + (k-1024)];
    else if (g==1) x = (k<1024) ? mWih[(size_t)(512+dd)*1024 + k]  : mWhh[(size_t)(512+dd)*512 + (k-1024)];
    else if (g==2) x = (k<1024) ? mWih[(size_t)(1024+dd)*1024 + k] : 0.f;
    else           x = (k<1024) ? 0.f : mWhh[(size_t)(1024+dd)*512 + (k-1024)];
    v[j] = x;
  }
  uint2 o;
  o.x = (unsigned)f2bf(v[0]) | ((unsigned)f2bf(v[1])<<16);
  o.y = (unsigned)f2bf(v[2]) | ((unsigned)f2bf(v[3])<<16);
  *(uint2*)(Wcat + (size_t)np*1536 + k4) = o;
}

__global__ void bpack_k(const float* __restrict__ mbih, const float* __restrict__ mbhh,
                        float* __restrict__ bc){
  int dd = blockIdx.x*256 + threadIdx.x;
  if (dd >= 512) return;
  bc[dd]      = mbih[dd] + mbhh[dd];
  bc[512+dd]  = mbih[512+dd] + mbhh[512+dd];
  bc[1024+dd] = mbih[1024+dd];
  bc[1536+dd] = mbhh[1024+dd];
}

__global__ void fuse_bias_k(const float* __restrict__ Wih, const float* __restrict__ bih,
                            const float* __restrict__ pb, float* __restrict__ bout)
{
  int g = blockIdx.x*256 + threadIdx.x;
  if (g >= G3) return;
  float acc = bih[g];
  const float* w = Wih + (size_t)g*HID;
  for (int e=0;e<HID;e+=4){
    float4 wv = *(const float4*)(w+e);
    float4 pv = *(const float4*)(pb+e);
    acc += wv.x*pv.x + wv.y*pv.y + wv.z*pv.z + wv.w*pv.w;
  }
  bout[g] = acc;
}

// ---- MFMA bf16 GEMM: C[MxN] = A[MxK] * B^T (+bias); z selects operand set ----
template<typename TA, typename TC, bool BIAS>
__global__ __launch_bounds__(256)
void mgemm(const TA* __restrict__ A0, const TA* __restrict__ A1,
           const bfraw* __restrict__ B0, const bfraw* __restrict__ B1,
           const float* __restrict__ bias0, const float* __restrict__ bias1,
           TC* __restrict__ C0, TC* __restrict__ C1,
           int K, int lda, int ldb, int ldc)
{
  const TA* A = blockIdx.z ? A1 : A0;
  const bfraw* B = blockIdx.z ? B1 : B0;
  const float* bias = blockIdx.z ? bias1 : bias0;
  TC* C = blockIdx.z ? C1 : C0;
  __shared__ bfraw Al[128*40];
  __shared__ bfraw Bl[128*40];
  const int tid = threadIdx.x;
  const size_t m0 = (size_t)blockIdx.y*128, n0 = (size_t)blockIdx.x*128;
  const int w = tid>>6, l = tid&63;
  const int wr = (w>>1)*64, wc = (w&1)*64;
  const int fr = l&15, fg = l>>4;
  f32x4 acc[4][4];
  #pragma unroll
  for (int i=0;i<4;++i)
    #pragma unroll
    for (int j=0;j<4;++j) acc[i][j] = (f32x4){0.f,0.f,0.f,0.f};

  const int srow = tid>>1, skc = (tid&1)*16;
  for (int k0=0; k0<K; k0+=32){
    if constexpr (sizeof(TA)==4){
      const float* ap = (const float*)A + (m0+srow)*lda + k0 + skc;
      float4 v0=*(const float4*)ap, v1=*(const float4*)(ap+4),
             v2=*(const float4*)(ap+8), v3=*(const float4*)(ap+12);
      uint4 w0, w1;
      w0.x=(unsigned)f2bf(v0.x)|((unsigned)f2bf(v0.y)<<16);
      w0.y=(unsigned)f2bf(v0.z)|((unsigned)f2bf(v0.w)<<16);
      w0.z=(unsigned)f2bf(v1.x)|((unsigned)f2bf(v1.y)<<16);
      w0.w=(unsigned)f2bf(v1.z)|((unsigned)f2bf(v1.w)<<16);
      w1.x=(unsigned)f2bf(v2.x)|((unsigned)f2bf(v2.y)<<16);
      w1.y=(unsigned)f2bf(v2.z)|((unsigned)f2bf(v2.w)<<16);
      w1.z=(unsigned)f2bf(v3.x)|((unsigned)f2bf(v3.y)<<16);
      w1.w=(unsigned)f2bf(v3.z)|((unsigned)f2bf(v3.w)<<16);
      *(uint4*)&Al[srow*40+skc]   = w0;
      *(uint4*)&Al[srow*40+skc+8] = w1;
    } else {
      const bfraw* ap = (const bfraw*)A + (m0+srow)*lda + k0 + skc;
      *(uint4*)&Al[srow*40+skc]   = *(const uint4*)ap;
      *(uint4*)&Al[srow*40+skc+8] = *(const uint4*)(ap+8);
    }
    {
      const bfraw* bp = B + (n0+srow)*ldb + k0 + skc;
      *(uint4*)&Bl[srow*40+skc]   = *(const uint4*)bp;
      *(uint4*)&Bl[srow*40+skc+8] = *(const uint4*)(bp+8);
    }
    __syncthreads();
    short8 af[4], bfr[4];
    #pragma unroll
    for (int i=0;i<4;++i) af[i]  = *(const short8*)&Al[(wr+i*16+fr)*40 + fg*8];
    #pragma unroll
    for (int j=0;j<4;++j) bfr[j] = *(const short8*)&Bl[(wc+j*16+fr)*40 + fg*8];
    #pragma unroll
    for (int i=0;i<4;++i)
      #pragma unroll
      for (int j=0;j<4;++j)
        acc[i][j] = MFMA16(af[i], bfr[j], acc[i][j], 0,0,0);
    __syncthreads();
  }
  #pragma unroll
  for (int i=0;i<4;++i){
    #pragma unroll
    for (int j=0;j<4;++j){
      size_t n = n0 + wc + j*16 + fr;
      float bv = BIAS ? bias[n] : 0.f;
      #pragma unroll
      for (int r=0;r<4;++r){
        size_t m = m0 + wr + i*16 + fg*4 + r;
        float v = acc[i][j][r] + bv;
        if constexpr (sizeof(TC)==2) ((bfraw*)C)[m*ldc + n] = f2bf(v);
        else                         ((float*)C)[m*ldc + n] = v;
      }
    }
  }
}

// ---- Phase B: persistent GRU scan; 16-WG-group DIRECT flag sync (1 hop/step) ----
__global__ __launch_bounds__(512, 2)
void scanB(const float* __restrict__ GIp, const float* __restrict__ GIh,
           const bfraw* __restrict__ Whhp, const bfraw* __restrict__ Whhh,
           const float* __restrict__ bhhp, const float* __restrict__ bhhh,
           float* __restrict__ hst, bfraw* __restrict__ o_p, bfraw* __restrict__ o_h,
           int c0, unsigned* __restrict__ bar)
{
  extern __shared__ char smem[];
  bfraw* wl = (bfraw*)smem;                  // 98304 B
  float* sh = (float*)(smem + 98304);        // 32768 B
  const int wg = blockIdx.x;
  const int z = wg>>7, rem = wg&127;
  const int bg = rem>>4, dg = rem&15;
  const float* GI  = z ? GIh : GIp;
  const bfraw* Wb  = z ? Whhh : Whhp;
  const float* bhh = z ? bhhh : bhhp;
  bfraw* ob = z ? o_h : o_p;
  float* hz = hst + (size_t)z*2*NB*HID;
  const int tid = threadIdx.x;
  unsigned* bfl = bar + 3*NWG*FLS;
  unsigned* grp = bfl + (size_t)(z*128 + bg*16)*FLS;
  unsigned* own = bfl + (size_t)wg*FLS;

  #pragma unroll
  for (int g=0; g<3; ++g){
    const unsigned* src = (const unsigned*)(Wb + (size_t)(g*512 + dg*32)*512);
    for (int j=0; j<16; ++j){
      int iu = tid + j*512;
      unsigned v = src[iu];
      int d = iu>>8, kk = (iu&255)*2;
      int idx0 = g*16384 + (kk>>2)*128 + d*4 + (kk&3);
      *((unsigned*)wl + (idx0>>1)) = v;
    }
  }
  __syncthreads();

  const int bl = tid>>5, dl = tid&31;
  const int d = dg*32+dl, bglob = bg*16+bl;
  const float br = bhh[d], bz = bhh[512+d], bn = bhh[1024+d];

  #pragma clang loop unroll(disable)
  for (int tt=0; tt<CH; ++tt){
    const int t = c0+tt;
    if (t > 0) pollN(grp, 16, (unsigned)t);
    if (t == 0){
      for (int j=0;j<4;++j){
        int i4 = tid + j*512;
        *(float4*)&sh[i4*4] = (float4){1.f,1.f,1.f,1.f};
      }
    } else {
      const float* hp = hz + (size_t)((t-1)&1)*NB*HID + (size_t)bg*16*HID;
      for (int j=0;j<4;++j){
        int i4 = tid + j*512;
        *(float4*)&sh[i4*4] = *(const float4*)&hp[i4*4];
      }
    }
    __syncthreads();
    float ar = br, az = bz, an = bn;
    const float* hb = sh + bl*512;
    for (int k=0;k<512;k+=4){
      float4 h4 = *(const float4*)(hb+k);
      int base = (k>>2)*128 + dl*4;
      uint2 wr = *(const uint2*)(wl + base);
      uint2 wz = *(const uint2*)(wl + 16384 + base);
      uint2 wn = *(const uint2*)(wl + 32768 + base);
      ar += h4.x*bf2f(wr.x&0xffffu) + h4.y*bf2f(wr.x>>16) + h4.z*bf2f(wr.y&0xffffu) + h4.w*bf2f(wr.y>>16);
      az += h4.x*bf2f(wz.x&0xffffu) + h4.y*bf2f(wz.x>>16) + h4.z*bf2f(wz.y&0xffffu) + h4.w*bf2f(wz.y>>16);
      an += h4.x*bf2f(wn.x&0xffffu) + h4.y*bf2f(wn.x>>16) + h4.z*bf2f(wn.y&0xffffu) + h4.w*bf2f(wn.y>>16);
    }
    const float* gi = GI + ((size_t)tt*NB + bglob)*G3;
    float r  = fsig(gi[d] + ar);
    float zz = fsig(gi[512+d] + az);
    float n  = ftanh(gi[1024+d] + r*an);
    float hp = hb[d];
    float hv = (1.0f-zz)*n + zz*hp;
    (hz + (size_t)(t&1)*NB*HID)[(size_t)bglob*HID + d] = hv;
    ob[((size_t)t*NB + bglob)*HID + d] = f2bf(hv);
    __syncthreads();
    setflag(own, (unsigned)(t+1));
  }
}

// ---- Phase D: persistent scan — direct flags; gate GEMM split a/x/hm --------
// WG = (b = wg>>1, dh = wg&1). LDS: Whs[all tq, b, dh-half] 128 KB (swizzled).
__global__ __launch_bounds__(512, 2)
void scanD(const bfraw* __restrict__ Whs, const bfraw* __restrict__ o_p,
           const bfraw* __restrict__ o_h,
           const bfraw* __restrict__ WtT, const bfraw* __restrict__ WmT,
           const float* __restrict__ w_e,
           const bfraw* __restrict__ Wcat, const float* __restrict__ bc,
           float* __restrict__ hmbuf, bfraw* __restrict__ hm_bf,
           bfraw* __restrict__ a_bf, float* __restrict__ Lbuf, float* __restrict__ Gx,
           const float* __restrict__ outW, const float* __restrict__ outb,
           float* __restrict__ out, unsigned* __restrict__ bar)
{
  extern __shared__ char smem[];
  bfraw* whs_l = (bfraw*)smem;                 // 131072 B
  float* pt    = (float*)(smem + 131072);      // 16384 B [16][256]
  float* xlf   = (float*)(smem + 147456);      // 2048 B
  float* hml   = (float*)(smem + 149504);      // 2048 B
  float* c_l   = (float*)(smem + 151552);      // 1024 B
  float* lp0   = (float*)(smem + 152576);      // 1024 B
  float* lp1   = (float*)(smem + 153600);      // 1024 B
  float* l_s   = (float*)(smem + 154624);      // 1024 B
  float* red   = (float*)(smem + 155648);      // 128 B

  const int wg = blockIdx.x, tid = threadIdx.x;
  const int b = wg>>1, dh = wg&1;
  unsigned* pf  = bar;
  unsigned* afl = bar + NWG*FLS;
  unsigned* hfl = bar + 2*NWG*FLS;

  for (int it=0; it<16; ++it){
    int idx = tid + it*512;
    int tq = idx>>5, c = idx&31;
    const bfraw* src = Whs + ((size_t)tq*NB + b)*HID + dh*256 + c*8;
    *(uint4*)&whs_l[tq*256 + ((c ^ (tq&15))<<3)] = *(const uint4*)src;
  }
  const int cc_ = tid&31;
  float we8[8];
  #pragma unroll
  for (int r=0;r<8;++r) we8[r] = w_e[dh*256 + cc_*8 + r];
  __syncthreads();

  // gate-slice geometry (used by both halves)
  const int gw = tid>>6, gl = tid&63, gfr = gl&15, gfg = gl>>4;
  const int m0w = gw*16;
  const int n0g = (wg&127)*16;          // n-slice for gates (wg<128) / Gx (wg>=128)
  const bfraw* wrowA = Wcat + (size_t)(n0g+gfr)*1536;

  #pragma clang loop unroll(disable)
  for (int t=0; t<TSEQ; ++t){
    const int rs = (t+1)&1;
    const bfraw* hmr = hm_bf + (size_t)rs*65536;
    const float* hpr = hmbuf + (size_t)rs*65536;
    bfraw* hmw = hm_bf + (size_t)(t&1)*65536;
    float* hpw = hmbuf + (size_t)(t&1)*65536;

    if (t > 0) pollN(hfl, 128, (unsigned)t);

    // ---- stage x_t[b], hm[b] ----
    if (tid < 64){
      uint4 u = *(const uint4*)(o_h + ((size_t)t*NB + b)*HID + tid*8);
      float4 f0, f1;
      f0.x=bf2f(u.x&0xffffu); f0.y=bf2f(u.x>>16); f0.z=bf2f(u.y&0xffffu); f0.w=bf2f(u.y>>16);
      f1.x=bf2f(u.z&0xffffu); f1.y=bf2f(u.z>>16); f1.z=bf2f(u.w&0xffffu); f1.w=bf2f(u.w>>16);
      *(float4*)&xlf[tid*8]   = f0;
      *(float4*)&xlf[tid*8+4] = f1;
    } else if (tid < 192){
      int i2 = tid - 64;
      *(float4*)&hml[i2*4] = *(const float4*)(hpr + (size_t)b*HID + i2*4);
    }
    __syncthreads();

    // ---- c[b, e] for e in dh-half ----
    {
      const int el = tid>>1, kh = tid&1;
      const bfraw* wt = WtT + (size_t)(dh*256+el)*HID + kh*256;
      const bfraw* wm = WmT + (size_t)(dh*256+el)*HID + kh*256;
      const float* xv = xlf + kh*256;
      const float* hv = hml + kh*256;
      float acc = 0.f;
      #pragma unroll 4
      for (int k8=0;k8<32;++k8){
        uint4 wu = *(const uint4*)(wt+k8*8);
        uint4 mu = *(const uint4*)(wm+k8*8);
        float4 x0 = *(const float4*)(xv+k8*8), x1 = *(const float4*)(xv+k8*8+4);
        float4 h0 = *(const float4*)(hv+k8*8), h1 = *(const float4*)(hv+k8*8+4);
        acc += x0.x*bf2f(wu.x&0xffffu) + x0.y*bf2f(wu.x>>16) + x0.z*bf2f(wu.y&0xffffu) + x0.w*bf2f(wu.y>>16);
        acc += x1.x*bf2f(wu.z&0xffffu) + x1.y*bf2f(wu.z>>16) + x1.z*bf2f(wu.w&0xffffu) + x1.w*bf2f(wu.w>>16);
        acc += h0.x*bf2f(mu.x&0xffffu) + h0.y*bf2f(mu.x>>16) + h0.z*bf2f(mu.y&0xffffu) + h0.w*bf2f(mu.y>>16);
        acc += h1.x*bf2f(mu.z&0xffffu) + h1.y*bf2f(mu.z>>16) + h1.z*bf2f(mu.w&0xffffu) + h1.w*bf2f(mu.w>>16);
      }
      acc += __shfl_xor(acc, 1);
      if (kh == 0) c_l[el] = acc;
    }
    __syncthreads();

    // ---- logit partials over this d-half ----
    {
      const int tqs = tid>>5;
      float c8[8];
      *(float4*)&c8[0] = *(const float4*)&c_l[cc_*8];
      *(float4*)&c8[4] = *(const float4*)&c_l[cc_*8+4];
      #pragma unroll 2
      for (int i=0;i<16;++i){
        int tq = tqs + i*16;
        uint4 u = *(const uint4*)&whs_l[tq*256 + ((cc_ ^ (tq&15))<<3)];
        float s = 0.f;
        #pragma unroll
        for (int j=0;j<4;++j){
          unsigned uu = ((const unsigned*)&u)[j];
          s += ftanh(bf2f(uu&0xffffu) + c8[j*2])   * we8[j*2];
          s += ftanh(bf2f(uu>>16)     + c8[j*2+1]) * we8[j*2+1];
        }
        #pragma unroll
        for (int off=16; off; off>>=1) s += __shfl_xor(s, off);
        if (cc_ == 0) lp0[tq] = s;
      }
    }
    __syncthreads();
    if (tid < 64) *(float4*)&Lbuf[(size_t)wg*256 + tid*4] = *(const float4*)&lp0[tid*4];
    __syncthreads();
    setflag(&pf[wg*FLS], (unsigned)(t+1));

    // ---- issue o_p prefetch ----
    const int dgrp = tid&31, tqs2 = tid>>5, d8 = dgrp*8;
    const bfraw* opb = o_p + (size_t)b*HID + dh*256 + d8;
    uint4 uu[16];
    #pragma unroll
    for (int i=0;i<16;++i)
      uu[i] = *(const uint4*)(opb + (size_t)(tqs2*16 + i)*NB*HID);

    // ---- overlapped gate partials (hide under pairsync + softmax) ----
    f32x4 accA = {0.f,0.f,0.f,0.f};
    if (wg < 128){
      // hm-segment (depends only on hm(t-1))
      const bfraw* hrow = hmr + (size_t)(m0w+gfr)*HID;
      #pragma unroll
      for (int kk=0; kk<16; ++kk){
        short8 af = *(const short8*)(hrow + kk*32 + gfg*8);
        short8 bv = *(const short8*)(wrowA + 1024 + kk*32 + gfg*8);
        accA = MFMA16(af, bv, accA, 0,0,0);
      }
    } else {
      // x-segment -> Gx (depends only on o_h[t])
      f32x4 accB = {0.f,0.f,0.f,0.f};
      const bfraw* xrow = o_h + ((size_t)t*NB + m0w+gfr)*HID;
      #pragma unroll
      for (int kk=0; kk<16; ++kk){
        short8 af = *(const short8*)(xrow + kk*32 + gfg*8);
        short8 bv = *(const short8*)(wrowA + 512 + kk*32 + gfg*8);
        accB = MFMA16(af, bv, accB, 0,0,0);
      }
      #pragma unroll
      for (int rr=0; rr<4; ++rr)
        Gx[(size_t)(m0w + gfg*4 + rr)*2048 + n0g + gfr] = accB[rr];
    }

    // ---- pairwise sync + read buddy partials ----
    if (tid == 0) spin_ge(&pf[(wg^1)*FLS], (unsigned)(t+1));
    __syncthreads();
    if (tid < 64) *(float4*)&lp1[tid*4] = bpf4(&Lbuf[(size_t)(wg^1)*256 + tid*4]);
    __syncthreads();

    // ---- softmax over 256 logits ----
    {
      const int lane = tid&63;
      float v = -1e30f, e = 0.f;
      if (tid < TSEQ){
        v = lp0[tid] + lp1[tid];
        float m = v;
        #pragma unroll
        for (int off=32; off; off>>=1) m = fmaxf(m, __shfl_xor(m, off));
        if (lane==0) red[tid>>6] = m;
      }
      __syncthreads();
      float mx = fmaxf(fmaxf(red[0],red[1]), fmaxf(red[2],red[3]));
      if (tid < TSEQ){
        e = __expf(v - mx);
        float s2 = e;
        #pragma unroll
        for (int off=32; off; off>>=1) s2 += __shfl_xor(s2, off);
        if (lane==0) red[8+(tid>>6)] = s2;
      }
      __syncthreads();
      float S = red[8]+red[9]+red[10]+red[11];
      if (tid < TSEQ) l_s[tid] = e * __builtin_amdgcn_rcpf(S);
      __syncthreads();
    }

    // ---- consume prefetched o_p -> a_t d-half ----
    {
      float a0=0,a1=0,a2=0,a3=0,a4=0,a5=0,a6=0,a7=0;
      #pragma unroll
      for (int i=0;i<16;++i){
        float al = l_s[tqs2*16 + i];
        uint4 u = uu[i];
        a0 += al*bf2f(u.x&0xffffu); a1 += al*bf2f(u.x>>16);
        a2 += al*bf2f(u.y&0xffffu); a3 += al*bf2f(u.y>>16);
        a4 += al*bf2f(u.z&0xffffu); a5 += al*bf2f(u.z>>16);
        a6 += al*bf2f(u.w&0xffffu); a7 += al*bf2f(u.w>>16);
      }
      *(float4*)&pt[tqs2*256+d8]   = (float4){a0,a1,a2,a3};
      *(float4*)&pt[tqs2*256+d8+4] = (float4){a4,a5,a6,a7};
      __syncthreads();
      if (tid < 256){
        float sA = 0.f;
        #pragma unroll
        for (int ss=0;ss<16;++ss) sA += pt[ss*256 + tid];
        float sB = __shfl_down(sA, 1);
        if ((tid&1)==0){
          unsigned pk = (unsigned)f2bf(sA) | ((unsigned)f2bf(sB)<<16);
          *(unsigned*)(a_bf + (size_t)b*HID + dh*256 + tid) = pk;
        }
      }
    }
    __syncthreads();
    setflag(&afl[wg*FLS], (unsigned)(t+1));   // covers a_bf half (and Gx for wg>=128)

    // ---- gates: a-segment + combine + state update (wg<128) ----
    if (wg < 128){
      pollN(afl, 256, (unsigned)(t+1));
      const bfraw* arow = a_bf + (size_t)(m0w+gfr)*HID;
      #pragma unroll
      for (int kk=0; kk<16; ++kk){
        short8 af = *(const short8*)(arow + kk*32 + gfg*8);
        short8 bv = *(const short8*)(wrowA + kk*32 + gfg*8);
        accA = MFMA16(af, bv, accA, 0,0,0);
      }
      const int np = n0g + gfr, dd = np>>2, g = np&3;
      #pragma unroll
      for (int rr=0; rr<4; ++rr){
        float x0 = accA[rr] + Gx[(size_t)(m0w + gfg*4 + rr)*2048 + np];
        float x1 = __shfl_xor(x0, 1);
        float x2 = __shfl_xor(x0, 2);
        float x3 = __shfl_xor(x1, 2);
        if (g==0){
          int b3 = m0w + gfg*4 + rr;
          float hp = hpr[(size_t)b3*HID + dd];
          float rg = fsig(x0 + bc[dd]);
          float zg = fsig(x1 + bc[512+dd]);
          float gn = ftanh(x2 + bc[1024+dd] + rg*(x3 + bc[1536+dd]));
          float h = (1.f-zg)*gn + zg*hp;
          hpw[(size_t)b3*HID + dd] = h;
          hmw[(size_t)b3*HID + dd] = f2bf(h);
        }
      }
      __syncthreads();
      setflag(&hfl[wg*FLS], (unsigned)(t+1));
    }
  }

  // ---- output head ----
  if (wg == 0){
    pollN(hfl, 128, (unsigned)TSEQ);
    if (tid < NB*3){
      const float* hf = hmbuf + (size_t)((TSEQ-1)&1)*65536;
      int b2 = tid/3, c = tid%3;
      float acc = outb[c];
      const float* h = hf + (size_t)b2*HID;
      const float* w = outW + (size_t)c*HID;
      for (int d2=0; d2<HID; ++d2) acc = fmaf(h[d2], w[d2], acc);
      out[tid] = fmaxf(acc, 0.f);
    }
  }
}

extern "C" void kernel_launch(void* const* d_in, const int* in_sizes, int n_in,
                              void* d_out, int out_size, void* d_ws, size_t ws_size,
                              hipStream_t stream)
{
  const float* Ep    = (const float*)d_in[0];
  const float* Eh    = (const float*)d_in[1];
  const float* p_W   = (const float*)d_in[2];
  const float* p_b   = (const float*)d_in[3];
  const float* h_W   = (const float*)d_in[4];
  const float* h_b   = (const float*)d_in[5];
  const float* pgWih = (const float*)d_in[6];
  const float* pgWhh = (const float*)d_in[7];
  const float* pgbih = (const float*)d_in[8];
  const float* pgbhh = (const float*)d_in[9];
  const float* hgWih = (const float*)d_in[10];
  const float* hgWhh = (const float*)d_in[11];
  const float* hgbih = (const float*)d_in[12];
  const float* hgbhh = (const float*)d_in[13];
  const float* W_s   = (const float*)d_in[14];
  const float* W_t   = (const float*)d_in[15];
  const float* w_e   = (const float*)d_in[16];
  const float* W_m   = (const float*)d_in[17];
  const float* mWih  = (const float*)d_in[18];
  const float* mWhh  = (const float*)d_in[19];
  const float* mbih  = (const float*)d_in[20];
  const float* mbhh  = (const float*)d_in[21];
  const float* outW  = (const float*)d_in[22];
  const float* outb  = (const float*)d_in[23];

  const size_t OB    = (size_t)TSEQ*NB*HID*sizeof(bfraw);
  const size_t RB    = OB;
  const size_t WFB   = (size_t)G3*INDIM*sizeof(bfraw);
  const size_t SQB   = (size_t)HID*HID*sizeof(bfraw);
  const size_t WHHB  = (size_t)G3*HID*sizeof(bfraw);
  const size_t WCATB = (size_t)2048*1536*sizeof(bfraw);
  const size_t BARB  = (size_t)4*NWG*FLS*sizeof(unsigned);
  const size_t needed = 2*OB + RB + 2*WFB + 3*SQB + 2*WHHB + WCATB
                        + 8192 + 2*6144
                        + 4*262144 + 2*262144 + 2*131072
                        + BARB;
  if (ws_size < needed) return;

  char* p = (char*)d_ws;
  bfraw* o_p_bf = (bfraw*)p; p += OB;
  bfraw* o_h_bf = (bfraw*)p; p += OB;
  char*  Rreg   = p;         p += RB;
  bfraw* Wfp_bf = (bfraw*)p; p += WFB;
  bfraw* Wfh_bf = (bfraw*)p; p += WFB;
  bfraw* WsT_bf = (bfraw*)p; p += SQB;
  bfraw* WtT_bf = (bfraw*)p; p += SQB;
  bfraw* WmT_bf = (bfraw*)p; p += SQB;
  bfraw* Whhp_bf= (bfraw*)p; p += WHHB;
  bfraw* Whhh_bf= (bfraw*)p; p += WHHB;
  bfraw* Wcat_bf= (bfraw*)p; p += WCATB;
  float* bc     = (float*)p; p += 8192;
  float* bfp    = (float*)p; p += 6144;
  float* bfh    = (float*)p; p += 6144;
  float* hst    = (float*)p; p += 4*262144;
  float* hmbuf  = (float*)p; p += 2*262144;
  bfraw* hm_bf  = (bfraw*)p; p += 2*131072;
  unsigned* bar = (unsigned*)p; p += BARB;

  bfraw* pWT_bf = (bfraw*)Rreg;
  bfraw* hWT_bf = (bfraw*)(Rreg + (size_t)INDIM*HID*sizeof(bfraw));
  float* GIp_c  = (float*)Rreg;
  float* GIh_c  = (float*)(Rreg + (size_t)CH*NB*G3*sizeof(float));
  bfraw* Whs_bf = (bfraw*)Rreg;
  // phase-D scratch overlays the dead Wf fold region (4.7 MB total)
  float* Lbuf   = (float*)Wfp_bf;                          // 256 KB
  bfraw* a_bf   = (bfraw*)((char*)Wfp_bf + 2097152);       // 128 KB
  float* Gx     = (float*)((char*)Wfp_bf + WFB);           // 1 MB (in Wfh region)

  (void)hipFuncSetAttribute((const void*)scanB, hipFuncAttributeMaxDynamicSharedMemorySize, 131072);
  (void)hipFuncSetAttribute((const void*)scanD, hipFuncAttributeMaxDynamicSharedMemorySize, 155776);

  dim3 b256(256), b512(512);

  init_k<<<dim3(128), b256, 0, stream>>>(bar);
  hminit_k<<<dim3(512), b256, 0, stream>>>(hmbuf, hm_bf);

  // ---- Phase A: weight prep ----
  tconv_k<<<dim3(INDIM/32, HID/32), b256, 0, stream>>>(p_W, pWT_bf, HID, INDIM);
  tconv_k<<<dim3(INDIM/32, HID/32), b256, 0, stream>>>(h_W, hWT_bf, HID, INDIM);
  tconv_k<<<dim3(HID/32, HID/32),  b256, 0, stream>>>(W_s, WsT_bf, HID, HID);
  tconv_k<<<dim3(HID/32, HID/32),  b256, 0, stream>>>(W_t, WtT_bf, HID, HID);
  tconv_k<<<dim3(HID/32, HID/32),  b256, 0, stream>>>(W_m, WmT_bf, HID, HID);
  cvt_k<<<dim3((G3*HID)/1024), b256, 0, stream>>>(pgWhh, Whhp_bf, G3*HID);
  cvt_k<<<dim3((G3*HID)/1024), b256, 0, stream>>>(hgWhh, Whhh_bf, G3*HID);
  wcat_k<<<dim3(3072), b256, 0, stream>>>(mWih, mWhh, Wcat_bf);
  bpack_k<<<dim3(2), b256, 0, stream>>>(mbih, mbhh, bc);
  fuse_bias_k<<<dim3(G3/256), b256, 0, stream>>>(pgWih, pgbih, p_b, bfp);
  fuse_bias_k<<<dim3(G3/256), b256, 0, stream>>>(hgWih, hgbih, h_b, bfh);
  mgemm<float, bfraw, false><<<dim3(INDIM/128, G3/128, 2), b256, 0, stream>>>(
    pgWih, hgWih, pWT_bf, hWT_bf, nullptr, nullptr, Wfp_bf, Wfh_bf,
    HID, HID, HID, INDIM);

  // ---- Phase B: chunked GI GEMM + persistent scan ----
  for (int c = 0; c < TSEQ/CH; ++c){
    mgemm<float, float, true><<<dim3(G3/128, (CH*NB)/128, 2), b256, 0, stream>>>(
      Ep + (size_t)c*CH*NB*INDIM, Eh + (size_t)c*CH*NB*INDIM,
      Wfp_bf, Wfh_bf, bfp, bfh, GIp_c, GIh_c,
      INDIM, INDIM, INDIM, G3);
    scanB<<<dim3(NWG), b512, 131072, stream>>>(
      GIp_c, GIh_c, Whhp_bf, Whhh_bf, pgbhh, hgbhh,
      hst, o_p_bf, o_h_bf, c*CH, bar);
  }

  // ---- Phase C: Whs = o_p @ W_s ----
  mgemm<bfraw, bfraw, false><<<dim3(HID/128, (TSEQ*NB)/128, 1), b256, 0, stream>>>(
    o_p_bf, o_p_bf, WsT_bf, WsT_bf, nullptr, nullptr, Whs_bf, Whs_bf,
    HID, HID, HID, HID);

  // ---- Phase D: persistent scan ----
  scanD<<<dim3(NWG), b512, 155776, stream>>>(
    Whs_bf, o_p_bf, o_h_bf, WtT_bf, WmT_bf, w_e, Wcat_bf, bc,
    hmbuf, hm_bf, a_bf, Lbuf, Gx,
    outW, outb, (float*)d_out, bar);
}

// Round 14
// 20772.887 us; speedup vs baseline: 1.5265x; 1.0663x over previous
//
#include <hip/hip_runtime.h>
#include <cstddef>

#define TSEQ 256
#define NB   128
#define HID  512
#define G3   1536
#define INDIM 768
#define CH   16
#define NWG  256
#define FLS  32   // u32 stride between flag lines (128 B)

typedef unsigned short bfraw;
using short8 = __attribute__((ext_vector_type(8))) short;
using f32x4  = __attribute__((ext_vector_type(4))) float;

#define MFMA16 __builtin_amdgcn_mfma_f32_16x16x32_bf16

__device__ __forceinline__ float bf2f(unsigned int u){ return __uint_as_float(u<<16); }
__device__ __forceinline__ bfraw f2bf(float f){
  unsigned int u = __float_as_uint(f);
  u += 0x7fffu + ((u>>16)&1u);
  return (bfraw)(u>>16);
}
__device__ __forceinline__ float fsig(float x){
  return __builtin_amdgcn_rcpf(1.0f + __expf(-x));
}
__device__ __forceinline__ float ftanh(float x){
  return 1.0f - 2.0f*__builtin_amdgcn_rcpf(1.0f + __expf(2.0f*x));
}
// coherence-point (sc1) 16B read — tiny pairwise payloads only
__device__ __forceinline__ float4 bpf4(const void* p){
  unsigned long long a = __hip_atomic_load((const unsigned long long*)p,     __ATOMIC_RELAXED, __HIP_MEMORY_SCOPE_AGENT);
  unsigned long long b = __hip_atomic_load((const unsigned long long*)p + 1, __ATOMIC_RELAXED, __HIP_MEMORY_SCOPE_AGENT);
  union{ unsigned long long q[2]; float4 f; } cv; cv.q[0]=a; cv.q[1]=b; return cv.f;
}

// ---- relaxed spin with exponential backoff ----
__device__ __forceinline__ void spin_ge(unsigned* p, unsigned epoch){
  int sp = 0;
  while (__hip_atomic_load(p, __ATOMIC_RELAXED, __HIP_MEMORY_SCOPE_AGENT) < epoch){
    if (sp < 3){ __builtin_amdgcn_s_sleep(1); ++sp; }
    else        __builtin_amdgcn_s_sleep(16);
  }
}

// ---- direct flag wait: poll n producer flags in parallel, ONE acquire at wakeup ----
__device__ __forceinline__ void pollN(unsigned* flags, int n, unsigned epoch){
  const int tid = threadIdx.x;
  if (tid < n) spin_ge(&flags[tid*FLS], epoch);
  __syncthreads();
  if (tid == 0)
    (void)__hip_atomic_load(&flags[0], __ATOMIC_ACQUIRE, __HIP_MEMORY_SCOPE_AGENT);
  __syncthreads();
}
__device__ __forceinline__ void setflag(unsigned* f, unsigned v){
  if (threadIdx.x == 0)
    __hip_atomic_store(f, v, __ATOMIC_RELEASE, __HIP_MEMORY_SCOPE_AGENT);
}

__global__ void init_k(unsigned* bar){
  int i = blockIdx.x*256 + threadIdx.x;
  if (i < 4*NWG*FLS) bar[i] = 0u;
}

__global__ void hminit_k(float* hmbuf, bfraw* hm_bf){
  int i = blockIdx.x*256 + threadIdx.x;   // 131072 (both slots)
  hmbuf[i] = 1.0f;
  hm_bf[i] = (bfraw)0x3f80;
}

// ---- transpose+convert: in fp32 [R][Cc] -> out bf16 [Cc][R] ----
__global__ __launch_bounds__(256)
void tconv_k(const float* __restrict__ in, bfraw* __restrict__ out, int R, int Cc){
  __shared__ float t[32][33];
  int c0 = blockIdx.x*32, r0 = blockIdx.y*32;
  int tx = threadIdx.x&31, ty = threadIdx.x>>5;
  #pragma unroll
  for (int i=0;i<32;i+=8) t[ty+i][tx] = in[(size_t)(r0+ty+i)*Cc + c0+tx];
  __syncthreads();
  #pragma unroll
  for (int i=0;i<32;i+=8) out[(size_t)(c0+ty+i)*R + r0+tx] = f2bf(t[tx][ty+i]);
}

__global__ void cvt_k(const float* __restrict__ in, bfraw* __restrict__ out, int n){
  int i = (blockIdx.x*256 + threadIdx.x)*4;
  if (i >= n) return;
  float4 v = *(const float4*)(in+i);
  uint2 o;
  o.x = (unsigned)f2bf(v.x) | ((unsigned)f2bf(v.y)<<16);
  o.y = (unsigned)f2bf(v.z) | ((unsigned)f2bf(v.w)<<16);
  *(uint2*)(out+i) = o;
}

// W_cat[n'][k], n'=dd*4+g, k<1536 (segs: a[0,512) x[512,1024) -> mWih; hm[1024,1536) -> mWhh)
__global__ void wcat_k(const float* __restrict__ mWih, const float* __restrict__ mWhh,
                       bfraw* __restrict__ Wcat){
  size_t gid = (size_t)blockIdx.x*256 + threadIdx.x;
  int np = (int)(gid / 384);
  int k4 = ((int)(gid % 384))*4;
  int dd = np>>2, g = np&3;
  float v[4];
  #pragma unroll
  for (int j=0;j<4;++j){
    int k = k4+j; float x = 0.f;
    if (g==0)      x = (k<1024) ? mWih[(size_t)dd*1024 + k]        : mWhh[(size_t)dd*512 + (k-1024)];
    else if (g==1) x = (k<1024) ? mWih[(size_t)(512+dd)*1024 + k]  : mWhh[(size_t)(512+dd)*512 + (k-1024)];
    else if (g==2) x = (k<1024) ? mWih[(size_t)(1024+dd)*1024 + k] : 0.f;
    else           x = (k<1024) ? 0.f : mWhh[(size_t)(1024+dd)*512 + (k-1024)];
    v[j] = x;
  }
  uint2 o;
  o.x = (unsigned)f2bf(v[0]) | ((unsigned)f2bf(v[1])<<16);
  o.y = (unsigned)f2bf(v[2]) | ((unsigned)f2bf(v[3])<<16);
  *(uint2*)(Wcat + (size_t)np*1536 + k4) = o;
}

__global__ void bpack_k(const float* __restrict__ mbih, const float* __restrict__ mbhh,
                        float* __restrict__ bc){
  int dd = blockIdx.x*256 + threadIdx.x;
  if (dd >= 512) return;
  bc[dd]      = mbih[dd] + mbhh[dd];
  bc[512+dd]  = mbih[512+dd] + mbhh[512+dd];
  bc[1024+dd] = mbih[1024+dd];
  bc[1536+dd] = mbhh[1024+dd];
}

__global__ void fuse_bias_k(const float* __restrict__ Wih, const float* __restrict__ bih,
                            const float* __restrict__ pb, float* __restrict__ bout)
{
  int g = blockIdx.x*256 + threadIdx.x;
  if (g >= G3) return;
  float acc = bih[g];
  const float* w = Wih + (size_t)g*HID;
  for (int e=0;e<HID;e+=4){
    float4 wv = *(const float4*)(w+e);
    float4 pv = *(const float4*)(pb+e);
    acc += wv.x*pv.x + wv.y*pv.y + wv.z*pv.z + wv.w*pv.w;
  }
  bout[g] = acc;
}

// ---- MFMA bf16 GEMM: C[MxN] = A[MxK] * B^T (+bias); z selects operand set ----
template<typename TA, typename TC, bool BIAS>
__global__ __launch_bounds__(256)
void mgemm(const TA* __restrict__ A0, const TA* __restrict__ A1,
           const bfraw* __restrict__ B0, const bfraw* __restrict__ B1,
           const float* __restrict__ bias0, const float* __restrict__ bias1,
           TC* __restrict__ C0, TC* __restrict__ C1,
           int K, int lda, int ldb, int ldc)
{
  const TA* A = blockIdx.z ? A1 : A0;
  const bfraw* B = blockIdx.z ? B1 : B0;
  const float* bias = blockIdx.z ? bias1 : bias0;
  TC* C = blockIdx.z ? C1 : C0;
  __shared__ bfraw Al[128*40];
  __shared__ bfraw Bl[128*40];
  const int tid = threadIdx.x;
  const size_t m0 = (size_t)blockIdx.y*128, n0 = (size_t)blockIdx.x*128;
  const int w = tid>>6, l = tid&63;
  const int wr = (w>>1)*64, wc = (w&1)*64;
  const int fr = l&15, fg = l>>4;
  f32x4 acc[4][4];
  #pragma unroll
  for (int i=0;i<4;++i)
    #pragma unroll
    for (int j=0;j<4;++j) acc[i][j] = (f32x4){0.f,0.f,0.f,0.f};

  const int srow = tid>>1, skc = (tid&1)*16;
  for (int k0=0; k0<K; k0+=32){
    if constexpr (sizeof(TA)==4){
      const float* ap = (const float*)A + (m0+srow)*lda + k0 + skc;
      float4 v0=*(const float4*)ap, v1=*(const float4*)(ap+4),
             v2=*(const float4*)(ap+8), v3=*(const float4*)(ap+12);
      uint4 w0, w1;
      w0.x=(unsigned)f2bf(v0.x)|((unsigned)f2bf(v0.y)<<16);
      w0.y=(unsigned)f2bf(v0.z)|((unsigned)f2bf(v0.w)<<16);
      w0.z=(unsigned)f2bf(v1.x)|((unsigned)f2bf(v1.y)<<16);
      w0.w=(unsigned)f2bf(v1.z)|((unsigned)f2bf(v1.w)<<16);
      w1.x=(unsigned)f2bf(v2.x)|((unsigned)f2bf(v2.y)<<16);
      w1.y=(unsigned)f2bf(v2.z)|((unsigned)f2bf(v2.w)<<16);
      w1.z=(unsigned)f2bf(v3.x)|((unsigned)f2bf(v3.y)<<16);
      w1.w=(unsigned)f2bf(v3.z)|((unsigned)f2bf(v3.w)<<16);
      *(uint4*)&Al[srow*40+skc]   = w0;
      *(uint4*)&Al[srow*40+skc+8] = w1;
    } else {
      const bfraw* ap = (const bfraw*)A + (m0+srow)*lda + k0 + skc;
      *(uint4*)&Al[srow*40+skc]   = *(const uint4*)ap;
      *(uint4*)&Al[srow*40+skc+8] = *(const uint4*)(ap+8);
    }
    {
      const bfraw* bp = B + (n0+srow)*ldb + k0 + skc;
      *(uint4*)&Bl[srow*40+skc]   = *(const uint4*)bp;
      *(uint4*)&Bl[srow*40+skc+8] = *(const uint4*)(bp+8);
    }
    __syncthreads();
    short8 af[4], bfr[4];
    #pragma unroll
    for (int i=0;i<4;++i) af[i]  = *(const short8*)&Al[(wr+i*16+fr)*40 + fg*8];
    #pragma unroll
    for (int j=0;j<4;++j) bfr[j] = *(const short8*)&Bl[(wc+j*16+fr)*40 + fg*8];
    #pragma unroll
    for (int i=0;i<4;++i)
      #pragma unroll
      for (int j=0;j<4;++j)
        acc[i][j] = MFMA16(af[i], bfr[j], acc[i][j], 0,0,0);
    __syncthreads();
  }
  #pragma unroll
  for (int i=0;i<4;++i){
    #pragma unroll
    for (int j=0;j<4;++j){
      size_t n = n0 + wc + j*16 + fr;
      float bv = BIAS ? bias[n] : 0.f;
      #pragma unroll
      for (int r=0;r<4;++r){
        size_t m = m0 + wr + i*16 + fg*4 + r;
        float v = acc[i][j][r] + bv;
        if constexpr (sizeof(TC)==2) ((bfraw*)C)[m*ldc + n] = f2bf(v);
        else                         ((float*)C)[m*ldc + n] = v;
      }
    }
  }
}

// ---- Phase B: persistent GRU scan; 16-WG-group DIRECT flag sync (r13-verbatim) ----
__global__ __launch_bounds__(512, 2)
void scanB(const float* __restrict__ GIp, const float* __restrict__ GIh,
           const bfraw* __restrict__ Whhp, const bfraw* __restrict__ Whhh,
           const float* __restrict__ bhhp, const float* __restrict__ bhhh,
           float* __restrict__ hst, bfraw* __restrict__ o_p, bfraw* __restrict__ o_h,
           int c0, unsigned* __restrict__ bar)
{
  extern __shared__ char smem[];
  bfraw* wl = (bfraw*)smem;                  // 98304 B
  float* sh = (float*)(smem + 98304);        // 32768 B
  const int wg = blockIdx.x;
  const int z = wg>>7, rem = wg&127;
  const int bg = rem>>4, dg = rem&15;
  const float* GI  = z ? GIh : GIp;
  const bfraw* Wb  = z ? Whhh : Whhp;
  const float* bhh = z ? bhhh : bhhp;
  bfraw* ob = z ? o_h : o_p;
  float* hz = hst + (size_t)z*2*NB*HID;
  const int tid = threadIdx.x;
  unsigned* bfl = bar + 3*NWG*FLS;
  unsigned* grp = bfl + (size_t)(z*128 + bg*16)*FLS;
  unsigned* own = bfl + (size_t)wg*FLS;

  #pragma unroll
  for (int g=0; g<3; ++g){
    const unsigned* src = (const unsigned*)(Wb + (size_t)(g*512 + dg*32)*512);
    for (int j=0; j<16; ++j){
      int iu = tid + j*512;
      unsigned v = src[iu];
      int d = iu>>8, kk = (iu&255)*2;
      int idx0 = g*16384 + (kk>>2)*128 + d*4 + (kk&3);
      *((unsigned*)wl + (idx0>>1)) = v;
    }
  }
  __syncthreads();

  const int bl = tid>>5, dl = tid&31;
  const int d = dg*32+dl, bglob = bg*16+bl;
  const float br = bhh[d], bz = bhh[512+d], bn = bhh[1024+d];

  #pragma clang loop unroll(disable)
  for (int tt=0; tt<CH; ++tt){
    const int t = c0+tt;
    if (t > 0) pollN(grp, 16, (unsigned)t);
    if (t == 0){
      for (int j=0;j<4;++j){
        int i4 = tid + j*512;
        *(float4*)&sh[i4*4] = (float4){1.f,1.f,1.f,1.f};
      }
    } else {
      const float* hp = hz + (size_t)((t-1)&1)*NB*HID + (size_t)bg*16*HID;
      for (int j=0;j<4;++j){
        int i4 = tid + j*512;
        *(float4*)&sh[i4*4] = *(const float4*)&hp[i4*4];
      }
    }
    __syncthreads();
    float ar = br, az = bz, an = bn;
    const float* hb = sh + bl*512;
    for (int k=0;k<512;k+=4){
      float4 h4 = *(const float4*)(hb+k);
      int base = (k>>2)*128 + dl*4;
      uint2 wr = *(const uint2*)(wl + base);
      uint2 wz = *(const uint2*)(wl + 16384 + base);
      uint2 wn = *(const uint2*)(wl + 32768 + base);
      ar += h4.x*bf2f(wr.x&0xffffu) + h4.y*bf2f(wr.x>>16) + h4.z*bf2f(wr.y&0xffffu) + h4.w*bf2f(wr.y>>16);
      az += h4.x*bf2f(wz.x&0xffffu) + h4.y*bf2f(wz.x>>16) + h4.z*bf2f(wz.y&0xffffu) + h4.w*bf2f(wz.y>>16);
      an += h4.x*bf2f(wn.x&0xffffu) + h4.y*bf2f(wn.x>>16) + h4.z*bf2f(wn.y&0xffffu) + h4.w*bf2f(wn.y>>16);
    }
    const float* gi = GI + ((size_t)tt*NB + bglob)*G3;
    float r  = fsig(gi[d] + ar);
    float zz = fsig(gi[512+d] + az);
    float n  = ftanh(gi[1024+d] + r*an);
    float hp = hb[d];
    float hv = (1.0f-zz)*n + zz*hp;
    (hz + (size_t)(t&1)*NB*HID)[(size_t)bglob*HID + d] = hv;
    ob[((size_t)t*NB + bglob)*HID + d] = f2bf(hv);
    __syncthreads();
    setflag(own, (unsigned)(t+1));
  }
}

// ---- Phase D: persistent scan — low-fan-in flags; gates sliced 16b x 128n ----
// Pair role: WG = (b = wg>>1, dh = wg&1). Gate role (wg<128): bgrp=wg>>4, ddg=wg&15.
__global__ __launch_bounds__(512, 2)
void scanD(const bfraw* __restrict__ Whs, const bfraw* __restrict__ o_p,
           const bfraw* __restrict__ o_h,
           const bfraw* __restrict__ WtT, const bfraw* __restrict__ WmT,
           const float* __restrict__ w_e,
           const bfraw* __restrict__ Wcat, const float* __restrict__ bc,
           float* __restrict__ hmbuf, bfraw* __restrict__ hm_bf,
           bfraw* __restrict__ a_bf, float* __restrict__ Lbuf, float* __restrict__ Gx,
           const float* __restrict__ outW, const float* __restrict__ outb,
           float* __restrict__ out, unsigned* __restrict__ bar)
{
  extern __shared__ char smem[];
  bfraw* whs_l = (bfraw*)smem;                 // 131072 B
  float* pt    = (float*)(smem + 131072);      // 16384 B [16][256]
  float* xlf   = (float*)(smem + 147456);      // 2048 B
  float* hml   = (float*)(smem + 149504);      // 2048 B
  float* c_l   = (float*)(smem + 151552);      // 1024 B
  float* lp0   = (float*)(smem + 152576);      // 1024 B
  float* lp1   = (float*)(smem + 153600);      // 1024 B
  float* l_s   = (float*)(smem + 154624);      // 1024 B
  float* red   = (float*)(smem + 155648);      // 128 B

  const int wg = blockIdx.x, tid = threadIdx.x;
  const int b = wg>>1, dh = wg&1;
  unsigned* pf  = bar;
  unsigned* afl = bar + NWG*FLS;
  unsigned* hfl = bar + 2*NWG*FLS;

  for (int it=0; it<16; ++it){
    int idx = tid + it*512;
    int tq = idx>>5, c = idx&31;
    const bfraw* src = Whs + ((size_t)tq*NB + b)*HID + dh*256 + c*8;
    *(uint4*)&whs_l[tq*256 + ((c ^ (tq&15))<<3)] = *(const uint4*)src;
  }
  const int cc_ = tid&31;
  float we8[8];
  #pragma unroll
  for (int r=0;r<8;++r) we8[r] = w_e[dh*256 + cc_*8 + r];
  __syncthreads();

  // gate/x-slice geometry: slice id s = wg&127 -> bgrp=s>>4 (16 b), ddg=s&15 (128 n)
  const int gs = wg&127, gbgrp = gs>>4, gddg = gs&15;
  const int gw = tid>>6, gl = tid&63, gfr = gl&15, gfg = gl>>4;
  const int n0w = gddg*128 + gw*16;          // wave's 16-n tile
  const int mb0 = gbgrp*16;                  // slice's 16-b block
  const bfraw* wrowA = Wcat + (size_t)(n0w+gfr)*1536;

  #pragma clang loop unroll(disable)
  for (int t=0; t<TSEQ; ++t){
    const int rs = (t+1)&1;
    const bfraw* hmr = hm_bf + (size_t)rs*65536;
    const float* hpr = hmbuf + (size_t)rs*65536;
    bfraw* hmw = hm_bf + (size_t)(t&1)*65536;
    float* hpw = hmbuf + (size_t)(t&1)*65536;

    // ---- step start: hm(t-1) ready — low-fan-in polls ----
    if (t > 0){
      if (tid < 16) spin_ge(&hfl[((b>>4)*16 + tid)*FLS], (unsigned)t);           // pair b-group
      else if (wg < 128 && tid < 32) spin_ge(&hfl[(gbgrp*16 + (tid-16))*FLS], (unsigned)t); // gate slice group
      else if (wg >= 128 && tid == 16) spin_ge(&hfl[gs*FLS], (unsigned)t);       // mirror gate (Gx reuse)
      __syncthreads();
      if (tid == 0)
        (void)__hip_atomic_load(&hfl[0], __ATOMIC_ACQUIRE, __HIP_MEMORY_SCOPE_AGENT);
      __syncthreads();
    }

    // ---- stage x_t[b], hm[b] ----
    if (tid < 64){
      uint4 u = *(const uint4*)(o_h + ((size_t)t*NB + b)*HID + tid*8);
      float4 f0, f1;
      f0.x=bf2f(u.x&0xffffu); f0.y=bf2f(u.x>>16); f0.z=bf2f(u.y&0xffffu); f0.w=bf2f(u.y>>16);
      f1.x=bf2f(u.z&0xffffu); f1.y=bf2f(u.z>>16); f1.z=bf2f(u.w&0xffffu); f1.w=bf2f(u.w>>16);
      *(float4*)&xlf[tid*8]   = f0;
      *(float4*)&xlf[tid*8+4] = f1;
    } else if (tid < 192){
      int i2 = tid - 64;
      *(float4*)&hml[i2*4] = *(const float4*)(hpr + (size_t)b*HID + i2*4);
    }
    __syncthreads();

    // ---- c[b, e] for e in dh-half ----
    {
      const int el = tid>>1, kh = tid&1;
      const bfraw* wt = WtT + (size_t)(dh*256+el)*HID + kh*256;
      const bfraw* wm = WmT + (size_t)(dh*256+el)*HID + kh*256;
      const float* xv = xlf + kh*256;
      const float* hv = hml + kh*256;
      float acc = 0.f;
      #pragma unroll 4
      for (int k8=0;k8<32;++k8){
        uint4 wu = *(const uint4*)(wt+k8*8);
        uint4 mu = *(const uint4*)(wm+k8*8);
        float4 x0 = *(const float4*)(xv+k8*8), x1 = *(const float4*)(xv+k8*8+4);
        float4 h0 = *(const float4*)(hv+k8*8), h1 = *(const float4*)(hv+k8*8+4);
        acc += x0.x*bf2f(wu.x&0xffffu) + x0.y*bf2f(wu.x>>16) + x0.z*bf2f(wu.y&0xffffu) + x0.w*bf2f(wu.y>>16);
        acc += x1.x*bf2f(wu.z&0xffffu) + x1.y*bf2f(wu.z>>16) + x1.z*bf2f(wu.w&0xffffu) + x1.w*bf2f(wu.w>>16);
        acc += h0.x*bf2f(mu.x&0xffffu) + h0.y*bf2f(mu.x>>16) + h0.z*bf2f(mu.y&0xffffu) + h0.w*bf2f(mu.y>>16);
        acc += h1.x*bf2f(mu.z&0xffffu) + h1.y*bf2f(mu.z>>16) + h1.z*bf2f(mu.w&0xffffu) + h1.w*bf2f(mu.w>>16);
      }
      acc += __shfl_xor(acc, 1);
      if (kh == 0) c_l[el] = acc;
    }
    __syncthreads();

    // ---- logit partials over this d-half ----
    {
      const int tqs = tid>>5;
      float c8[8];
      *(float4*)&c8[0] = *(const float4*)&c_l[cc_*8];
      *(float4*)&c8[4] = *(const float4*)&c_l[cc_*8+4];
      #pragma unroll 2
      for (int i=0;i<16;++i){
        int tq = tqs + i*16;
        uint4 u = *(const uint4*)&whs_l[tq*256 + ((cc_ ^ (tq&15))<<3)];
        float s = 0.f;
        #pragma unroll
        for (int j=0;j<4;++j){
          unsigned uu = ((const unsigned*)&u)[j];
          s += ftanh(bf2f(uu&0xffffu) + c8[j*2])   * we8[j*2];
          s += ftanh(bf2f(uu>>16)     + c8[j*2+1]) * we8[j*2+1];
        }
        #pragma unroll
        for (int off=16; off; off>>=1) s += __shfl_xor(s, off);
        if (cc_ == 0) lp0[tq] = s;
      }
    }
    __syncthreads();
    if (tid < 64) *(float4*)&Lbuf[(size_t)wg*256 + tid*4] = *(const float4*)&lp0[tid*4];
    __syncthreads();
    setflag(&pf[wg*FLS], (unsigned)(t+1));

    // ---- issue o_p prefetch ----
    const int dgrp = tid&31, tqs2 = tid>>5, d8 = dgrp*8;
    const bfraw* opb = o_p + (size_t)b*HID + dh*256 + d8;
    uint4 uu[16];
    #pragma unroll
    for (int i=0;i<16;++i)
      uu[i] = *(const uint4*)(opb + (size_t)(tqs2*16 + i)*NB*HID);

    // ---- overlapped gate partials (hide under pairsync + softmax) ----
    f32x4 accA = {0.f,0.f,0.f,0.f};
    if (wg < 128){
      // hm-segment (16 b of gate slice; depends only on hm(t-1))
      const bfraw* hrow = hmr + (size_t)(mb0+gfr)*HID;
      #pragma unroll
      for (int kk=0; kk<16; ++kk){
        short8 af = *(const short8*)(hrow + kk*32 + gfg*8);
        short8 bv = *(const short8*)(wrowA + 1024 + kk*32 + gfg*8);
        accA = MFMA16(af, bv, accA, 0,0,0);
      }
    } else {
      // x-segment -> Gx (depends only on o_h[t]; mirror-guarded at step start)
      f32x4 accB = {0.f,0.f,0.f,0.f};
      const bfraw* xrow = o_h + ((size_t)t*NB + mb0+gfr)*HID;
      #pragma unroll
      for (int kk=0; kk<16; ++kk){
        short8 af = *(const short8*)(xrow + kk*32 + gfg*8);
        short8 bv = *(const short8*)(wrowA + 512 + kk*32 + gfg*8);
        accB = MFMA16(af, bv, accB, 0,0,0);
      }
      #pragma unroll
      for (int rr=0; rr<4; ++rr)
        Gx[(size_t)(mb0 + gfg*4 + rr)*2048 + n0w + gfr] = accB[rr];
    }

    // ---- pairwise sync + read buddy partials ----
    if (tid == 0) spin_ge(&pf[(wg^1)*FLS], (unsigned)(t+1));
    __syncthreads();
    if (tid < 64) *(float4*)&lp1[tid*4] = bpf4(&Lbuf[(size_t)(wg^1)*256 + tid*4]);
    __syncthreads();

    // ---- softmax over 256 logits ----
    {
      const int lane = tid&63;
      float v = -1e30f, e = 0.f;
      if (tid < TSEQ){
        v = lp0[tid] + lp1[tid];
        float m = v;
        #pragma unroll
        for (int off=32; off; off>>=1) m = fmaxf(m, __shfl_xor(m, off));
        if (lane==0) red[tid>>6] = m;
      }
      __syncthreads();
      float mx = fmaxf(fmaxf(red[0],red[1]), fmaxf(red[2],red[3]));
      if (tid < TSEQ){
        e = __expf(v - mx);
        float s2 = e;
        #pragma unroll
        for (int off=32; off; off>>=1) s2 += __shfl_xor(s2, off);
        if (lane==0) red[8+(tid>>6)] = s2;
      }
      __syncthreads();
      float S = red[8]+red[9]+red[10]+red[11];
      if (tid < TSEQ) l_s[tid] = e * __builtin_amdgcn_rcpf(S);
      __syncthreads();
    }

    // ---- consume prefetched o_p -> a_t d-half ----
    {
      float a0=0,a1=0,a2=0,a3=0,a4=0,a5=0,a6=0,a7=0;
      #pragma unroll
      for (int i=0;i<16;++i){
        float al = l_s[tqs2*16 + i];
        uint4 u = uu[i];
        a0 += al*bf2f(u.x&0xffffu); a1 += al*bf2f(u.x>>16);
        a2 += al*bf2f(u.y&0xffffu); a3 += al*bf2f(u.y>>16);
        a4 += al*bf2f(u.z&0xffffu); a5 += al*bf2f(u.z>>16);
        a6 += al*bf2f(u.w&0xffffu); a7 += al*bf2f(u.w>>16);
      }
      *(float4*)&pt[tqs2*256+d8]   = (float4){a0,a1,a2,a3};
      *(float4*)&pt[tqs2*256+d8+4] = (float4){a4,a5,a6,a7};
      __syncthreads();
      if (tid < 256){
        float sA = 0.f;
        #pragma unroll
        for (int ss=0;ss<16;++ss) sA += pt[ss*256 + tid];
        float sB = __shfl_down(sA, 1);
        if ((tid&1)==0){
          unsigned pk = (unsigned)f2bf(sA) | ((unsigned)f2bf(sB)<<16);
          *(unsigned*)(a_bf + (size_t)b*HID + dh*256 + tid) = pk;
        }
      }
    }
    __syncthreads();
    setflag(&afl[wg*FLS], (unsigned)(t+1));   // a_bf half (and Gx for wg>=128) published

    // ---- gates: a-segment + combine + state update (wg<128) ----
    if (wg < 128){
      // wait: 32 pair WGs of gate b-group + mirror x-WG — fan-in 33
      if (tid < 32) spin_ge(&afl[(gbgrp*32 + tid)*FLS], (unsigned)(t+1));
      else if (tid == 32) spin_ge(&afl[(128 + gs)*FLS], (unsigned)(t+1));
      __syncthreads();
      if (tid == 0)
        (void)__hip_atomic_load(&afl[0], __ATOMIC_ACQUIRE, __HIP_MEMORY_SCOPE_AGENT);
      __syncthreads();

      const bfraw* arow = a_bf + (size_t)(mb0+gfr)*HID;
      #pragma unroll
      for (int kk=0; kk<16; ++kk){
        short8 af = *(const short8*)(arow + kk*32 + gfg*8);
        short8 bv = *(const short8*)(wrowA + kk*32 + gfg*8);
        accA = MFMA16(af, bv, accA, 0,0,0);
      }
      const int np = n0w + gfr, dd = np>>2, g = np&3;
      #pragma unroll
      for (int rr=0; rr<4; ++rr){
        float x0 = accA[rr] + Gx[(size_t)(mb0 + gfg*4 + rr)*2048 + np];
        float x1 = __shfl_xor(x0, 1);
        float x2 = __shfl_xor(x0, 2);
        float x3 = __shfl_xor(x1, 2);
        if (g==0){
          int b3 = mb0 + gfg*4 + rr;
          float hp = hpr[(size_t)b3*HID + dd];
          float rg = fsig(x0 + bc[dd]);
          float zg = fsig(x1 + bc[512+dd]);
          float gn = ftanh(x2 + bc[1024+dd] + rg*(x3 + bc[1536+dd]));
          float h = (1.f-zg)*gn + zg*hp;
          hpw[(size_t)b3*HID + dd] = h;
          hmw[(size_t)b3*HID + dd] = f2bf(h);
        }
      }
      __syncthreads();
      setflag(&hfl[wg*FLS], (unsigned)(t+1));
    }
  }

  // ---- output head ----
  if (wg == 0){
    pollN(hfl, 128, (unsigned)TSEQ);
    if (tid < NB*3){
      const float* hf = hmbuf + (size_t)((TSEQ-1)&1)*65536;
      int b2 = tid/3, c = tid%3;
      float acc = outb[c];
      const float* h = hf + (size_t)b2*HID;
      const float* w = outW + (size_t)c*HID;
      for (int d2=0; d2<HID; ++d2) acc = fmaf(h[d2], w[d2], acc);
      out[tid] = fmaxf(acc, 0.f);
    }
  }
}

extern "C" void kernel_launch(void* const* d_in, const int* in_sizes, int n_in,
                              void* d_out, int out_size, void* d_ws, size_t ws_size,
                              hipStream_t stream)
{
  const float* Ep    = (const float*)d_in[0];
  const float* Eh    = (const float*)d_in[1];
  const float* p_W   = (const float*)d_in[2];
  const float* p_b   = (const float*)d_in[3];
  const float* h_W   = (const float*)d_in[4];
  const float* h_b   = (const float*)d_in[5];
  const float* pgWih = (const float*)d_in[6];
  const float* pgWhh = (const float*)d_in[7];
  const float* pgbih = (const float*)d_in[8];
  const float* pgbhh = (const float*)d_in[9];
  const float* hgWih = (const float*)d_in[10];
  const float* hgWhh = (const float*)d_in[11];
  const float* hgbih = (const float*)d_in[12];
  const float* hgbhh = (const float*)d_in[13];
  const float* W_s   = (const float*)d_in[14];
  const float* W_t   = (const float*)d_in[15];
  const float* w_e   = (const float*)d_in[16];
  const float* W_m   = (const float*)d_in[17];
  const float* mWih  = (const float*)d_in[18];
  const float* mWhh  = (const float*)d_in[19];
  const float* mbih  = (const float*)d_in[20];
  const float* mbhh  = (const float*)d_in[21];
  const float* outW  = (const float*)d_in[22];
  const float* outb  = (const float*)d_in[23];

  const size_t OB    = (size_t)TSEQ*NB*HID*sizeof(bfraw);
  const size_t RB    = OB;
  const size_t WFB   = (size_t)G3*INDIM*sizeof(bfraw);
  const size_t SQB   = (size_t)HID*HID*sizeof(bfraw);
  const size_t WHHB  = (size_t)G3*HID*sizeof(bfraw);
  const size_t WCATB = (size_t)2048*1536*sizeof(bfraw);
  const size_t BARB  = (size_t)4*NWG*FLS*sizeof(unsigned);
  const size_t needed = 2*OB + RB + 2*WFB + 3*SQB + 2*WHHB + WCATB
                        + 8192 + 2*6144
                        + 4*262144 + 2*262144 + 2*131072
                        + BARB;
  if (ws_size < needed) return;

  char* p = (char*)d_ws;
  bfraw* o_p_bf = (bfraw*)p; p += OB;
  bfraw* o_h_bf = (bfraw*)p; p += OB;
  char*  Rreg   = p;         p += RB;
  bfraw* Wfp_bf = (bfraw*)p; p += WFB;
  bfraw* Wfh_bf = (bfraw*)p; p += WFB;
  bfraw* WsT_bf = (bfraw*)p; p += SQB;
  bfraw* WtT_bf = (bfraw*)p; p += SQB;
  bfraw* WmT_bf = (bfraw*)p; p += SQB;
  bfraw* Whhp_bf= (bfraw*)p; p += WHHB;
  bfraw* Whhh_bf= (bfraw*)p; p += WHHB;
  bfraw* Wcat_bf= (bfraw*)p; p += WCATB;
  float* bc     = (float*)p; p += 8192;
  float* bfp    = (float*)p; p += 6144;
  float* bfh    = (float*)p; p += 6144;
  float* hst    = (float*)p; p += 4*262144;
  float* hmbuf  = (float*)p; p += 2*262144;
  bfraw* hm_bf  = (bfraw*)p; p += 2*131072;
  unsigned* bar = (unsigned*)p; p += BARB;

  bfraw* pWT_bf = (bfraw*)Rreg;
  bfraw* hWT_bf = (bfraw*)(Rreg + (size_t)INDIM*HID*sizeof(bfraw));
  float* GIp_c  = (float*)Rreg;
  float* GIh_c  = (float*)(Rreg + (size_t)CH*NB*G3*sizeof(float));
  bfraw* Whs_bf = (bfraw*)Rreg;
  float* Lbuf   = (float*)Wfp_bf;                          // 256 KB overlay
  bfraw* a_bf   = (bfraw*)((char*)Wfp_bf + 2097152);       // 128 KB
  float* Gx     = (float*)((char*)Wfp_bf + WFB);           // 1 MB (Wfh region)

  (void)hipFuncSetAttribute((const void*)scanB, hipFuncAttributeMaxDynamicSharedMemorySize, 131072);
  (void)hipFuncSetAttribute((const void*)scanD, hipFuncAttributeMaxDynamicSharedMemorySize, 155776);

  dim3 b256(256), b512(512);

  init_k<<<dim3(128), b256, 0, stream>>>(bar);
  hminit_k<<<dim3(512), b256, 0, stream>>>(hmbuf, hm_bf);

  // ---- Phase A: weight prep ----
  tconv_k<<<dim3(INDIM/32, HID/32), b256, 0, stream>>>(p_W, pWT_bf, HID, INDIM);
  tconv_k<<<dim3(INDIM/32, HID/32), b256, 0, stream>>>(h_W, hWT_bf, HID, INDIM);
  tconv_k<<<dim3(HID/32, HID/32),  b256, 0, stream>>>(W_s, WsT_bf, HID, HID);
  tconv_k<<<dim3(HID/32, HID/32),  b256, 0, stream>>>(W_t, WtT_bf, HID, HID);
  tconv_k<<<dim3(HID/32, HID/32),  b256, 0, stream>>>(W_m, WmT_bf, HID, HID);
  cvt_k<<<dim3((G3*HID)/1024), b256, 0, stream>>>(pgWhh, Whhp_bf, G3*HID);
  cvt_k<<<dim3((G3*HID)/1024), b256, 0, stream>>>(hgWhh, Whhh_bf, G3*HID);
  wcat_k<<<dim3(3072), b256, 0, stream>>>(mWih, mWhh, Wcat_bf);
  bpack_k<<<dim3(2), b256, 0, stream>>>(mbih, mbhh, bc);
  fuse_bias_k<<<dim3(G3/256), b256, 0, stream>>>(pgWih, pgbih, p_b, bfp);
  fuse_bias_k<<<dim3(G3/256), b256, 0, stream>>>(hgWih, hgbih, h_b, bfh);
  mgemm<float, bfraw, false><<<dim3(INDIM/128, G3/128, 2), b256, 0, stream>>>(
    pgWih, hgWih, pWT_bf, hWT_bf, nullptr, nullptr, Wfp_bf, Wfh_bf,
    HID, HID, HID, INDIM);

  // ---- Phase B: chunked GI GEMM + persistent scan ----
  for (int c = 0; c < TSEQ/CH; ++c){
    mgemm<float, float, true><<<dim3(G3/128, (CH*NB)/128, 2), b256, 0, stream>>>(
      Ep + (size_t)c*CH*NB*INDIM, Eh + (size_t)c*CH*NB*INDIM,
      Wfp_bf, Wfh_bf, bfp, bfh, GIp_c, GIh_c,
      INDIM, INDIM, INDIM, G3);
    scanB<<<dim3(NWG), b512, 131072, stream>>>(
      GIp_c, GIh_c, Whhp_bf, Whhh_bf, pgbhh, hgbhh,
      hst, o_p_bf, o_h_bf, c*CH, bar);
  }

  // ---- Phase C: Whs = o_p @ W_s ----
  mgemm<bfraw, bfraw, false><<<dim3(HID/128, (TSEQ*NB)/128, 1), b256, 0, stream>>>(
    o_p_bf, o_p_bf, WsT_bf, WsT_bf, nullptr, nullptr, Whs_bf, Whs_bf,
    HID, HID, HID, HID);

  // ---- Phase D: persistent scan ----
  scanD<<<dim3(NWG), b512, 155776, stream>>>(
    Whs_bf, o_p_bf, o_h_bf, WtT_bf, WmT_bf, w_e, Wcat_bf, bc,
    hmbuf, hm_bf, a_bf, Lbuf, Gx,
    outW, outb, (float*)d_out, bar);
}

// Round 15
// 20758.867 us; speedup vs baseline: 1.5275x; 1.0007x over previous
//
#include <hip/hip_runtime.h>
#include <cstddef>

#define TSEQ 256
#define NB   128
#define HID  512
#define G3   1536
#define INDIM 768
#define CH   16
#define NWG  256
#define FLS  32   // u32 stride between flag lines (128 B)

typedef unsigned short bfraw;
using short8 = __attribute__((ext_vector_type(8))) short;
using f32x4  = __attribute__((ext_vector_type(4))) float;

#define MFMA16 __builtin_amdgcn_mfma_f32_16x16x32_bf16

__device__ __forceinline__ float bf2f(unsigned int u){ return __uint_as_float(u<<16); }
__device__ __forceinline__ bfraw f2bf(float f){
  unsigned int u = __float_as_uint(f);
  u += 0x7fffu + ((u>>16)&1u);
  return (bfraw)(u>>16);
}
__device__ __forceinline__ float fsig(float x){
  return __builtin_amdgcn_rcpf(1.0f + __expf(-x));
}
__device__ __forceinline__ float ftanh(float x){
  return 1.0f - 2.0f*__builtin_amdgcn_rcpf(1.0f + __expf(2.0f*x));
}

// ==== sc1 coherence-point access (L2-bypass): ALL cross-WG mutable state ====
__device__ __forceinline__ uint4 bpu4(const void* p){
  unsigned long long a = __hip_atomic_load((const unsigned long long*)p,     __ATOMIC_RELAXED, __HIP_MEMORY_SCOPE_AGENT);
  unsigned long long b = __hip_atomic_load((const unsigned long long*)p + 1, __ATOMIC_RELAXED, __HIP_MEMORY_SCOPE_AGENT);
  uint4 r; r.x=(unsigned)a; r.y=(unsigned)(a>>32); r.z=(unsigned)b; r.w=(unsigned)(b>>32);
  return r;
}
__device__ __forceinline__ short8 bps8(const void* p){
  union{ uint4 u; short8 s; } cv; cv.u = bpu4(p); return cv.s;
}
__device__ __forceinline__ float4 bpf4(const void* p){
  union{ uint4 u; float4 f; } cv; cv.u = bpu4(p); return cv.f;
}
__device__ __forceinline__ float bpf(const void* p){
  unsigned u = __hip_atomic_load((const unsigned*)p, __ATOMIC_RELAXED, __HIP_MEMORY_SCOPE_AGENT);
  return __uint_as_float(u);
}
__device__ __forceinline__ void st4_cp(void* p, unsigned v){
  __hip_atomic_store((unsigned*)p, v, __ATOMIC_RELAXED, __HIP_MEMORY_SCOPE_AGENT);
}
__device__ __forceinline__ void st8_cp(void* p, unsigned long long v){
  __hip_atomic_store((unsigned long long*)p, v, __ATOMIC_RELAXED, __HIP_MEMORY_SCOPE_AGENT);
}
__device__ __forceinline__ void stf_cp(float* p, float v){
  __hip_atomic_store((unsigned*)p, __float_as_uint(v), __ATOMIC_RELAXED, __HIP_MEMORY_SCOPE_AGENT);
}
__device__ __forceinline__ void sth_cp(bfraw* p, bfraw v){
  __hip_atomic_store((unsigned short*)p, v, __ATOMIC_RELAXED, __HIP_MEMORY_SCOPE_AGENT);
}
__device__ __forceinline__ unsigned long long pk64(float a, float b){
  return (unsigned long long)__float_as_uint(a) | ((unsigned long long)__float_as_uint(b)<<32);
}

// ---- relaxed spin with exponential backoff; NO acquires anywhere ----
__device__ __forceinline__ void spin_ge(unsigned* p, unsigned epoch){
  int sp = 0;
  while (__hip_atomic_load(p, __ATOMIC_RELAXED, __HIP_MEMORY_SCOPE_AGENT) < epoch){
    if (sp < 3){ __builtin_amdgcn_s_sleep(1); ++sp; }
    else        __builtin_amdgcn_s_sleep(16);
  }
}
// poll n producer flags in parallel (no acquire — data paths are sc1)
__device__ __forceinline__ void pollN(unsigned* flags, int n, unsigned epoch){
  const int tid = threadIdx.x;
  if (tid < n) spin_ge(&flags[tid*FLS], epoch);
  __syncthreads();
}
// release flag: orders prior sc1 payload stores (vmcnt drain) before flag
__device__ __forceinline__ void setflag(unsigned* f, unsigned v){
  if (threadIdx.x == 0)
    __hip_atomic_store(f, v, __ATOMIC_RELEASE, __HIP_MEMORY_SCOPE_AGENT);
}

__global__ void init_k(unsigned* bar){
  int i = blockIdx.x*256 + threadIdx.x;
  if (i < 4*NWG*FLS) bar[i] = 0u;
}

__global__ void hminit_k(float* hmbuf, bfraw* hm_bf){
  int i = blockIdx.x*256 + threadIdx.x;   // 131072 (both slots)
  hmbuf[i] = 1.0f;
  hm_bf[i] = (bfraw)0x3f80;
}

// ---- transpose+convert: in fp32 [R][Cc] -> out bf16 [Cc][R] ----
__global__ __launch_bounds__(256)
void tconv_k(const float* __restrict__ in, bfraw* __restrict__ out, int R, int Cc){
  __shared__ float t[32][33];
  int c0 = blockIdx.x*32, r0 = blockIdx.y*32;
  int tx = threadIdx.x&31, ty = threadIdx.x>>5;
  #pragma unroll
  for (int i=0;i<32;i+=8) t[ty+i][tx] = in[(size_t)(r0+ty+i)*Cc + c0+tx];
  __syncthreads();
  #pragma unroll
  for (int i=0;i<32;i+=8) out[(size_t)(c0+ty+i)*R + r0+tx] = f2bf(t[tx][ty+i]);
}

__global__ void cvt_k(const float* __restrict__ in, bfraw* __restrict__ out, int n){
  int i = (blockIdx.x*256 + threadIdx.x)*4;
  if (i >= n) return;
  float4 v = *(const float4*)(in+i);
  uint2 o;
  o.x = (unsigned)f2bf(v.x) | ((unsigned)f2bf(v.y)<<16);
  o.y = (unsigned)f2bf(v.z) | ((unsigned)f2bf(v.w)<<16);
  *(uint2*)(out+i) = o;
}

// W_cat[n'][k], n'=dd*4+g, k<1536 (segs: a[0,512) x[512,1024) -> mWih; hm[1024,1536) -> mWhh)
__global__ void wcat_k(const float* __restrict__ mWih, const float* __restrict__ mWhh,
                       bfraw* __restrict__ Wcat){
  size_t gid = (size_t)blockIdx.x*256 + threadIdx.x;
  int np = (int)(gid / 384);
  int k4 = ((int)(gid % 384))*4;
  int dd = np>>2, g = np&3;
  float v[4];
  #pragma unroll
  for (int j=0;j<4;++j){
    int k = k4+j; float x = 0.f;
    if (g==0)      x = (k<1024) ? mWih[(size_t)dd*1024 + k]        : mWhh[(size_t)dd*512 + (k-1024)];
    else if (g==1) x = (k<1024) ? mWih[(size_t)(512+dd)*1024 + k]  : mWhh[(size_t)(512+dd)*512 + (k-1024)];
    else if (g==2) x = (k<1024) ? mWih[(size_t)(1024+dd)*1024 + k] : 0.f;
    else           x = (k<1024) ? 0.f : mWhh[(size_t)(1024+dd)*512 + (k-1024)];
    v[j] = x;
  }
  uint2 o;
  o.x = (unsigned)f2bf(v[0]) | ((unsigned)f2bf(v[1])<<16);
  o.y = (unsigned)f2bf(v[2]) | ((unsigned)f2bf(v[3])<<16);
  *(uint2*)(Wcat + (size_t)np*1536 + k4) = o;
}

__global__ void bpack_k(const float* __restrict__ mbih, const float* __restrict__ mbhh,
                        float* __restrict__ bc){
  int dd = blockIdx.x*256 + threadIdx.x;
  if (dd >= 512) return;
  bc[dd]      = mbih[dd] + mbhh[dd];
  bc[512+dd]  = mbih[512+dd] + mbhh[512+dd];
  bc[1024+dd] = mbih[1024+dd];
  bc[1536+dd] = mbhh[1024+dd];
}

__global__ void fuse_bias_k(const float* __restrict__ Wih, const float* __restrict__ bih,
                            const float* __restrict__ pb, float* __restrict__ bout)
{
  int g = blockIdx.x*256 + threadIdx.x;
  if (g >= G3) return;
  float acc = bih[g];
  const float* w = Wih + (size_t)g*HID;
  for (int e=0;e<HID;e+=4){
    float4 wv = *(const float4*)(w+e);
    float4 pv = *(const float4*)(pb+e);
    acc += wv.x*pv.x + wv.y*pv.y + wv.z*pv.z + wv.w*pv.w;
  }
  bout[g] = acc;
}

// ---- MFMA bf16 GEMM: C[MxN] = A[MxK] * B^T (+bias); z selects operand set ----
template<typename TA, typename TC, bool BIAS>
__global__ __launch_bounds__(256)
void mgemm(const TA* __restrict__ A0, const TA* __restrict__ A1,
           const bfraw* __restrict__ B0, const bfraw* __restrict__ B1,
           const float* __restrict__ bias0, const float* __restrict__ bias1,
           TC* __restrict__ C0, TC* __restrict__ C1,
           int K, int lda, int ldb, int ldc)
{
  const TA* A = blockIdx.z ? A1 : A0;
  const bfraw* B = blockIdx.z ? B1 : B0;
  const float* bias = blockIdx.z ? bias1 : bias0;
  TC* C = blockIdx.z ? C1 : C0;
  __shared__ bfraw Al[128*40];
  __shared__ bfraw Bl[128*40];
  const int tid = threadIdx.x;
  const size_t m0 = (size_t)blockIdx.y*128, n0 = (size_t)blockIdx.x*128;
  const int w = tid>>6, l = tid&63;
  const int wr = (w>>1)*64, wc = (w&1)*64;
  const int fr = l&15, fg = l>>4;
  f32x4 acc[4][4];
  #pragma unroll
  for (int i=0;i<4;++i)
    #pragma unroll
    for (int j=0;j<4;++j) acc[i][j] = (f32x4){0.f,0.f,0.f,0.f};

  const int srow = tid>>1, skc = (tid&1)*16;
  for (int k0=0; k0<K; k0+=32){
    if constexpr (sizeof(TA)==4){
      const float* ap = (const float*)A + (m0+srow)*lda + k0 + skc;
      float4 v0=*(const float4*)ap, v1=*(const float4*)(ap+4),
             v2=*(const float4*)(ap+8), v3=*(const float4*)(ap+12);
      uint4 w0, w1;
      w0.x=(unsigned)f2bf(v0.x)|((unsigned)f2bf(v0.y)<<16);
      w0.y=(unsigned)f2bf(v0.z)|((unsigned)f2bf(v0.w)<<16);
      w0.z=(unsigned)f2bf(v1.x)|((unsigned)f2bf(v1.y)<<16);
      w0.w=(unsigned)f2bf(v1.z)|((unsigned)f2bf(v1.w)<<16);
      w1.x=(unsigned)f2bf(v2.x)|((unsigned)f2bf(v2.y)<<16);
      w1.y=(unsigned)f2bf(v2.z)|((unsigned)f2bf(v2.w)<<16);
      w1.z=(unsigned)f2bf(v3.x)|((unsigned)f2bf(v3.y)<<16);
      w1.w=(unsigned)f2bf(v3.z)|((unsigned)f2bf(v3.w)<<16);
      *(uint4*)&Al[srow*40+skc]   = w0;
      *(uint4*)&Al[srow*40+skc+8] = w1;
    } else {
      const bfraw* ap = (const bfraw*)A + (m0+srow)*lda + k0 + skc;
      *(uint4*)&Al[srow*40+skc]   = *(const uint4*)ap;
      *(uint4*)&Al[srow*40+skc+8] = *(const uint4*)(ap+8);
    }
    {
      const bfraw* bp = B + (n0+srow)*ldb + k0 + skc;
      *(uint4*)&Bl[srow*40+skc]   = *(const uint4*)bp;
      *(uint4*)&Bl[srow*40+skc+8] = *(const uint4*)(bp+8);
    }
    __syncthreads();
    short8 af[4], bfr[4];
    #pragma unroll
    for (int i=0;i<4;++i) af[i]  = *(const short8*)&Al[(wr+i*16+fr)*40 + fg*8];
    #pragma unroll
    for (int j=0;j<4;++j) bfr[j] = *(const short8*)&Bl[(wc+j*16+fr)*40 + fg*8];
    #pragma unroll
    for (int i=0;i<4;++i)
      #pragma unroll
      for (int j=0;j<4;++j)
        acc[i][j] = MFMA16(af[i], bfr[j], acc[i][j], 0,0,0);
    __syncthreads();
  }
  #pragma unroll
  for (int i=0;i<4;++i){
    #pragma unroll
    for (int j=0;j<4;++j){
      size_t n = n0 + wc + j*16 + fr;
      float bv = BIAS ? bias[n] : 0.f;
      #pragma unroll
      for (int r=0;r<4;++r){
        size_t m = m0 + wr + i*16 + fg*4 + r;
        float v = acc[i][j][r] + bv;
        if constexpr (sizeof(TC)==2) ((bfraw*)C)[m*ldc + n] = f2bf(v);
        else                         ((float*)C)[m*ldc + n] = v;
      }
    }
  }
}

// ---- Phase B: persistent GRU scan; group flags; hz state via sc1 ----
__global__ __launch_bounds__(512, 2)
void scanB(const float* __restrict__ GIp, const float* __restrict__ GIh,
           const bfraw* __restrict__ Whhp, const bfraw* __restrict__ Whhh,
           const float* __restrict__ bhhp, const float* __restrict__ bhhh,
           float* __restrict__ hst, bfraw* __restrict__ o_p, bfraw* __restrict__ o_h,
           int c0, unsigned* __restrict__ bar)
{
  extern __shared__ char smem[];
  bfraw* wl = (bfraw*)smem;                  // 98304 B
  float* sh = (float*)(smem + 98304);        // 32768 B
  const int wg = blockIdx.x;
  const int z = wg>>7, rem = wg&127;
  const int bg = rem>>4, dg = rem&15;
  const float* GI  = z ? GIh : GIp;
  const bfraw* Wb  = z ? Whhh : Whhp;
  const float* bhh = z ? bhhh : bhhp;
  bfraw* ob = z ? o_h : o_p;
  float* hz = hst + (size_t)z*2*NB*HID;
  const int tid = threadIdx.x;
  unsigned* bfl = bar + 3*NWG*FLS;
  unsigned* grp = bfl + (size_t)(z*128 + bg*16)*FLS;
  unsigned* own = bfl + (size_t)wg*FLS;

  #pragma unroll
  for (int g=0; g<3; ++g){
    const unsigned* src = (const unsigned*)(Wb + (size_t)(g*512 + dg*32)*512);
    for (int j=0; j<16; ++j){
      int iu = tid + j*512;
      unsigned v = src[iu];
      int d = iu>>8, kk = (iu&255)*2;
      int idx0 = g*16384 + (kk>>2)*128 + d*4 + (kk&3);
      *((unsigned*)wl + (idx0>>1)) = v;
    }
  }
  __syncthreads();

  const int bl = tid>>5, dl = tid&31;
  const int d = dg*32+dl, bglob = bg*16+bl;
  const float br = bhh[d], bz = bhh[512+d], bn = bhh[1024+d];

  #pragma clang loop unroll(disable)
  for (int tt=0; tt<CH; ++tt){
    const int t = c0+tt;
    if (t > 0) pollN(grp, 16, (unsigned)t);
    if (t == 0){
      for (int j=0;j<4;++j){
        int i4 = tid + j*512;
        *(float4*)&sh[i4*4] = (float4){1.f,1.f,1.f,1.f};
      }
    } else {
      const float* hp = hz + (size_t)((t-1)&1)*NB*HID + (size_t)bg*16*HID;
      for (int j=0;j<4;++j){
        int i4 = tid + j*512;
        *(float4*)&sh[i4*4] = bpf4(&hp[i4*4]);        // sc1 read
      }
    }
    __syncthreads();
    float ar = br, az = bz, an = bn;
    const float* hb = sh + bl*512;
    for (int k=0;k<512;k+=4){
      float4 h4 = *(const float4*)(hb+k);
      int base = (k>>2)*128 + dl*4;
      uint2 wr = *(const uint2*)(wl + base);
      uint2 wz = *(const uint2*)(wl + 16384 + base);
      uint2 wn = *(const uint2*)(wl + 32768 + base);
      ar += h4.x*bf2f(wr.x&0xffffu) + h4.y*bf2f(wr.x>>16) + h4.z*bf2f(wr.y&0xffffu) + h4.w*bf2f(wr.y>>16);
      az += h4.x*bf2f(wz.x&0xffffu) + h4.y*bf2f(wz.x>>16) + h4.z*bf2f(wz.y&0xffffu) + h4.w*bf2f(wz.y>>16);
      an += h4.x*bf2f(wn.x&0xffffu) + h4.y*bf2f(wn.x>>16) + h4.z*bf2f(wn.y&0xffffu) + h4.w*bf2f(wn.y>>16);
    }
    const float* gi = GI + ((size_t)tt*NB + bglob)*G3;
    float r  = fsig(gi[d] + ar);
    float zz = fsig(gi[512+d] + az);
    float n  = ftanh(gi[1024+d] + r*an);
    float hp = hb[d];
    float hv = (1.0f-zz)*n + zz*hp;
    stf_cp(&(hz + (size_t)(t&1)*NB*HID)[(size_t)bglob*HID + d], hv);   // sc1 write
    ob[((size_t)t*NB + bglob)*HID + d] = f2bf(hv);                     // cached (consumed by later kernels)
    __syncthreads();
    setflag(own, (unsigned)(t+1));
  }
}

// ---- Phase D: persistent scan — low-fan-in flags; all mutable state via sc1 ----
__global__ __launch_bounds__(512, 2)
void scanD(const bfraw* __restrict__ Whs, const bfraw* __restrict__ o_p,
           const bfraw* __restrict__ o_h,
           const bfraw* __restrict__ WtT, const bfraw* __restrict__ WmT,
           const float* __restrict__ w_e,
           const bfraw* __restrict__ Wcat, const float* __restrict__ bc,
           float* __restrict__ hmbuf, bfraw* __restrict__ hm_bf,
           bfraw* __restrict__ a_bf, float* __restrict__ Lbuf, float* __restrict__ Gx,
           const float* __restrict__ outW, const float* __restrict__ outb,
           float* __restrict__ out, unsigned* __restrict__ bar)
{
  extern __shared__ char smem[];
  bfraw* whs_l = (bfraw*)smem;                 // 131072 B
  float* pt    = (float*)(smem + 131072);      // 16384 B [16][256]
  float* xlf   = (float*)(smem + 147456);      // 2048 B
  float* hml   = (float*)(smem + 149504);      // 2048 B
  float* c_l   = (float*)(smem + 151552);      // 1024 B
  float* lp0   = (float*)(smem + 152576);      // 1024 B
  float* lp1   = (float*)(smem + 153600);      // 1024 B
  float* l_s   = (float*)(smem + 154624);      // 1024 B
  float* red   = (float*)(smem + 155648);      // 128 B

  const int wg = blockIdx.x, tid = threadIdx.x;
  const int b = wg>>1, dh = wg&1;
  unsigned* pf  = bar;
  unsigned* afl = bar + NWG*FLS;
  unsigned* hfl = bar + 2*NWG*FLS;

  for (int it=0; it<16; ++it){
    int idx = tid + it*512;
    int tq = idx>>5, c = idx&31;
    const bfraw* src = Whs + ((size_t)tq*NB + b)*HID + dh*256 + c*8;
    *(uint4*)&whs_l[tq*256 + ((c ^ (tq&15))<<3)] = *(const uint4*)src;
  }
  const int cc_ = tid&31;
  float we8[8];
  #pragma unroll
  for (int r=0;r<8;++r) we8[r] = w_e[dh*256 + cc_*8 + r];
  __syncthreads();

  // gate/x-slice geometry: slice id s = wg&127 -> bgrp=s>>4 (16 b), ddg=s&15 (128 n)
  const int gs = wg&127, gbgrp = gs>>4, gddg = gs&15;
  const int gw = tid>>6, gl = tid&63, gfr = gl&15, gfg = gl>>4;
  const int n0w = gddg*128 + gw*16;
  const int mb0 = gbgrp*16;
  const bfraw* wrowA = Wcat + (size_t)(n0w+gfr)*1536;

  #pragma clang loop unroll(disable)
  for (int t=0; t<TSEQ; ++t){
    const int rs = (t+1)&1;
    const bfraw* hmr = hm_bf + (size_t)rs*65536;
    const float* hpr = hmbuf + (size_t)rs*65536;
    bfraw* hmw = hm_bf + (size_t)(t&1)*65536;
    float* hpw = hmbuf + (size_t)(t&1)*65536;

    // ---- step start: hm(t-1) ready — low-fan-in polls ----
    if (t > 0){
      if (tid < 16) spin_ge(&hfl[((b>>4)*16 + tid)*FLS], (unsigned)t);
      else if (wg < 128 && tid < 32) spin_ge(&hfl[(gbgrp*16 + (tid-16))*FLS], (unsigned)t);
      else if (wg >= 128 && tid == 16) spin_ge(&hfl[gs*FLS], (unsigned)t);
      __syncthreads();
    }

    // ---- stage x_t[b] (cached, read-only) and hm[b] (sc1) ----
    if (tid < 64){
      uint4 u = *(const uint4*)(o_h + ((size_t)t*NB + b)*HID + tid*8);
      float4 f0, f1;
      f0.x=bf2f(u.x&0xffffu); f0.y=bf2f(u.x>>16); f0.z=bf2f(u.y&0xffffu); f0.w=bf2f(u.y>>16);
      f1.x=bf2f(u.z&0xffffu); f1.y=bf2f(u.z>>16); f1.z=bf2f(u.w&0xffffu); f1.w=bf2f(u.w>>16);
      *(float4*)&xlf[tid*8]   = f0;
      *(float4*)&xlf[tid*8+4] = f1;
    } else if (tid < 192){
      int i2 = tid - 64;
      *(float4*)&hml[i2*4] = bpf4(hpr + (size_t)b*HID + i2*4);    // sc1 read
    }
    __syncthreads();

    // ---- c[b, e] for e in dh-half ----
    {
      const int el = tid>>1, kh = tid&1;
      const bfraw* wt = WtT + (size_t)(dh*256+el)*HID + kh*256;
      const bfraw* wm = WmT + (size_t)(dh*256+el)*HID + kh*256;
      const float* xv = xlf + kh*256;
      const float* hv = hml + kh*256;
      float acc = 0.f;
      #pragma unroll 4
      for (int k8=0;k8<32;++k8){
        uint4 wu = *(const uint4*)(wt+k8*8);
        uint4 mu = *(const uint4*)(wm+k8*8);
        float4 x0 = *(const float4*)(xv+k8*8), x1 = *(const float4*)(xv+k8*8+4);
        float4 h0 = *(const float4*)(hv+k8*8), h1 = *(const float4*)(hv+k8*8+4);
        acc += x0.x*bf2f(wu.x&0xffffu) + x0.y*bf2f(wu.x>>16) + x0.z*bf2f(wu.y&0xffffu) + x0.w*bf2f(wu.y>>16);
        acc += x1.x*bf2f(wu.z&0xffffu) + x1.y*bf2f(wu.z>>16) + x1.z*bf2f(wu.w&0xffffu) + x1.w*bf2f(wu.w>>16);
        acc += h0.x*bf2f(mu.x&0xffffu) + h0.y*bf2f(mu.x>>16) + h0.z*bf2f(mu.y&0xffffu) + h0.w*bf2f(mu.y>>16);
        acc += h1.x*bf2f(mu.z&0xffffu) + h1.y*bf2f(mu.z>>16) + h1.z*bf2f(mu.w&0xffffu) + h1.w*bf2f(mu.w>>16);
      }
      acc += __shfl_xor(acc, 1);
      if (kh == 0) c_l[el] = acc;
    }
    __syncthreads();

    // ---- logit partials over this d-half ----
    {
      const int tqs = tid>>5;
      float c8[8];
      *(float4*)&c8[0] = *(const float4*)&c_l[cc_*8];
      *(float4*)&c8[4] = *(const float4*)&c_l[cc_*8+4];
      #pragma unroll 2
      for (int i=0;i<16;++i){
        int tq = tqs + i*16;
        uint4 u = *(const uint4*)&whs_l[tq*256 + ((cc_ ^ (tq&15))<<3)];
        float s = 0.f;
        #pragma unroll
        for (int j=0;j<4;++j){
          unsigned uu = ((const unsigned*)&u)[j];
          s += ftanh(bf2f(uu&0xffffu) + c8[j*2])   * we8[j*2];
          s += ftanh(bf2f(uu>>16)     + c8[j*2+1]) * we8[j*2+1];
        }
        #pragma unroll
        for (int off=16; off; off>>=1) s += __shfl_xor(s, off);
        if (cc_ == 0) lp0[tq] = s;
      }
    }
    __syncthreads();
    if (tid < 64){                                    // Lbuf via sc1 stores
      float4 v = *(const float4*)&lp0[tid*4];
      st8_cp(&Lbuf[(size_t)wg*256 + tid*4],     pk64(v.x, v.y));
      st8_cp(&Lbuf[(size_t)wg*256 + tid*4 + 2], pk64(v.z, v.w));
    }
    __syncthreads();
    setflag(&pf[wg*FLS], (unsigned)(t+1));

    // ---- issue o_p prefetch (cached; o_p never invalidated -> L2-resident) ----
    const int dgrp = tid&31, tqs2 = tid>>5, d8 = dgrp*8;
    const bfraw* opb = o_p + (size_t)b*HID + dh*256 + d8;
    uint4 uu[16];
    #pragma unroll
    for (int i=0;i<16;++i)
      uu[i] = *(const uint4*)(opb + (size_t)(tqs2*16 + i)*NB*HID);

    // ---- overlapped gate partials ----
    f32x4 accA = {0.f,0.f,0.f,0.f};
    if (wg < 128){
      const bfraw* hrow = hmr + (size_t)(mb0+gfr)*HID;
      #pragma unroll
      for (int kk=0; kk<16; ++kk){
        short8 af = bps8(hrow + kk*32 + gfg*8);       // sc1 read
        short8 bv = *(const short8*)(wrowA + 1024 + kk*32 + gfg*8);
        accA = MFMA16(af, bv, accA, 0,0,0);
      }
    } else {
      f32x4 accB = {0.f,0.f,0.f,0.f};
      const bfraw* xrow = o_h + ((size_t)t*NB + mb0+gfr)*HID;
      #pragma unroll
      for (int kk=0; kk<16; ++kk){
        short8 af = *(const short8*)(xrow + kk*32 + gfg*8);
        short8 bv = *(const short8*)(wrowA + 512 + kk*32 + gfg*8);
        accB = MFMA16(af, bv, accB, 0,0,0);
      }
      #pragma unroll
      for (int rr=0; rr<4; ++rr)
        stf_cp(&Gx[(size_t)(mb0 + gfg*4 + rr)*2048 + n0w + gfr], accB[rr]);  // sc1
    }

    // ---- pairwise sync + read buddy partials (sc1) ----
    if (tid == 0) spin_ge(&pf[(wg^1)*FLS], (unsigned)(t+1));
    __syncthreads();
    if (tid < 64) *(float4*)&lp1[tid*4] = bpf4(&Lbuf[(size_t)(wg^1)*256 + tid*4]);
    __syncthreads();

    // ---- softmax over 256 logits ----
    {
      const int lane = tid&63;
      float v = -1e30f, e = 0.f;
      if (tid < TSEQ){
        v = lp0[tid] + lp1[tid];
        float m = v;
        #pragma unroll
        for (int off=32; off; off>>=1) m = fmaxf(m, __shfl_xor(m, off));
        if (lane==0) red[tid>>6] = m;
      }
      __syncthreads();
      float mx = fmaxf(fmaxf(red[0],red[1]), fmaxf(red[2],red[3]));
      if (tid < TSEQ){
        e = __expf(v - mx);
        float s2 = e;
        #pragma unroll
        for (int off=32; off; off>>=1) s2 += __shfl_xor(s2, off);
        if (lane==0) red[8+(tid>>6)] = s2;
      }
      __syncthreads();
      float S = red[8]+red[9]+red[10]+red[11];
      if (tid < TSEQ) l_s[tid] = e * __builtin_amdgcn_rcpf(S);
      __syncthreads();
    }

    // ---- consume prefetched o_p -> a_t d-half ----
    {
      float a0=0,a1=0,a2=0,a3=0,a4=0,a5=0,a6=0,a7=0;
      #pragma unroll
      for (int i=0;i<16;++i){
        float al = l_s[tqs2*16 + i];
        uint4 u = uu[i];
        a0 += al*bf2f(u.x&0xffffu); a1 += al*bf2f(u.x>>16);
        a2 += al*bf2f(u.y&0xffffu); a3 += al*bf2f(u.y>>16);
        a4 += al*bf2f(u.z&0xffffu); a5 += al*bf2f(u.z>>16);
        a6 += al*bf2f(u.w&0xffffu); a7 += al*bf2f(u.w>>16);
      }
      *(float4*)&pt[tqs2*256+d8]   = (float4){a0,a1,a2,a3};
      *(float4*)&pt[tqs2*256+d8+4] = (float4){a4,a5,a6,a7};
      __syncthreads();
      if (tid < 256){
        float sA = 0.f;
        #pragma unroll
        for (int ss=0;ss<16;++ss) sA += pt[ss*256 + tid];
        float sB = __shfl_down(sA, 1);
        if ((tid&1)==0){
          unsigned pk = (unsigned)f2bf(sA) | ((unsigned)f2bf(sB)<<16);
          st4_cp(a_bf + (size_t)b*HID + dh*256 + tid, pk);   // sc1 write
        }
      }
    }
    __syncthreads();
    setflag(&afl[wg*FLS], (unsigned)(t+1));

    // ---- gates: a-segment + combine + state update (wg<128) ----
    if (wg < 128){
      if (tid < 32) spin_ge(&afl[(gbgrp*32 + tid)*FLS], (unsigned)(t+1));
      else if (tid == 32) spin_ge(&afl[(128 + gs)*FLS], (unsigned)(t+1));
      __syncthreads();

      const bfraw* arow = a_bf + (size_t)(mb0+gfr)*HID;
      #pragma unroll
      for (int kk=0; kk<16; ++kk){
        short8 af = bps8(arow + kk*32 + gfg*8);       // sc1 read
        short8 bv = *(const short8*)(wrowA + kk*32 + gfg*8);
        accA = MFMA16(af, bv, accA, 0,0,0);
      }
      const int np = n0w + gfr, dd = np>>2, g = np&3;
      #pragma unroll
      for (int rr=0; rr<4; ++rr){
        float x0 = accA[rr] + bpf(&Gx[(size_t)(mb0 + gfg*4 + rr)*2048 + np]);   // sc1
        float x1 = __shfl_xor(x0, 1);
        float x2 = __shfl_xor(x0, 2);
        float x3 = __shfl_xor(x1, 2);
        if (g==0){
          int b3 = mb0 + gfg*4 + rr;
          float hp = bpf(&hpr[(size_t)b3*HID + dd]);  // sc1
          float rg = fsig(x0 + bc[dd]);
          float zg = fsig(x1 + bc[512+dd]);
          float gn = ftanh(x2 + bc[1024+dd] + rg*(x3 + bc[1536+dd]));
          float h = (1.f-zg)*gn + zg*hp;
          stf_cp(&hpw[(size_t)b3*HID + dd], h);       // sc1 write
          sth_cp(&hmw[(size_t)b3*HID + dd], f2bf(h)); // sc1 write
        }
      }
      __syncthreads();
      setflag(&hfl[wg*FLS], (unsigned)(t+1));
    }
  }

  // ---- output head ----
  if (wg == 0){
    pollN(hfl, 128, (unsigned)TSEQ);
    if (tid < NB*3){
      const float* hf = hmbuf + (size_t)((TSEQ-1)&1)*65536;
      int b2 = tid/3, c = tid%3;
      float acc = outb[c];
      const float* h = hf + (size_t)b2*HID;
      const float* w = outW + (size_t)c*HID;
      for (int d2=0; d2<HID; ++d2) acc = fmaf(bpf(h+d2), w[d2], acc);
      out[tid] = fmaxf(acc, 0.f);
    }
  }
}

extern "C" void kernel_launch(void* const* d_in, const int* in_sizes, int n_in,
                              void* d_out, int out_size, void* d_ws, size_t ws_size,
                              hipStream_t stream)
{
  const float* Ep    = (const float*)d_in[0];
  const float* Eh    = (const float*)d_in[1];
  const float* p_W   = (const float*)d_in[2];
  const float* p_b   = (const float*)d_in[3];
  const float* h_W   = (const float*)d_in[4];
  const float* h_b   = (const float*)d_in[5];
  const float* pgWih = (const float*)d_in[6];
  const float* pgWhh = (const float*)d_in[7];
  const float* pgbih = (const float*)d_in[8];
  const float* pgbhh = (const float*)d_in[9];
  const float* hgWih = (const float*)d_in[10];
  const float* hgWhh = (const float*)d_in[11];
  const float* hgbih = (const float*)d_in[12];
  const float* hgbhh = (const float*)d_in[13];
  const float* W_s   = (const float*)d_in[14];
  const float* W_t   = (const float*)d_in[15];
  const float* w_e   = (const float*)d_in[16];
  const float* W_m   = (const float*)d_in[17];
  const float* mWih  = (const float*)d_in[18];
  const float* mWhh  = (const float*)d_in[19];
  const float* mbih  = (const float*)d_in[20];
  const float* mbhh  = (const float*)d_in[21];
  const float* outW  = (const float*)d_in[22];
  const float* outb  = (const float*)d_in[23];

  const size_t OB    = (size_t)TSEQ*NB*HID*sizeof(bfraw);
  const size_t RB    = OB;
  const size_t WFB   = (size_t)G3*INDIM*sizeof(bfraw);
  const size_t SQB   = (size_t)HID*HID*sizeof(bfraw);
  const size_t WHHB  = (size_t)G3*HID*sizeof(bfraw);
  const size_t WCATB = (size_t)2048*1536*sizeof(bfraw);
  const size_t BARB  = (size_t)4*NWG*FLS*sizeof(unsigned);
  const size_t needed = 2*OB + RB + 2*WFB + 3*SQB + 2*WHHB + WCATB
                        + 8192 + 2*6144
                        + 4*262144 + 2*262144 + 2*131072
                        + BARB;
  if (ws_size < needed) return;

  char* p = (char*)d_ws;
  bfraw* o_p_bf = (bfraw*)p; p += OB;
  bfraw* o_h_bf = (bfraw*)p; p += OB;
  char*  Rreg   = p;         p += RB;
  bfraw* Wfp_bf = (bfraw*)p; p += WFB;
  bfraw* Wfh_bf = (bfraw*)p; p += WFB;
  bfraw* WsT_bf = (bfraw*)p; p += SQB;
  bfraw* WtT_bf = (bfraw*)p; p += SQB;
  bfraw* WmT_bf = (bfraw*)p; p += SQB;
  bfraw* Whhp_bf= (bfraw*)p; p += WHHB;
  bfraw* Whhh_bf= (bfraw*)p; p += WHHB;
  bfraw* Wcat_bf= (bfraw*)p; p += WCATB;
  float* bc     = (float*)p; p += 8192;
  float* bfp    = (float*)p; p += 6144;
  float* bfh    = (float*)p; p += 6144;
  float* hst    = (float*)p; p += 4*262144;
  float* hmbuf  = (float*)p; p += 2*262144;
  bfraw* hm_bf  = (bfraw*)p; p += 2*131072;
  unsigned* bar = (unsigned*)p; p += BARB;

  bfraw* pWT_bf = (bfraw*)Rreg;
  bfraw* hWT_bf = (bfraw*)(Rreg + (size_t)INDIM*HID*sizeof(bfraw));
  float* GIp_c  = (float*)Rreg;
  float* GIh_c  = (float*)(Rreg + (size_t)CH*NB*G3*sizeof(float));
  bfraw* Whs_bf = (bfraw*)Rreg;
  float* Lbuf   = (float*)Wfp_bf;                          // 256 KB overlay
  bfraw* a_bf   = (bfraw*)((char*)Wfp_bf + 2097152);       // 128 KB
  float* Gx     = (float*)((char*)Wfp_bf + WFB);           // 1 MB (Wfh region)

  (void)hipFuncSetAttribute((const void*)scanB, hipFuncAttributeMaxDynamicSharedMemorySize, 131072);
  (void)hipFuncSetAttribute((const void*)scanD, hipFuncAttributeMaxDynamicSharedMemorySize, 155776);

  dim3 b256(256), b512(512);

  init_k<<<dim3(128), b256, 0, stream>>>(bar);
  hminit_k<<<dim3(512), b256, 0, stream>>>(hmbuf, hm_bf);

  // ---- Phase A: weight prep ----
  tconv_k<<<dim3(INDIM/32, HID/32), b256, 0, stream>>>(p_W, pWT_bf, HID, INDIM);
  tconv_k<<<dim3(INDIM/32, HID/32), b256, 0, stream>>>(h_W, hWT_bf, HID, INDIM);
  tconv_k<<<dim3(HID/32, HID/32),  b256, 0, stream>>>(W_s, WsT_bf, HID, HID);
  tconv_k<<<dim3(HID/32, HID/32),  b256, 0, stream>>>(W_t, WtT_bf, HID, HID);
  tconv_k<<<dim3(HID/32, HID/32),  b256, 0, stream>>>(W_m, WmT_bf, HID, HID);
  cvt_k<<<dim3((G3*HID)/1024), b256, 0, stream>>>(pgWhh, Whhp_bf, G3*HID);
  cvt_k<<<dim3((G3*HID)/1024), b256, 0, stream>>>(hgWhh, Whhh_bf, G3*HID);
  wcat_k<<<dim3(3072), b256, 0, stream>>>(mWih, mWhh, Wcat_bf);
  bpack_k<<<dim3(2), b256, 0, stream>>>(mbih, mbhh, bc);
  fuse_bias_k<<<dim3(G3/256), b256, 0, stream>>>(pgWih, pgbih, p_b, bfp);
  fuse_bias_k<<<dim3(G3/256), b256, 0, stream>>>(hgWih, hgbih, h_b, bfh);
  mgemm<float, bfraw, false><<<dim3(INDIM/128, G3/128, 2), b256, 0, stream>>>(
    pgWih, hgWih, pWT_bf, hWT_bf, nullptr, nullptr, Wfp_bf, Wfh_bf,
    HID, HID, HID, INDIM);

  // ---- Phase B: chunked GI GEMM + persistent scan ----
  for (int c = 0; c < TSEQ/CH; ++c){
    mgemm<float, float, true><<<dim3(G3/128, (CH*NB)/128, 2), b256, 0, stream>>>(
      Ep + (size_t)c*CH*NB*INDIM, Eh + (size_t)c*CH*NB*INDIM,
      Wfp_bf, Wfh_bf, bfp, bfh, GIp_c, GIh_c,
      INDIM, INDIM, INDIM, G3);
    scanB<<<dim3(NWG), b512, 131072, stream>>>(
      GIp_c, GIh_c, Whhp_bf, Whhh_bf, pgbhh, hgbhh,
      hst, o_p_bf, o_h_bf, c*CH, bar);
  }

  // ---- Phase C: Whs = o_p @ W_s ----
  mgemm<bfraw, bfraw, false><<<dim3(HID/128, (TSEQ*NB)/128, 1), b256, 0, stream>>>(
    o_p_bf, o_p_bf, WsT_bf, WsT_bf, nullptr, nullptr, Whs_bf, Whs_bf,
    HID, HID, HID, HID);

  // ---- Phase D: persistent scan ----
  scanD<<<dim3(NWG), b512, 155776, stream>>>(
    Whs_bf, o_p_bf, o_h_bf, WtT_bf, WmT_bf, w_e, Wcat_bf, bc,
    hmbuf, hm_bf, a_bf, Lbuf, Gx,
    outW, outb, (float*)d_out, bar);
}

// Round 16
// 18662.909 us; speedup vs baseline: 1.6991x; 1.1123x over previous
//
#include <hip/hip_runtime.h>
#include <cstddef>

#define TSEQ 256
#define NB   128
#define HID  512
#define G3   1536
#define INDIM 768
#define CH   16
#define NWG  256
#define FLS  32   // u32 stride between flag lines (128 B)

typedef unsigned short bfraw;
using short8 = __attribute__((ext_vector_type(8))) short;
using f32x4  = __attribute__((ext_vector_type(4))) float;

#define MFMA16 __builtin_amdgcn_mfma_f32_16x16x32_bf16

__device__ __forceinline__ float bf2f(unsigned int u){ return __uint_as_float(u<<16); }
__device__ __forceinline__ bfraw f2bf(float f){
  unsigned int u = __float_as_uint(f);
  u += 0x7fffu + ((u>>16)&1u);
  return (bfraw)(u>>16);
}
__device__ __forceinline__ float fsig(float x){
  return __builtin_amdgcn_rcpf(1.0f + __expf(-x));
}
__device__ __forceinline__ float ftanh(float x){
  return 1.0f - 2.0f*__builtin_amdgcn_rcpf(1.0f + __expf(2.0f*x));
}

// ==== sc1 coherence-point access (L2-bypass): ALL cross-WG mutable state ====
__device__ __forceinline__ uint4 bpu4(const void* p){
  unsigned long long a = __hip_atomic_load((const unsigned long long*)p,     __ATOMIC_RELAXED, __HIP_MEMORY_SCOPE_AGENT);
  unsigned long long b = __hip_atomic_load((const unsigned long long*)p + 1, __ATOMIC_RELAXED, __HIP_MEMORY_SCOPE_AGENT);
  uint4 r; r.x=(unsigned)a; r.y=(unsigned)(a>>32); r.z=(unsigned)b; r.w=(unsigned)(b>>32);
  return r;
}
__device__ __forceinline__ short8 bps8(const void* p){
  union{ uint4 u; short8 s; } cv; cv.u = bpu4(p); return cv.s;
}
__device__ __forceinline__ float4 bpf4(const void* p){
  union{ uint4 u; float4 f; } cv; cv.u = bpu4(p); return cv.f;
}
__device__ __forceinline__ float bpf(const void* p){
  unsigned u = __hip_atomic_load((const unsigned*)p, __ATOMIC_RELAXED, __HIP_MEMORY_SCOPE_AGENT);
  return __uint_as_float(u);
}
__device__ __forceinline__ void st4_cp(void* p, unsigned v){
  __hip_atomic_store((unsigned*)p, v, __ATOMIC_RELAXED, __HIP_MEMORY_SCOPE_AGENT);
}
__device__ __forceinline__ void st8_cp(void* p, unsigned long long v){
  __hip_atomic_store((unsigned long long*)p, v, __ATOMIC_RELAXED, __HIP_MEMORY_SCOPE_AGENT);
}
__device__ __forceinline__ void stf_cp(float* p, float v){
  __hip_atomic_store((unsigned*)p, __float_as_uint(v), __ATOMIC_RELAXED, __HIP_MEMORY_SCOPE_AGENT);
}
__device__ __forceinline__ void sth_cp(bfraw* p, bfraw v){
  __hip_atomic_store((unsigned short*)p, v, __ATOMIC_RELAXED, __HIP_MEMORY_SCOPE_AGENT);
}
__device__ __forceinline__ unsigned long long pk64(float a, float b){
  return (unsigned long long)__float_as_uint(a) | ((unsigned long long)__float_as_uint(b)<<32);
}

// ---- relaxed spin with exponential backoff; NO cache maintenance anywhere ----
__device__ __forceinline__ void spin_ge(unsigned* p, unsigned epoch){
  int sp = 0;
  while (__hip_atomic_load(p, __ATOMIC_RELAXED, __HIP_MEMORY_SCOPE_AGENT) < epoch){
    if (sp < 3){ __builtin_amdgcn_s_sleep(1); ++sp; }
    else        __builtin_amdgcn_s_sleep(16);
  }
}
// poll n producer flags in parallel (no acquire — data paths are sc1)
__device__ __forceinline__ void pollN(unsigned* flags, int n, unsigned epoch){
  const int tid = threadIdx.x;
  if (tid < n) spin_ge(&flags[tid*FLS], epoch);
  __syncthreads();
}
// RELAXED flag publish. Correctness: caller passed __syncthreads() after the
// sc1 payload stores; barrier entry drains vmcnt(0) on every wave, so payload
// is complete at the coherence point before any thread reaches here. The
// explicit waitcnt drains any thread-0 stragglers. NO wbl2 is emitted.
__device__ __forceinline__ void setflag(unsigned* f, unsigned v){
  if (threadIdx.x == 0){
    asm volatile("s_waitcnt vmcnt(0)" ::: "memory");
    __hip_atomic_store(f, v, __ATOMIC_RELAXED, __HIP_MEMORY_SCOPE_AGENT);
  }
}

__global__ void init_k(unsigned* bar){
  int i = blockIdx.x*256 + threadIdx.x;
  if (i < 4*NWG*FLS) bar[i] = 0u;
}

__global__ void hminit_k(float* hmbuf, bfraw* hm_bf){
  int i = blockIdx.x*256 + threadIdx.x;   // 131072 (both slots)
  hmbuf[i] = 1.0f;
  hm_bf[i] = (bfraw)0x3f80;
}

// ---- transpose+convert: in fp32 [R][Cc] -> out bf16 [Cc][R] ----
__global__ __launch_bounds__(256)
void tconv_k(const float* __restrict__ in, bfraw* __restrict__ out, int R, int Cc){
  __shared__ float t[32][33];
  int c0 = blockIdx.x*32, r0 = blockIdx.y*32;
  int tx = threadIdx.x&31, ty = threadIdx.x>>5;
  #pragma unroll
  for (int i=0;i<32;i+=8) t[ty+i][tx] = in[(size_t)(r0+ty+i)*Cc + c0+tx];
  __syncthreads();
  #pragma unroll
  for (int i=0;i<32;i+=8) out[(size_t)(c0+ty+i)*R + r0+tx] = f2bf(t[tx][ty+i]);
}

__global__ void cvt_k(const float* __restrict__ in, bfraw* __restrict__ out, int n){
  int i = (blockIdx.x*256 + threadIdx.x)*4;
  if (i >= n) return;
  float4 v = *(const float4*)(in+i);
  uint2 o;
  o.x = (unsigned)f2bf(v.x) | ((unsigned)f2bf(v.y)<<16);
  o.y = (unsigned)f2bf(v.z) | ((unsigned)f2bf(v.w)<<16);
  *(uint2*)(out+i) = o;
}

// W_cat[n'][k], n'=dd*4+g, k<1536 (segs: a[0,512) x[512,1024) -> mWih; hm[1024,1536) -> mWhh)
__global__ void wcat_k(const float* __restrict__ mWih, const float* __restrict__ mWhh,
                       bfraw* __restrict__ Wcat){
  size_t gid = (size_t)blockIdx.x*256 + threadIdx.x;
  int np = (int)(gid / 384);
  int k4 = ((int)(gid % 384))*4;
  int dd = np>>2, g = np&3;
  float v[4];
  #pragma unroll
  for (int j=0;j<4;++j){
    int k = k4+j; float x = 0.f;
    if (g==0)      x = (k<1024) ? mWih[(size_t)dd*1024 + k]        : mWhh[(size_t)dd*512 + (k-1024)];
    else if (g==1) x = (k<1024) ? mWih[(size_t)(512+dd)*1024 + k]  : mWhh[(size_t)(512+dd)*512 + (k-1024)];
    else if (g==2) x = (k<1024) ? mWih[(size_t)(1024+dd)*1024 + k] : 0.f;
    else           x = (k<1024) ? 0.f : mWhh[(size_t)(1024+dd)*512 + (k-1024)];
    v[j] = x;
  }
  uint2 o;
  o.x = (unsigned)f2bf(v[0]) | ((unsigned)f2bf(v[1])<<16);
  o.y = (unsigned)f2bf(v[2]) | ((unsigned)f2bf(v[3])<<16);
  *(uint2*)(Wcat + (size_t)np*1536 + k4) = o;
}

__global__ void bpack_k(const float* __restrict__ mbih, const float* __restrict__ mbhh,
                        float* __restrict__ bc){
  int dd = blockIdx.x*256 + threadIdx.x;
  if (dd >= 512) return;
  bc[dd]      = mbih[dd] + mbhh[dd];
  bc[512+dd]  = mbih[512+dd] + mbhh[512+dd];
  bc[1024+dd] = mbih[1024+dd];
  bc[1536+dd] = mbhh[1024+dd];
}

__global__ void fuse_bias_k(const float* __restrict__ Wih, const float* __restrict__ bih,
                            const float* __restrict__ pb, float* __restrict__ bout)
{
  int g = blockIdx.x*256 + threadIdx.x;
  if (g >= G3) return;
  float acc = bih[g];
  const float* w = Wih + (size_t)g*HID;
  for (int e=0;e<HID;e+=4){
    float4 wv = *(const float4*)(w+e);
    float4 pv = *(const float4*)(pb+e);
    acc += wv.x*pv.x + wv.y*pv.y + wv.z*pv.z + wv.w*pv.w;
  }
  bout[g] = acc;
}

// ---- MFMA bf16 GEMM: C[MxN] = A[MxK] * B^T (+bias); z selects operand set ----
template<typename TA, typename TC, bool BIAS>
__global__ __launch_bounds__(256)
void mgemm(const TA* __restrict__ A0, const TA* __restrict__ A1,
           const bfraw* __restrict__ B0, const bfraw* __restrict__ B1,
           const float* __restrict__ bias0, const float* __restrict__ bias1,
           TC* __restrict__ C0, TC* __restrict__ C1,
           int K, int lda, int ldb, int ldc)
{
  const TA* A = blockIdx.z ? A1 : A0;
  const bfraw* B = blockIdx.z ? B1 : B0;
  const float* bias = blockIdx.z ? bias1 : bias0;
  TC* C = blockIdx.z ? C1 : C0;
  __shared__ bfraw Al[128*40];
  __shared__ bfraw Bl[128*40];
  const int tid = threadIdx.x;
  const size_t m0 = (size_t)blockIdx.y*128, n0 = (size_t)blockIdx.x*128;
  const int w = tid>>6, l = tid&63;
  const int wr = (w>>1)*64, wc = (w&1)*64;
  const int fr = l&15, fg = l>>4;
  f32x4 acc[4][4];
  #pragma unroll
  for (int i=0;i<4;++i)
    #pragma unroll
    for (int j=0;j<4;++j) acc[i][j] = (f32x4){0.f,0.f,0.f,0.f};

  const int srow = tid>>1, skc = (tid&1)*16;
  for (int k0=0; k0<K; k0+=32){
    if constexpr (sizeof(TA)==4){
      const float* ap = (const float*)A + (m0+srow)*lda + k0 + skc;
      float4 v0=*(const float4*)ap, v1=*(const float4*)(ap+4),
             v2=*(const float4*)(ap+8), v3=*(const float4*)(ap+12);
      uint4 w0, w1;
      w0.x=(unsigned)f2bf(v0.x)|((unsigned)f2bf(v0.y)<<16);
      w0.y=(unsigned)f2bf(v0.z)|((unsigned)f2bf(v0.w)<<16);
      w0.z=(unsigned)f2bf(v1.x)|((unsigned)f2bf(v1.y)<<16);
      w0.w=(unsigned)f2bf(v1.z)|((unsigned)f2bf(v1.w)<<16);
      w1.x=(unsigned)f2bf(v2.x)|((unsigned)f2bf(v2.y)<<16);
      w1.y=(unsigned)f2bf(v2.z)|((unsigned)f2bf(v2.w)<<16);
      w1.z=(unsigned)f2bf(v3.x)|((unsigned)f2bf(v3.y)<<16);
      w1.w=(unsigned)f2bf(v3.z)|((unsigned)f2bf(v3.w)<<16);
      *(uint4*)&Al[srow*40+skc]   = w0;
      *(uint4*)&Al[srow*40+skc+8] = w1;
    } else {
      const bfraw* ap = (const bfraw*)A + (m0+srow)*lda + k0 + skc;
      *(uint4*)&Al[srow*40+skc]   = *(const uint4*)ap;
      *(uint4*)&Al[srow*40+skc+8] = *(const uint4*)(ap+8);
    }
    {
      const bfraw* bp = B + (n0+srow)*ldb + k0 + skc;
      *(uint4*)&Bl[srow*40+skc]   = *(const uint4*)bp;
      *(uint4*)&Bl[srow*40+skc+8] = *(const uint4*)(bp+8);
    }
    __syncthreads();
    short8 af[4], bfr[4];
    #pragma unroll
    for (int i=0;i<4;++i) af[i]  = *(const short8*)&Al[(wr+i*16+fr)*40 + fg*8];
    #pragma unroll
    for (int j=0;j<4;++j) bfr[j] = *(const short8*)&Bl[(wc+j*16+fr)*40 + fg*8];
    #pragma unroll
    for (int i=0;i<4;++i)
      #pragma unroll
      for (int j=0;j<4;++j)
        acc[i][j] = MFMA16(af[i], bfr[j], acc[i][j], 0,0,0);
    __syncthreads();
  }
  #pragma unroll
  for (int i=0;i<4;++i){
    #pragma unroll
    for (int j=0;j<4;++j){
      size_t n = n0 + wc + j*16 + fr;
      float bv = BIAS ? bias[n] : 0.f;
      #pragma unroll
      for (int r=0;r<4;++r){
        size_t m = m0 + wr + i*16 + fg*4 + r;
        float v = acc[i][j][r] + bv;
        if constexpr (sizeof(TC)==2) ((bfraw*)C)[m*ldc + n] = f2bf(v);
        else                         ((float*)C)[m*ldc + n] = v;
      }
    }
  }
}

// ---- Phase B: persistent GRU scan; group flags; hz state via sc1 ----
__global__ __launch_bounds__(512, 2)
void scanB(const float* __restrict__ GIp, const float* __restrict__ GIh,
           const bfraw* __restrict__ Whhp, const bfraw* __restrict__ Whhh,
           const float* __restrict__ bhhp, const float* __restrict__ bhhh,
           float* __restrict__ hst, bfraw* __restrict__ o_p, bfraw* __restrict__ o_h,
           int c0, unsigned* __restrict__ bar)
{
  extern __shared__ char smem[];
  bfraw* wl = (bfraw*)smem;                  // 98304 B
  float* sh = (float*)(smem + 98304);        // 32768 B
  const int wg = blockIdx.x;
  const int z = wg>>7, rem = wg&127;
  const int bg = rem>>4, dg = rem&15;
  const float* GI  = z ? GIh : GIp;
  const bfraw* Wb  = z ? Whhh : Whhp;
  const float* bhh = z ? bhhh : bhhp;
  bfraw* ob = z ? o_h : o_p;
  float* hz = hst + (size_t)z*2*NB*HID;
  const int tid = threadIdx.x;
  unsigned* bfl = bar + 3*NWG*FLS;
  unsigned* grp = bfl + (size_t)(z*128 + bg*16)*FLS;
  unsigned* own = bfl + (size_t)wg*FLS;

  #pragma unroll
  for (int g=0; g<3; ++g){
    const unsigned* src = (const unsigned*)(Wb + (size_t)(g*512 + dg*32)*512);
    for (int j=0; j<16; ++j){
      int iu = tid + j*512;
      unsigned v = src[iu];
      int d = iu>>8, kk = (iu&255)*2;
      int idx0 = g*16384 + (kk>>2)*128 + d*4 + (kk&3);
      *((unsigned*)wl + (idx0>>1)) = v;
    }
  }
  __syncthreads();

  const int bl = tid>>5, dl = tid&31;
  const int d = dg*32+dl, bglob = bg*16+bl;
  const float br = bhh[d], bz = bhh[512+d], bn = bhh[1024+d];

  #pragma clang loop unroll(disable)
  for (int tt=0; tt<CH; ++tt){
    const int t = c0+tt;
    if (t > 0) pollN(grp, 16, (unsigned)t);
    if (t == 0){
      for (int j=0;j<4;++j){
        int i4 = tid + j*512;
        *(float4*)&sh[i4*4] = (float4){1.f,1.f,1.f,1.f};
      }
    } else {
      const float* hp = hz + (size_t)((t-1)&1)*NB*HID + (size_t)bg*16*HID;
      for (int j=0;j<4;++j){
        int i4 = tid + j*512;
        *(float4*)&sh[i4*4] = bpf4(&hp[i4*4]);        // sc1 read
      }
    }
    __syncthreads();
    float ar = br, az = bz, an = bn;
    const float* hb = sh + bl*512;
    for (int k=0;k<512;k+=4){
      float4 h4 = *(const float4*)(hb+k);
      int base = (k>>2)*128 + dl*4;
      uint2 wr = *(const uint2*)(wl + base);
      uint2 wz = *(const uint2*)(wl + 16384 + base);
      uint2 wn = *(const uint2*)(wl + 32768 + base);
      ar += h4.x*bf2f(wr.x&0xffffu) + h4.y*bf2f(wr.x>>16) + h4.z*bf2f(wr.y&0xffffu) + h4.w*bf2f(wr.y>>16);
      az += h4.x*bf2f(wz.x&0xffffu) + h4.y*bf2f(wz.x>>16) + h4.z*bf2f(wz.y&0xffffu) + h4.w*bf2f(wz.y>>16);
      an += h4.x*bf2f(wn.x&0xffffu) + h4.y*bf2f(wn.x>>16) + h4.z*bf2f(wn.y&0xffffu) + h4.w*bf2f(wn.y>>16);
    }
    const float* gi = GI + ((size_t)tt*NB + bglob)*G3;
    float r  = fsig(gi[d] + ar);
    float zz = fsig(gi[512+d] + az);
    float n  = ftanh(gi[1024+d] + r*an);
    float hp = hb[d];
    float hv = (1.0f-zz)*n + zz*hp;
    stf_cp(&(hz + (size_t)(t&1)*NB*HID)[(size_t)bglob*HID + d], hv);   // sc1 write
    ob[((size_t)t*NB + bglob)*HID + d] = f2bf(hv);                     // cached (kernel-boundary visibility)
    __syncthreads();
    setflag(own, (unsigned)(t+1));
  }
}

// ---- Phase D: persistent scan — low-fan-in flags; all mutable state via sc1 ----
__global__ __launch_bounds__(512, 2)
void scanD(const bfraw* __restrict__ Whs, const bfraw* __restrict__ o_p,
           const bfraw* __restrict__ o_h,
           const bfraw* __restrict__ WtT, const bfraw* __restrict__ WmT,
           const float* __restrict__ w_e,
           const bfraw* __restrict__ Wcat, const float* __restrict__ bc,
           float* __restrict__ hmbuf, bfraw* __restrict__ hm_bf,
           bfraw* __restrict__ a_bf, float* __restrict__ Lbuf, float* __restrict__ Gx,
           const float* __restrict__ outW, const float* __restrict__ outb,
           float* __restrict__ out, unsigned* __restrict__ bar)
{
  extern __shared__ char smem[];
  bfraw* whs_l = (bfraw*)smem;                 // 131072 B
  float* pt    = (float*)(smem + 131072);      // 16384 B [16][256]
  float* xlf   = (float*)(smem + 147456);      // 2048 B
  float* hml   = (float*)(smem + 149504);      // 2048 B
  float* c_l   = (float*)(smem + 151552);      // 1024 B
  float* lp0   = (float*)(smem + 152576);      // 1024 B
  float* lp1   = (float*)(smem + 153600);      // 1024 B
  float* l_s   = (float*)(smem + 154624);      // 1024 B
  float* red   = (float*)(smem + 155648);      // 128 B

  const int wg = blockIdx.x, tid = threadIdx.x;
  const int b = wg>>1, dh = wg&1;
  unsigned* pf  = bar;
  unsigned* afl = bar + NWG*FLS;
  unsigned* hfl = bar + 2*NWG*FLS;

  for (int it=0; it<16; ++it){
    int idx = tid + it*512;
    int tq = idx>>5, c = idx&31;
    const bfraw* src = Whs + ((size_t)tq*NB + b)*HID + dh*256 + c*8;
    *(uint4*)&whs_l[tq*256 + ((c ^ (tq&15))<<3)] = *(const uint4*)src;
  }
  const int cc_ = tid&31;
  float we8[8];
  #pragma unroll
  for (int r=0;r<8;++r) we8[r] = w_e[dh*256 + cc_*8 + r];
  __syncthreads();

  // gate/x-slice geometry: slice id s = wg&127 -> bgrp=s>>4 (16 b), ddg=s&15 (128 n)
  const int gs = wg&127, gbgrp = gs>>4, gddg = gs&15;
  const int gw = tid>>6, gl = tid&63, gfr = gl&15, gfg = gl>>4;
  const int n0w = gddg*128 + gw*16;
  const int mb0 = gbgrp*16;
  const bfraw* wrowA = Wcat + (size_t)(n0w+gfr)*1536;

  #pragma clang loop unroll(disable)
  for (int t=0; t<TSEQ; ++t){
    const int rs = (t+1)&1;
    const bfraw* hmr = hm_bf + (size_t)rs*65536;
    const float* hpr = hmbuf + (size_t)rs*65536;
    bfraw* hmw = hm_bf + (size_t)(t&1)*65536;
    float* hpw = hmbuf + (size_t)(t&1)*65536;

    // ---- step start: hm(t-1) ready — low-fan-in polls ----
    if (t > 0){
      if (tid < 16) spin_ge(&hfl[((b>>4)*16 + tid)*FLS], (unsigned)t);
      else if (wg < 128 && tid < 32) spin_ge(&hfl[(gbgrp*16 + (tid-16))*FLS], (unsigned)t);
      else if (wg >= 128 && tid == 16) spin_ge(&hfl[gs*FLS], (unsigned)t);
      __syncthreads();
    }

    // ---- stage x_t[b] (cached, read-only) and hm[b] (sc1) ----
    if (tid < 64){
      uint4 u = *(const uint4*)(o_h + ((size_t)t*NB + b)*HID + tid*8);
      float4 f0, f1;
      f0.x=bf2f(u.x&0xffffu); f0.y=bf2f(u.x>>16); f0.z=bf2f(u.y&0xffffu); f0.w=bf2f(u.y>>16);
      f1.x=bf2f(u.z&0xffffu); f1.y=bf2f(u.z>>16); f1.z=bf2f(u.w&0xffffu); f1.w=bf2f(u.w>>16);
      *(float4*)&xlf[tid*8]   = f0;
      *(float4*)&xlf[tid*8+4] = f1;
    } else if (tid < 192){
      int i2 = tid - 64;
      *(float4*)&hml[i2*4] = bpf4(hpr + (size_t)b*HID + i2*4);    // sc1 read
    }
    __syncthreads();

    // ---- c[b, e] for e in dh-half ----
    {
      const int el = tid>>1, kh = tid&1;
      const bfraw* wt = WtT + (size_t)(dh*256+el)*HID + kh*256;
      const bfraw* wm = WmT + (size_t)(dh*256+el)*HID + kh*256;
      const float* xv = xlf + kh*256;
      const float* hv = hml + kh*256;
      float acc = 0.f;
      #pragma unroll 4
      for (int k8=0;k8<32;++k8){
        uint4 wu = *(const uint4*)(wt+k8*8);
        uint4 mu = *(const uint4*)(wm+k8*8);
        float4 x0 = *(const float4*)(xv+k8*8), x1 = *(const float4*)(xv+k8*8+4);
        float4 h0 = *(const float4*)(hv+k8*8), h1 = *(const float4*)(hv+k8*8+4);
        acc += x0.x*bf2f(wu.x&0xffffu) + x0.y*bf2f(wu.x>>16) + x0.z*bf2f(wu.y&0xffffu) + x0.w*bf2f(wu.y>>16);
        acc += x1.x*bf2f(wu.z&0xffffu) + x1.y*bf2f(wu.z>>16) + x1.z*bf2f(wu.w&0xffffu) + x1.w*bf2f(wu.w>>16);
        acc += h0.x*bf2f(mu.x&0xffffu) + h0.y*bf2f(mu.x>>16) + h0.z*bf2f(mu.y&0xffffu) + h0.w*bf2f(mu.y>>16);
        acc += h1.x*bf2f(mu.z&0xffffu) + h1.y*bf2f(mu.z>>16) + h1.z*bf2f(mu.w&0xffffu) + h1.w*bf2f(mu.w>>16);
      }
      acc += __shfl_xor(acc, 1);
      if (kh == 0) c_l[el] = acc;
    }
    __syncthreads();

    // ---- logit partials over this d-half ----
    {
      const int tqs = tid>>5;
      float c8[8];
      *(float4*)&c8[0] = *(const float4*)&c_l[cc_*8];
      *(float4*)&c8[4] = *(const float4*)&c_l[cc_*8+4];
      #pragma unroll 2
      for (int i=0;i<16;++i){
        int tq = tqs + i*16;
        uint4 u = *(const uint4*)&whs_l[tq*256 + ((cc_ ^ (tq&15))<<3)];
        float s = 0.f;
        #pragma unroll
        for (int j=0;j<4;++j){
          unsigned uu = ((const unsigned*)&u)[j];
          s += ftanh(bf2f(uu&0xffffu) + c8[j*2])   * we8[j*2];
          s += ftanh(bf2f(uu>>16)     + c8[j*2+1]) * we8[j*2+1];
        }
        #pragma unroll
        for (int off=16; off; off>>=1) s += __shfl_xor(s, off);
        if (cc_ == 0) lp0[tq] = s;
      }
    }
    __syncthreads();
    if (tid < 64){                                    // Lbuf via sc1 stores
      float4 v = *(const float4*)&lp0[tid*4];
      st8_cp(&Lbuf[(size_t)wg*256 + tid*4],     pk64(v.x, v.y));
      st8_cp(&Lbuf[(size_t)wg*256 + tid*4 + 2], pk64(v.z, v.w));
    }
    __syncthreads();
    setflag(&pf[wg*FLS], (unsigned)(t+1));

    // ---- issue o_p prefetch (cached; o_p never invalidated -> L2-resident) ----
    const int dgrp = tid&31, tqs2 = tid>>5, d8 = dgrp*8;
    const bfraw* opb = o_p + (size_t)b*HID + dh*256 + d8;
    uint4 uu[16];
    #pragma unroll
    for (int i=0;i<16;++i)
      uu[i] = *(const uint4*)(opb + (size_t)(tqs2*16 + i)*NB*HID);

    // ---- overlapped gate partials ----
    f32x4 accA = {0.f,0.f,0.f,0.f};
    if (wg < 128){
      const bfraw* hrow = hmr + (size_t)(mb0+gfr)*HID;
      #pragma unroll
      for (int kk=0; kk<16; ++kk){
        short8 af = bps8(hrow + kk*32 + gfg*8);       // sc1 read
        short8 bv = *(const short8*)(wrowA + 1024 + kk*32 + gfg*8);
        accA = MFMA16(af, bv, accA, 0,0,0);
      }
    } else {
      f32x4 accB = {0.f,0.f,0.f,0.f};
      const bfraw* xrow = o_h + ((size_t)t*NB + mb0+gfr)*HID;
      #pragma unroll
      for (int kk=0; kk<16; ++kk){
        short8 af = *(const short8*)(xrow + kk*32 + gfg*8);
        short8 bv = *(const short8*)(wrowA + 512 + kk*32 + gfg*8);
        accB = MFMA16(af, bv, accB, 0,0,0);
      }
      #pragma unroll
      for (int rr=0; rr<4; ++rr)
        stf_cp(&Gx[(size_t)(mb0 + gfg*4 + rr)*2048 + n0w + gfr], accB[rr]);  // sc1
    }

    // ---- pairwise sync + read buddy partials (sc1) ----
    if (tid == 0) spin_ge(&pf[(wg^1)*FLS], (unsigned)(t+1));
    __syncthreads();
    if (tid < 64) *(float4*)&lp1[tid*4] = bpf4(&Lbuf[(size_t)(wg^1)*256 + tid*4]);
    __syncthreads();

    // ---- softmax over 256 logits ----
    {
      const int lane = tid&63;
      float v = -1e30f, e = 0.f;
      if (tid < TSEQ){
        v = lp0[tid] + lp1[tid];
        float m = v;
        #pragma unroll
        for (int off=32; off; off>>=1) m = fmaxf(m, __shfl_xor(m, off));
        if (lane==0) red[tid>>6] = m;
      }
      __syncthreads();
      float mx = fmaxf(fmaxf(red[0],red[1]), fmaxf(red[2],red[3]));
      if (tid < TSEQ){
        e = __expf(v - mx);
        float s2 = e;
        #pragma unroll
        for (int off=32; off; off>>=1) s2 += __shfl_xor(s2, off);
        if (lane==0) red[8+(tid>>6)] = s2;
      }
      __syncthreads();
      float S = red[8]+red[9]+red[10]+red[11];
      if (tid < TSEQ) l_s[tid] = e * __builtin_amdgcn_rcpf(S);
      __syncthreads();
    }

    // ---- consume prefetched o_p -> a_t d-half ----
    {
      float a0=0,a1=0,a2=0,a3=0,a4=0,a5=0,a6=0,a7=0;
      #pragma unroll
      for (int i=0;i<16;++i){
        float al = l_s[tqs2*16 + i];
        uint4 u = uu[i];
        a0 += al*bf2f(u.x&0xffffu); a1 += al*bf2f(u.x>>16);
        a2 += al*bf2f(u.y&0xffffu); a3 += al*bf2f(u.y>>16);
        a4 += al*bf2f(u.z&0xffffu); a5 += al*bf2f(u.z>>16);
        a6 += al*bf2f(u.w&0xffffu); a7 += al*bf2f(u.w>>16);
      }
      *(float4*)&pt[tqs2*256+d8]   = (float4){a0,a1,a2,a3};
      *(float4*)&pt[tqs2*256+d8+4] = (float4){a4,a5,a6,a7};
      __syncthreads();
      if (tid < 256){
        float sA = 0.f;
        #pragma unroll
        for (int ss=0;ss<16;++ss) sA += pt[ss*256 + tid];
        float sB = __shfl_down(sA, 1);
        if ((tid&1)==0){
          unsigned pk = (unsigned)f2bf(sA) | ((unsigned)f2bf(sB)<<16);
          st4_cp(a_bf + (size_t)b*HID + dh*256 + tid, pk);   // sc1 write
        }
      }
    }
    __syncthreads();
    setflag(&afl[wg*FLS], (unsigned)(t+1));

    // ---- gates: a-segment + combine + state update (wg<128) ----
    if (wg < 128){
      if (tid < 32) spin_ge(&afl[(gbgrp*32 + tid)*FLS], (unsigned)(t+1));
      else if (tid == 32) spin_ge(&afl[(128 + gs)*FLS], (unsigned)(t+1));
      __syncthreads();

      const bfraw* arow = a_bf + (size_t)(mb0+gfr)*HID;
      #pragma unroll
      for (int kk=0; kk<16; ++kk){
        short8 af = bps8(arow + kk*32 + gfg*8);       // sc1 read
        short8 bv = *(const short8*)(wrowA + kk*32 + gfg*8);
        accA = MFMA16(af, bv, accA, 0,0,0);
      }
      const int np = n0w + gfr, dd = np>>2, g = np&3;
      #pragma unroll
      for (int rr=0; rr<4; ++rr){
        float x0 = accA[rr] + bpf(&Gx[(size_t)(mb0 + gfg*4 + rr)*2048 + np]);   // sc1
        float x1 = __shfl_xor(x0, 1);
        float x2 = __shfl_xor(x0, 2);
        float x3 = __shfl_xor(x1, 2);
        if (g==0){
          int b3 = mb0 + gfg*4 + rr;
          float hp = bpf(&hpr[(size_t)b3*HID + dd]);  // sc1
          float rg = fsig(x0 + bc[dd]);
          float zg = fsig(x1 + bc[512+dd]);
          float gn = ftanh(x2 + bc[1024+dd] + rg*(x3 + bc[1536+dd]));
          float h = (1.f-zg)*gn + zg*hp;
          stf_cp(&hpw[(size_t)b3*HID + dd], h);       // sc1 write
          sth_cp(&hmw[(size_t)b3*HID + dd], f2bf(h)); // sc1 write
        }
      }
      __syncthreads();
      setflag(&hfl[wg*FLS], (unsigned)(t+1));
    }
  }

  // ---- output head ----
  if (wg == 0){
    pollN(hfl, 128, (unsigned)TSEQ);
    if (tid < NB*3){
      const float* hf = hmbuf + (size_t)((TSEQ-1)&1)*65536;
      int b2 = tid/3, c = tid%3;
      float acc = outb[c];
      const float* h = hf + (size_t)b2*HID;
      const float* w = outW + (size_t)c*HID;
      for (int d2=0; d2<HID; ++d2) acc = fmaf(bpf(h+d2), w[d2], acc);
      out[tid] = fmaxf(acc, 0.f);
    }
  }
}

extern "C" void kernel_launch(void* const* d_in, const int* in_sizes, int n_in,
                              void* d_out, int out_size, void* d_ws, size_t ws_size,
                              hipStream_t stream)
{
  const float* Ep    = (const float*)d_in[0];
  const float* Eh    = (const float*)d_in[1];
  const float* p_W   = (const float*)d_in[2];
  const float* p_b   = (const float*)d_in[3];
  const float* h_W   = (const float*)d_in[4];
  const float* h_b   = (const float*)d_in[5];
  const float* pgWih = (const float*)d_in[6];
  const float* pgWhh = (const float*)d_in[7];
  const float* pgbih = (const float*)d_in[8];
  const float* pgbhh = (const float*)d_in[9];
  const float* hgWih = (const float*)d_in[10];
  const float* hgWhh = (const float*)d_in[11];
  const float* hgbih = (const float*)d_in[12];
  const float* hgbhh = (const float*)d_in[13];
  const float* W_s   = (const float*)d_in[14];
  const float* W_t   = (const float*)d_in[15];
  const float* w_e   = (const float*)d_in[16];
  const float* W_m   = (const float*)d_in[17];
  const float* mWih  = (const float*)d_in[18];
  const float* mWhh  = (const float*)d_in[19];
  const float* mbih  = (const float*)d_in[20];
  const float* mbhh  = (const float*)d_in[21];
  const float* outW  = (const float*)d_in[22];
  const float* outb  = (const float*)d_in[23];

  const size_t OB    = (size_t)TSEQ*NB*HID*sizeof(bfraw);
  const size_t RB    = OB;
  const size_t WFB   = (size_t)G3*INDIM*sizeof(bfraw);
  const size_t SQB   = (size_t)HID*HID*sizeof(bfraw);
  const size_t WHHB  = (size_t)G3*HID*sizeof(bfraw);
  const size_t WCATB = (size_t)2048*1536*sizeof(bfraw);
  const size_t BARB  = (size_t)4*NWG*FLS*sizeof(unsigned);
  const size_t needed = 2*OB + RB + 2*WFB + 3*SQB + 2*WHHB + WCATB
                        + 8192 + 2*6144
                        + 4*262144 + 2*262144 + 2*131072
                        + BARB;
  if (ws_size < needed) return;

  char* p = (char*)d_ws;
  bfraw* o_p_bf = (bfraw*)p; p += OB;
  bfraw* o_h_bf = (bfraw*)p; p += OB;
  char*  Rreg   = p;         p += RB;
  bfraw* Wfp_bf = (bfraw*)p; p += WFB;
  bfraw* Wfh_bf = (bfraw*)p; p += WFB;
  bfraw* WsT_bf = (bfraw*)p; p += SQB;
  bfraw* WtT_bf = (bfraw*)p; p += SQB;
  bfraw* WmT_bf = (bfraw*)p; p += SQB;
  bfraw* Whhp_bf= (bfraw*)p; p += WHHB;
  bfraw* Whhh_bf= (bfraw*)p; p += WHHB;
  bfraw* Wcat_bf= (bfraw*)p; p += WCATB;
  float* bc     = (float*)p; p += 8192;
  float* bfp    = (float*)p; p += 6144;
  float* bfh    = (float*)p; p += 6144;
  float* hst    = (float*)p; p += 4*262144;
  float* hmbuf  = (float*)p; p += 2*262144;
  bfraw* hm_bf  = (bfraw*)p; p += 2*131072;
  unsigned* bar = (unsigned*)p; p += BARB;

  bfraw* pWT_bf = (bfraw*)Rreg;
  bfraw* hWT_bf = (bfraw*)(Rreg + (size_t)INDIM*HID*sizeof(bfraw));
  float* GIp_c  = (float*)Rreg;
  float* GIh_c  = (float*)(Rreg + (size_t)CH*NB*G3*sizeof(float));
  bfraw* Whs_bf = (bfraw*)Rreg;
  float* Lbuf   = (float*)Wfp_bf;                          // 256 KB overlay
  bfraw* a_bf   = (bfraw*)((char*)Wfp_bf + 2097152);       // 128 KB
  float* Gx     = (float*)((char*)Wfp_bf + WFB);           // 1 MB (Wfh region)

  (void)hipFuncSetAttribute((const void*)scanB, hipFuncAttributeMaxDynamicSharedMemorySize, 131072);
  (void)hipFuncSetAttribute((const void*)scanD, hipFuncAttributeMaxDynamicSharedMemorySize, 155776);

  dim3 b256(256), b512(512);

  init_k<<<dim3(128), b256, 0, stream>>>(bar);
  hminit_k<<<dim3(512), b256, 0, stream>>>(hmbuf, hm_bf);

  // ---- Phase A: weight prep ----
  tconv_k<<<dim3(INDIM/32, HID/32), b256, 0, stream>>>(p_W, pWT_bf, HID, INDIM);
  tconv_k<<<dim3(INDIM/32, HID/32), b256, 0, stream>>>(h_W, hWT_bf, HID, INDIM);
  tconv_k<<<dim3(HID/32, HID/32),  b256, 0, stream>>>(W_s, WsT_bf, HID, HID);
  tconv_k<<<dim3(HID/32, HID/32),  b256, 0, stream>>>(W_t, WtT_bf, HID, HID);
  tconv_k<<<dim3(HID/32, HID/32),  b256, 0, stream>>>(W_m, WmT_bf, HID, HID);
  cvt_k<<<dim3((G3*HID)/1024), b256, 0, stream>>>(pgWhh, Whhp_bf, G3*HID);
  cvt_k<<<dim3((G3*HID)/1024), b256, 0, stream>>>(hgWhh, Whhh_bf, G3*HID);
  wcat_k<<<dim3(3072), b256, 0, stream>>>(mWih, mWhh, Wcat_bf);
  bpack_k<<<dim3(2), b256, 0, stream>>>(mbih, mbhh, bc);
  fuse_bias_k<<<dim3(G3/256), b256, 0, stream>>>(pgWih, pgbih, p_b, bfp);
  fuse_bias_k<<<dim3(G3/256), b256, 0, stream>>>(hgWih, hgbih, h_b, bfh);
  mgemm<float, bfraw, false><<<dim3(INDIM/128, G3/128, 2), b256, 0, stream>>>(
    pgWih, hgWih, pWT_bf, hWT_bf, nullptr, nullptr, Wfp_bf, Wfh_bf,
    HID, HID, HID, INDIM);

  // ---- Phase B: chunked GI GEMM + persistent scan ----
  for (int c = 0; c < TSEQ/CH; ++c){
    mgemm<float, float, true><<<dim3(G3/128, (CH*NB)/128, 2), b256, 0, stream>>>(
      Ep + (size_t)c*CH*NB*INDIM, Eh + (size_t)c*CH*NB*INDIM,
      Wfp_bf, Wfh_bf, bfp, bfh, GIp_c, GIh_c,
      INDIM, INDIM, INDIM, G3);
    scanB<<<dim3(NWG), b512, 131072, stream>>>(
      GIp_c, GIh_c, Whhp_bf, Whhh_bf, pgbhh, hgbhh,
      hst, o_p_bf, o_h_bf, c*CH, bar);
  }

  // ---- Phase C: Whs = o_p @ W_s ----
  mgemm<bfraw, bfraw, false><<<dim3(HID/128, (TSEQ*NB)/128, 1), b256, 0, stream>>>(
    o_p_bf, o_p_bf, WsT_bf, WsT_bf, nullptr, nullptr, Whs_bf, Whs_bf,
    HID, HID, HID, HID);

  // ---- Phase D: persistent scan ----
  scanD<<<dim3(NWG), b512, 155776, stream>>>(
    Whs_bf, o_p_bf, o_h_bf, WtT_bf, WmT_bf, w_e, Wcat_bf, bc,
    hmbuf, hm_bf, a_bf, Lbuf, Gx,
    outW, outb, (float*)d_out, bar);
}